// Round 2
// baseline (6295.638 us; speedup 1.0000x reference)
//
#include <hip/hip_runtime.h>
#include <hip/hip_bf16.h>
#include <math.h>

// AudioModelV3: 7-block xLSTM (blocks 1,4 = sLSTM+FFN; others mLSTM).
// Round 2 theory: inputs/outputs are fp32 (reference setup_inputs is all
// jnp.float32; bf16 reads produced NaN). Compute fp32 throughout.
// Workspace usage: ~210 MB of d_ws as fp32 scratch.

#define B_    64
#define S_    199
#define E_    256
#define NTOK  (B_*S_)          // 12736 (= 199*64, divisible by 64)

__device__ __forceinline__ float sigmoidf_(float x) { return 1.f / (1.f + expf(-x)); }
__device__ __forceinline__ float siluf_(float x) { return x / (1.f + expf(-x)); }
__device__ __forceinline__ float logsigf_(float x) { return fminf(x, 0.f) - log1pf(expf(-fabsf(x))); }

// ---------------- generic GEMM: C[M,N] = A[M,K] @ B[K,N] (+bias) (+=C) ------
// 64x64 tile, 256 threads, 4x4 micro-tile, K-tile 16. M%64==0, N%64==0, K%16==0.
__global__ void __launch_bounds__(256)
gemm64(const float* __restrict__ A, const float* __restrict__ Bw,
       const float* __restrict__ bias, float* __restrict__ C,
       int M, int K, int N, int accum) {
    __shared__ float As[16][68];   // [k][row], padded
    __shared__ float Bs[16][64];   // [k][col]
    int tid = threadIdx.x;
    int tx = tid & 15, ty = tid >> 4;
    int m0 = blockIdx.y * 64, n0 = blockIdx.x * 64;
    float acc[4][4] = {};
    for (int k0 = 0; k0 < K; k0 += 16) {
        {   // load A tile 64x16 (transposed into As)
            int r = tid >> 2, c4 = (tid & 3) * 4;
            const float* ap = A + (size_t)(m0 + r) * K + k0 + c4;
            #pragma unroll
            for (int i = 0; i < 4; i++) As[c4 + i][r] = ap[i];
        }
        #pragma unroll
        for (int i = 0; i < 4; i++) {   // load B tile 16x64
            int lin = i * 256 + tid;
            int kk = lin >> 6, nn = lin & 63;
            Bs[kk][nn] = Bw[(size_t)(k0 + kk) * N + n0 + nn];
        }
        __syncthreads();
        #pragma unroll
        for (int kk = 0; kk < 16; kk++) {
            float a[4], b[4];
            #pragma unroll
            for (int i = 0; i < 4; i++) a[i] = As[kk][ty * 4 + i];
            #pragma unroll
            for (int i = 0; i < 4; i++) b[i] = Bs[kk][tx * 4 + i];
            #pragma unroll
            for (int i = 0; i < 4; i++)
                #pragma unroll
                for (int j = 0; j < 4; j++) acc[i][j] += a[i] * b[j];
        }
        __syncthreads();
    }
    #pragma unroll
    for (int i = 0; i < 4; i++) {
        int m = m0 + ty * 4 + i;
        #pragma unroll
        for (int j = 0; j < 4; j++) {
            int n = n0 + tx * 4 + j;
            float o = acc[i][j];
            if (bias) o += bias[n];
            float* cp = &C[(size_t)m * N + n];
            if (accum) o += *cp;
            *cp = o;
        }
    }
}

// ---------------- layernorm over 256 with weight -----------------------------
__global__ void __launch_bounds__(256)
layernorm256(const float* __restrict__ x, const float* __restrict__ w, float* __restrict__ y) {
    int n = blockIdx.x, t = threadIdx.x;
    float v = x[(size_t)n * 256 + t];
    float s = v, s2 = v * v;
    #pragma unroll
    for (int off = 32; off; off >>= 1) { s += __shfl_xor(s, off); s2 += __shfl_xor(s2, off); }
    __shared__ float ps[4], ps2[4];
    if ((t & 63) == 0) { ps[t >> 6] = s; ps2[t >> 6] = s2; }
    __syncthreads();
    float S = ps[0] + ps[1] + ps[2] + ps[3];
    float S2 = ps2[0] + ps2[1] + ps2[2] + ps2[3];
    float mu = S / 256.f, var = S2 / 256.f - mu * mu;
    y[(size_t)n * 256 + t] = (v - mu) * rsqrtf(var + 1e-5f) * w[t];
}

// ---------------- post-LN + selu --------------------------------------------
__global__ void __launch_bounds__(256)
postln_selu(const float* __restrict__ x, const float* __restrict__ w, float* __restrict__ y) {
    int n = blockIdx.x, t = threadIdx.x;
    float v = x[(size_t)n * 256 + t];
    float s = v, s2 = v * v;
    #pragma unroll
    for (int off = 32; off; off >>= 1) { s += __shfl_xor(s, off); s2 += __shfl_xor(s2, off); }
    __shared__ float ps[4], ps2[4];
    if ((t & 63) == 0) { ps[t >> 6] = s; ps2[t >> 6] = s2; }
    __syncthreads();
    float S = ps[0] + ps[1] + ps[2] + ps[3];
    float S2 = ps2[0] + ps2[1] + ps2[2] + ps2[3];
    float mu = S / 256.f, var = S2 / 256.f - mu * mu;
    float yn = (v - mu) * rsqrtf(var + 1e-5f) * w[t];
    y[(size_t)n * 256 + t] = 1.0507009873554805f * (yn > 0.f ? yn : 1.6732632423543772f * (expf(yn) - 1.f));
}

// ---------------- mLSTM: causal conv (512 ch) + silu -------------------------
__global__ void conv_silu_m(const float* __restrict__ xi, const float* __restrict__ cw,
                            const float* __restrict__ cb, float* __restrict__ xca) {
    int idx = blockIdx.x * blockDim.x + threadIdx.x;
    if (idx >= NTOK * 512) return;
    int n = idx >> 9, c = idx & 511;
    int b = n / S_, s = n - b * S_;
    float y = cb[c];
    #pragma unroll
    for (int i = 0; i < 4; i++) {
        int sp = s - 3 + i;
        if (sp >= 0) y += xi[(size_t)(b * S_ + sp) * 1024 + c] * cw[c * 4 + i];
    }
    xca[idx] = siluf_(y);
}

// ---------------- mLSTM: block-diagonal headwise q,k,v -----------------------
__global__ void headwise_qkv(const float* __restrict__ xca, const float* __restrict__ xi,
                             const float* __restrict__ qw, const float* __restrict__ kw,
                             const float* __restrict__ vw,
                             float* __restrict__ qb, float* __restrict__ kb, float* __restrict__ vb) {
    int idx = blockIdx.x * blockDim.x + threadIdx.x;
    if (idx >= NTOK * 512) return;
    int n = idx >> 9, c = idx & 511;
    int hh = c >> 2, o = c & 3;
    float aq = 0, ak = 0, av = 0;
    #pragma unroll
    for (int d = 0; d < 4; d++) {
        float xc = xca[(size_t)n * 512 + hh * 4 + d];
        float xm = xi[(size_t)n * 1024 + hh * 4 + d];
        int wi = (hh * 4 + o) * 4 + d;
        aq += xc * qw[wi]; ak += xc * kw[wi]; av += xm * vw[wi];
    }
    qb[idx] = aq; kb[idx] = ak; vb[idx] = av;
}

// ---------------- mLSTM: ig/fg gates (one wave per (n,head,which)) -----------
__global__ void __launch_bounds__(256)
mlstm_gates(const float* __restrict__ qb, const float* __restrict__ kb, const float* __restrict__ vb,
            const float* __restrict__ igw, const float* __restrict__ igbias,
            const float* __restrict__ fgw, const float* __restrict__ fgbias,
            float* __restrict__ igo, float* __restrict__ fgo) {
    int gid = blockIdx.x * 256 + threadIdx.x;
    int wid = gid >> 6, lane = gid & 63;
    int which = wid & 1, hd = (wid >> 1) & 3, n = wid >> 3;
    if (n >= NTOK) return;
    const float* w = (which ? fgw : igw) + hd * 1536;
    float a = 0.f;
    for (int j = lane; j < 512; j += 64) {
        a += qb[(size_t)n * 512 + j] * w[j]
           + kb[(size_t)n * 512 + j] * w[512 + j]
           + vb[(size_t)n * 512 + j] * w[1024 + j];
    }
    #pragma unroll
    for (int off = 32; off; off >>= 1) a += __shfl_xor(a, off);
    if (lane == 0) {
        a += (which ? fgbias : igbias)[hd];
        (which ? fgo : igo)[(size_t)n * 4 + hd] = a;
    }
}

// ---------------- mLSTM: cumsum of logsigmoid(fg) + prefix max ---------------
__global__ void mlstm_cumsum(const float* __restrict__ fgo, const float* __restrict__ igo,
                             float* __restrict__ lfc, float* __restrict__ Mx) {
    int t = threadIdx.x;           // 256 threads = (b,h)
    int b = t >> 2, h = t & 3;
    float* lf = lfc + (b * 4 + h) * (S_ + 1);
    float c = 0.f, mx = -1e30f;
    lf[0] = 0.f;
    for (int s = 0; s < S_; s++) {
        float f = fgo[(size_t)(b * S_ + s) * 4 + h];
        c += logsigf_(f);
        lf[s + 1] = c;
        float g = igo[(size_t)(b * S_ + s) * 4 + h] - c;
        mx = fmaxf(mx, g);
        Mx[(b * 4 + h) * S_ + s] = mx;
    }
}

// ---------------- mLSTM: attention, one wave per query row -------------------
__global__ void __launch_bounds__(256)
mlstm_attn(const float* __restrict__ qb, const float* __restrict__ kb, const float* __restrict__ vb,
           const float* __restrict__ igb, const float* __restrict__ lfc, const float* __restrict__ Mx,
           float* __restrict__ outb) {
    int wv = threadIdx.x >> 6, lane = threadIdx.x & 63;
    int s = blockIdx.x * 4 + wv;
    if (s >= S_) return;
    int bh = blockIdx.y; int b = bh >> 2, h = bh & 3;
    size_t rowq = (size_t)(b * S_ + s) * 512 + h * 128;
    float q0 = qb[rowq + lane], q1 = qb[rowq + 64 + lane];
    const float* lf = lfc + bh * (S_ + 1);
    float lfs = lf[s + 1];
    float maxD = lfs + Mx[bh * S_ + s];
    float rowsum = 0.f, a0 = 0.f, a1 = 0.f;
    const float scale = 0.08838834764831845f;   // 1/sqrt(128)
    for (int t = 0; t <= s; t++) {
        size_t rt = (size_t)(b * S_ + t) * 512 + h * 128;
        float p = q0 * kb[rt + lane] + q1 * kb[rt + 64 + lane];
        #pragma unroll
        for (int off = 32; off; off >>= 1) p += __shfl_xor(p, off);
        float Cst = p * scale * expf(lfs - lf[t + 1] + igb[(size_t)(b * S_ + t) * 4 + h] - maxD);
        rowsum += Cst;
        a0 += Cst * vb[rt + lane];
        a1 += Cst * vb[rt + 64 + lane];
    }
    float nrm = fmaxf(fabsf(rowsum), expf(-maxD)) + 1e-6f;
    outb[rowq + lane] = a0 / nrm;
    outb[rowq + 64 + lane] = a1 / nrm;
}

// ---------------- mLSTM: per-head (128) layernorm, weight 512, in place ------
__global__ void __launch_bounds__(512)
mhln_m(float* __restrict__ hatt, const float* __restrict__ w) {
    int n = blockIdx.x, t = threadIdx.x;
    float v = hatt[(size_t)n * 512 + t];
    float s = v, s2 = v * v;
    #pragma unroll
    for (int off = 32; off; off >>= 1) { s += __shfl_xor(s, off); s2 += __shfl_xor(s2, off); }
    __shared__ float ps[8], ps2[8];
    if ((t & 63) == 0) { ps[t >> 6] = s; ps2[t >> 6] = s2; }
    __syncthreads();
    int hd = t >> 7;
    float S = ps[hd * 2] + ps[hd * 2 + 1], S2 = ps2[hd * 2] + ps2[hd * 2 + 1];
    float mu = S / 128.f, var = S2 / 128.f - mu * mu;
    hatt[(size_t)n * 512 + t] = (v - mu) * rsqrtf(var + 1e-5f) * w[t];
}

// ---------------- mLSTM: h_state = (hn + skip*xca)*silu(z), in place ---------
__global__ void hstate_m(float* __restrict__ hatt, const float* __restrict__ xca,
                         const float* __restrict__ xi, const float* __restrict__ skip) {
    int idx = blockIdx.x * blockDim.x + threadIdx.x;
    if (idx >= NTOK * 512) return;
    int n = idx >> 9, c = idx & 511;
    float z = xi[(size_t)n * 1024 + 512 + c];
    hatt[idx] = (hatt[idx] + skip[c] * xca[idx]) * siluf_(z);
}

// ---------------- sLSTM: causal conv (256 ch) + silu -------------------------
__global__ void conv_silu_s(const float* __restrict__ xln, const float* __restrict__ cw,
                            const float* __restrict__ cb, float* __restrict__ xc) {
    int idx = blockIdx.x * blockDim.x + threadIdx.x;
    if (idx >= NTOK * 256) return;
    int n = idx >> 8, c = idx & 255;
    int b = n / S_, s = n - b * S_;
    float y = cb[c];
    #pragma unroll
    for (int i = 0; i < 4; i++) {
        int sp = s - 3 + i;
        if (sp >= 0) y += xln[(size_t)(b * S_ + sp) * 256 + c] * cw[c * 4 + i];
    }
    xc[idx] = siluf_(y);
}

// ---------------- sLSTM: Wx gate pre-activations -----------------------------
__global__ void slstm_wx(const float* __restrict__ xc, const float* __restrict__ xln,
                         const float* __restrict__ gw, float* __restrict__ Wx) {
    int idx = blockIdx.x * blockDim.x + threadIdx.x;
    if (idx >= NTOK * 1024) return;
    int n = idx >> 10, r = idx & 1023;
    int g = r >> 8, h = (r >> 6) & 3, o = r & 63;
    const float* src = (g < 2) ? xc : xln;
    const float* wp = gw + (size_t)(((g * 4 + h) * 64 + o)) * 64;
    const float* sp = src + (size_t)n * 256 + h * 64;
    float a = 0.f;
    for (int d = 0; d < 64; d++) a += sp[d] * wp[d];
    Wx[idx] = a;
}

// ---------------- sLSTM: recurrence, one block per (b,head) ------------------
__global__ void __launch_bounds__(256)
slstm_rec(const float* __restrict__ Wx, const float* __restrict__ rw,
          const float* __restrict__ bias, float* __restrict__ ys) {
    int b = blockIdx.x >> 2, h = blockIdx.x & 3;
    int tid = threadIdx.x;
    int g = tid >> 6, o = tid & 63;
    float w[64];
    const float* wp = rw + (size_t)(((g * 4 + h) * 64 + o)) * 64;
    #pragma unroll
    for (int d = 0; d < 64; d++) w[d] = wp[d];
    float bi = bias[(g * 4 + h) * 64 + o];
    __shared__ float hs[64];
    __shared__ float raws[256];
    if (tid < 64) hs[tid] = 0.f;
    float c_ = 0.f, n_ = 0.f, m_ = 0.f;
    __syncthreads();
    for (int s = 0; s < S_; s++) {
        float acc = Wx[(size_t)(b * S_ + s) * 1024 + g * 256 + h * 64 + o] + bi;
        #pragma unroll
        for (int d = 0; d < 64; d++) acc += hs[d] * w[d];
        raws[tid] = acc;
        __syncthreads();
        if (tid < 64) {
            float ir = raws[tid], fr = raws[64 + tid], zr = raws[128 + tid], orr = raws[192 + tid];
            float lfpm = m_ + logsigf_(fr);
            float mn = fmaxf(ir, lfpm);
            float ig = expf(ir - mn), fg = expf(lfpm - mn);
            c_ = fg * c_ + ig * tanhf(zr);
            n_ = fg * n_ + ig;
            m_ = mn;
            float hn = sigmoidf_(orr) * (c_ / n_);
            hs[tid] = hn;
            ys[(size_t)(b * S_ + s) * 256 + h * 64 + tid] = hn;
        }
        __syncthreads();
    }
}

// ---------------- sLSTM: per-head (64) groupnorm + residual add --------------
__global__ void __launch_bounds__(256)
mhln_s_resid(const float* __restrict__ ys, const float* __restrict__ w, float* __restrict__ h) {
    int n = blockIdx.x, t = threadIdx.x;   // wave == head (64 dims)
    float v = ys[(size_t)n * 256 + t];
    float s = v, s2 = v * v;
    #pragma unroll
    for (int off = 32; off; off >>= 1) { s += __shfl_xor(s, off); s2 += __shfl_xor(s2, off); }
    float mu = s / 64.f, var = s2 / 64.f - mu * mu;
    h[(size_t)n * 256 + t] += (v - mu) * rsqrtf(var + 1e-5f) * w[t];
}

// ---------------- FFN: gelu(gate)*up -----------------------------------------
__global__ void ffn_act(const float* __restrict__ up, float* __restrict__ act) {
    int idx = blockIdx.x * blockDim.x + threadIdx.x;
    if (idx >= NTOK * 384) return;
    int n = idx / 384, j = idx - n * 384;
    float g = up[(size_t)n * 768 + j], u = up[(size_t)n * 768 + 384 + j];
    float t = tanhf(0.7978845608028654f * (g + 0.044715f * g * g * g));
    act[idx] = 0.5f * g * (1.f + t) * u;
}

// ---------------- pooling + heads --------------------------------------------
__global__ void pool_k(const float* __restrict__ a, float* __restrict__ pooled) {
    int b = blockIdx.x, e = threadIdx.x;
    float s = 0.f;
    for (int t = 0; t < S_; t++) s += a[(size_t)(b * S_ + t) * 256 + e];
    pooled[b * 256 + e] = s / (float)S_;
}

__global__ void heads_k(const float* __restrict__ pooled,
                        const float* __restrict__ we, const float* __restrict__ be,
                        const float* __restrict__ ws, const float* __restrict__ bs,
                        float* __restrict__ out) {
    int i = blockIdx.x * blockDim.x + threadIdx.x;
    if (i < B_ * 7) {
        int b = i / 7, o = i - b * 7;
        float a = be[o];
        for (int e = 0; e < 256; e++) a += pooled[b * 256 + e] * we[e * 7 + o];
        out[b * 7 + o] = a;
    } else if (i < B_ * 7 + B_ * 3) {
        int j = i - B_ * 7;
        int b = j / 3, o = j - b * 3;
        float a = bs[o];
        for (int e = 0; e < 256; e++) a += pooled[b * 256 + e] * ws[e * 3 + o];
        out[B_ * 7 + b * 3 + o] = a;
    }
}

// =============================================================================
extern "C" void kernel_launch(void* const* d_in, const int* in_sizes, int n_in,
                              void* d_out, int out_size, void* d_ws, size_t ws_size,
                              hipStream_t stream) {
    (void)in_sizes; (void)n_in; (void)out_size; (void)ws_size;
    const float* x          = (const float*)d_in[0];
    const float* w_down     = (const float*)d_in[1];
    const float* b_down     = (const float*)d_in[2];
    const float* m_ln_w     = (const float*)d_in[3];
    const float* m_proj_up  = (const float*)d_in[4];
    const float* m_conv_w   = (const float*)d_in[5];
    const float* m_conv_b   = (const float*)d_in[6];
    const float* m_q_w      = (const float*)d_in[7];
    const float* m_k_w      = (const float*)d_in[8];
    const float* m_v_w      = (const float*)d_in[9];
    const float* m_ig_w     = (const float*)d_in[10];
    const float* m_ig_b     = (const float*)d_in[11];
    const float* m_fg_w     = (const float*)d_in[12];
    const float* m_fg_b     = (const float*)d_in[13];
    const float* m_skip     = (const float*)d_in[14];
    const float* m_outnorm  = (const float*)d_in[15];
    const float* m_proj_dn  = (const float*)d_in[16];
    const float* s_ln_w     = (const float*)d_in[17];
    const float* s_conv_w   = (const float*)d_in[18];
    const float* s_conv_b   = (const float*)d_in[19];
    const float* s_gate_w   = (const float*)d_in[20];
    const float* s_rec_w    = (const float*)d_in[21];
    const float* s_bias     = (const float*)d_in[22];
    const float* s_gn_w     = (const float*)d_in[23];
    const float* s_ln2_w    = (const float*)d_in[24];
    const float* s_ffn_up   = (const float*)d_in[25];
    const float* s_ffn_dn   = (const float*)d_in[26];
    const float* post_ln_w  = (const float*)d_in[27];
    const float* w_emo      = (const float*)d_in[28];
    const float* b_emo      = (const float*)d_in[29];
    const float* w_sen      = (const float*)d_in[30];
    const float* b_sen      = (const float*)d_in[31];

    float* W    = (float*)d_ws;
    float* h    = W;                                   // NTOK*256
    float* lnb  = h    + (size_t)NTOK * 256;           // NTOK*256
    float* big0 = lnb  + (size_t)NTOK * 256;           // NTOK*1024 (xi / Wx / ffn-up)
    float* xca  = big0 + (size_t)NTOK * 1024;          // NTOK*512  (conv out)
    float* qb   = xca  + (size_t)NTOK * 512;           // NTOK*512
    float* kb   = qb   + (size_t)NTOK * 512;           // NTOK*512
    float* vb   = kb   + (size_t)NTOK * 512;           // NTOK*512
    float* hatt = vb   + (size_t)NTOK * 512;           // NTOK*512  (attn out / ys / ffn-act)
    float* igo  = hatt + (size_t)NTOK * 512;           // NTOK*4
    float* fgo  = igo  + (size_t)NTOK * 4;             // NTOK*4
    float* lfcb = fgo  + (size_t)NTOK * 4;             // 256*(S+1)
    float* Mxb  = lfcb + (size_t)256 * (S_ + 1);       // 256*S
    float* pooled = Mxb + (size_t)256 * S_;            // 64*256

    // embed: h = x @ w_down + b_down
    gemm64<<<dim3(256 / 64, NTOK / 64), 256, 0, stream>>>(x, w_down, b_down, h, NTOK, 1024, 256, 0);

    int mi = 0, si = 0;
    for (int blk = 0; blk < 7; blk++) {
        if (blk == 1 || blk == 4) {
            // ---- sLSTM block ----
            layernorm256<<<NTOK, 256, 0, stream>>>(h, s_ln_w + si * 256, lnb);
            conv_silu_s<<<(NTOK * 256 + 255) / 256, 256, 0, stream>>>(lnb, s_conv_w + si * 1024, s_conv_b + si * 256, xca);
            slstm_wx<<<(NTOK * 1024 + 255) / 256, 256, 0, stream>>>(xca, lnb, s_gate_w + (size_t)si * 65536, big0);
            slstm_rec<<<256, 256, 0, stream>>>(big0, s_rec_w + (size_t)si * 65536, s_bias + si * 1024, hatt);
            mhln_s_resid<<<NTOK, 256, 0, stream>>>(hatt, s_gn_w + si * 256, h);
            // ---- FFN ----
            layernorm256<<<NTOK, 256, 0, stream>>>(h, s_ln2_w + si * 256, lnb);
            gemm64<<<dim3(768 / 64, NTOK / 64), 256, 0, stream>>>(lnb, s_ffn_up + (size_t)si * 256 * 768, nullptr, big0, NTOK, 256, 768, 0);
            ffn_act<<<(NTOK * 384 + 255) / 256, 256, 0, stream>>>(big0, hatt);
            gemm64<<<dim3(256 / 64, NTOK / 64), 256, 0, stream>>>(hatt, s_ffn_dn + (size_t)si * 384 * 256, nullptr, h, NTOK, 384, 256, 1);
            si++;
        } else {
            // ---- mLSTM block ----
            layernorm256<<<NTOK, 256, 0, stream>>>(h, m_ln_w + mi * 256, lnb);
            gemm64<<<dim3(1024 / 64, NTOK / 64), 256, 0, stream>>>(lnb, m_proj_up + (size_t)mi * 256 * 1024, nullptr, big0, NTOK, 256, 1024, 0);
            conv_silu_m<<<(NTOK * 512 + 255) / 256, 256, 0, stream>>>(big0, m_conv_w + mi * 2048, m_conv_b + mi * 512, xca);
            headwise_qkv<<<(NTOK * 512 + 255) / 256, 256, 0, stream>>>(xca, big0, m_q_w + mi * 2048, m_k_w + mi * 2048, m_v_w + mi * 2048, qb, kb, vb);
            mlstm_gates<<<NTOK * 2, 256, 0, stream>>>(qb, kb, vb, m_ig_w + mi * 6144, m_ig_b + mi * 4, m_fg_w + mi * 6144, m_fg_b + mi * 4, igo, fgo);
            mlstm_cumsum<<<1, 256, 0, stream>>>(fgo, igo, lfcb, Mxb);
            mlstm_attn<<<dim3((S_ + 3) / 4, 256), 256, 0, stream>>>(qb, kb, vb, igo, lfcb, Mxb, hatt);
            mhln_m<<<NTOK, 512, 0, stream>>>(hatt, m_outnorm + mi * 512);
            hstate_m<<<(NTOK * 512 + 255) / 256, 256, 0, stream>>>(hatt, xca, big0, m_skip + mi * 512);
            gemm64<<<dim3(256 / 64, NTOK / 64), 256, 0, stream>>>(hatt, m_proj_dn + (size_t)mi * 512 * 256, nullptr, h, NTOK, 512, 256, 1);
            mi++;
        }
    }

    postln_selu<<<NTOK, 256, 0, stream>>>(h, post_ln_w, lnb);
    pool_k<<<B_, 256, 0, stream>>>(lnb, pooled);
    heads_k<<<3, 256, 0, stream>>>(pooled, w_emo, b_emo, w_sen, b_sen, (float*)d_out);
}

// Round 3
// 4712.162 us; speedup vs baseline: 1.3360x; 1.3360x over previous
//
#include <hip/hip_runtime.h>
#include <hip/hip_bf16.h>
#include <math.h>

// AudioModelV3: 7-block xLSTM (blocks 1,4 = sLSTM+FFN; others mLSTM).
// R3: all dense GEMMs -> bf16 MFMA (fp32 accum); slstm_wx -> block-diag MFMA.
// Everything else (norms, gates, attention, recurrence) stays fp32.

#define B_    64
#define S_    199
#define E_    256
#define NTOK  (B_*S_)          // 12736 (= 199*64)

typedef __attribute__((ext_vector_type(8))) short short8;
typedef __attribute__((ext_vector_type(4))) float floatx4;

__device__ __forceinline__ float sigmoidf_(float x) { return 1.f / (1.f + expf(-x)); }
__device__ __forceinline__ float siluf_(float x) { return x / (1.f + expf(-x)); }
__device__ __forceinline__ float logsigf_(float x) { return fminf(x, 0.f) - log1pf(expf(-fabsf(x))); }

__device__ __forceinline__ unsigned short f2b(float f) {   // fp32 -> bf16 (RNE)
    union { float f; unsigned u; } v; v.f = f;
    unsigned r = (v.u + 0x7fffu + ((v.u >> 16) & 1u)) >> 16;
    return (unsigned short)r;
}

// ---------------- MFMA GEMM: C[M,N] = A[M,K] @ B[K,N] (+bias) (+=C) ----------
// 64x64 block tile, 4 waves in 2x2, each wave 2x2 of 16x16x32 MFMA tiles.
// A,B fp32 in global; converted to bf16 in LDS staging. fp32 accumulate.
// M%64==0, N%64==0, K%32==0. LDS rows padded to 40 shorts (80B): 2-way bank
// aliasing only (free per m136); 16B-aligned for ds_read_b128.
__global__ void __launch_bounds__(256)
gemm_mfma(const float* __restrict__ A, const float* __restrict__ Bw,
          const float* __restrict__ bias, float* __restrict__ C,
          int M, int K, int N, int accum) {
    __shared__ __align__(16) unsigned short As[64][40];
    __shared__ __align__(16) unsigned short Bs[64][40];
    int tid = threadIdx.x;
    int wave = tid >> 6, lane = tid & 63;
    int wm = wave >> 1, wn = wave & 1;
    int quad = lane >> 4, l16 = lane & 15;
    int m0 = blockIdx.y * 64, n0 = blockIdx.x * 64;
    floatx4 zero = {0.f, 0.f, 0.f, 0.f};
    floatx4 acc[2][2];
    acc[0][0] = zero; acc[0][1] = zero; acc[1][0] = zero; acc[1][1] = zero;
    int ar = tid >> 2, ac = (tid & 3) * 8;      // A stage: row, col8
    int bn = tid & 63, bk = (tid >> 6) * 8;     // B stage: n, k8
    for (int k0 = 0; k0 < K; k0 += 32) {
        {   // stage A 64x32: each thread 8 consecutive k of one row
            const float* ap = A + (size_t)(m0 + ar) * K + k0 + ac;
            union { unsigned short us[8]; uint4 v; } t;
            #pragma unroll
            for (int i = 0; i < 8; i++) t.us[i] = f2b(ap[i]);
            *(uint4*)&As[ar][ac] = t.v;
        }
        {   // stage B 32x64 transposed -> Bs[n][k]
            const float* bp = Bw + (size_t)(k0 + bk) * N + n0 + bn;
            union { unsigned short us[8]; uint4 v; } t;
            #pragma unroll
            for (int i = 0; i < 8; i++) t.us[i] = f2b(bp[(size_t)i * N]);
            *(uint4*)&Bs[bn][bk] = t.v;
        }
        __syncthreads();
        short8 af[2], bf[2];
        #pragma unroll
        for (int i = 0; i < 2; i++) af[i] = *(const short8*)&As[wm * 32 + i * 16 + l16][quad * 8];
        #pragma unroll
        for (int j = 0; j < 2; j++) bf[j] = *(const short8*)&Bs[wn * 32 + j * 16 + l16][quad * 8];
        #pragma unroll
        for (int i = 0; i < 2; i++)
            #pragma unroll
            for (int j = 0; j < 2; j++)
                acc[i][j] = __builtin_amdgcn_mfma_f32_16x16x32_bf16(af[i], bf[j], acc[i][j], 0, 0, 0);
        __syncthreads();
    }
    #pragma unroll
    for (int i = 0; i < 2; i++)
        #pragma unroll
        for (int j = 0; j < 2; j++)
            #pragma unroll
            for (int r = 0; r < 4; r++) {
                int row = m0 + wm * 32 + i * 16 + quad * 4 + r;
                int col = n0 + wn * 32 + j * 16 + l16;
                float o = acc[i][j][r];
                if (bias) o += bias[col];
                float* cp = &C[(size_t)row * N + col];
                if (accum) o += *cp;
                *cp = o;
            }
}

// ---------------- sLSTM Wx as block-diagonal MFMA GEMM -----------------------
// out[n,g*256+h*64+o] = sum_d src_g[n,h*64+d] * gw[g,h,o,d].  Per (g,h):
// M=NTOK,K=64,N=64; weight [o][d] is already the B^T ([n][k]) layout.
__global__ void __launch_bounds__(256)
slstm_wx_mfma(const float* __restrict__ xc, const float* __restrict__ xln,
              const float* __restrict__ gw, float* __restrict__ Wx) {
    __shared__ __align__(16) unsigned short As[64][40];
    __shared__ __align__(16) unsigned short Bs[64][40];
    int gh = blockIdx.y; int g = gh >> 2, hh = gh & 3;
    const float* src = (g < 2) ? xc : xln;
    const float* w = gw + (size_t)gh * 4096;    // [o][d] 64x64
    int tid = threadIdx.x;
    int wave = tid >> 6, lane = tid & 63;
    int wm = wave >> 1, wn = wave & 1;
    int quad = lane >> 4, l16 = lane & 15;
    int m0 = blockIdx.x * 64;
    floatx4 zero = {0.f, 0.f, 0.f, 0.f};
    floatx4 acc[2][2];
    acc[0][0] = zero; acc[0][1] = zero; acc[1][0] = zero; acc[1][1] = zero;
    int ar = tid >> 2, ac = (tid & 3) * 8;
    int bn = tid & 63, bk = (tid >> 6) * 8;
    #pragma unroll
    for (int kt = 0; kt < 2; kt++) {
        int k0 = kt * 32;
        {
            const float* ap = src + (size_t)(m0 + ar) * 256 + hh * 64 + k0 + ac;
            union { unsigned short us[8]; uint4 v; } t;
            #pragma unroll
            for (int i = 0; i < 8; i++) t.us[i] = f2b(ap[i]);
            *(uint4*)&As[ar][ac] = t.v;
        }
        {
            const float* bp = w + (size_t)bn * 64 + k0 + bk;
            union { unsigned short us[8]; uint4 v; } t;
            #pragma unroll
            for (int i = 0; i < 8; i++) t.us[i] = f2b(bp[i]);
            *(uint4*)&Bs[bn][bk] = t.v;
        }
        __syncthreads();
        short8 af[2], bf[2];
        #pragma unroll
        for (int i = 0; i < 2; i++) af[i] = *(const short8*)&As[wm * 32 + i * 16 + l16][quad * 8];
        #pragma unroll
        for (int j = 0; j < 2; j++) bf[j] = *(const short8*)&Bs[wn * 32 + j * 16 + l16][quad * 8];
        #pragma unroll
        for (int i = 0; i < 2; i++)
            #pragma unroll
            for (int j = 0; j < 2; j++)
                acc[i][j] = __builtin_amdgcn_mfma_f32_16x16x32_bf16(af[i], bf[j], acc[i][j], 0, 0, 0);
        __syncthreads();
    }
    #pragma unroll
    for (int i = 0; i < 2; i++)
        #pragma unroll
        for (int j = 0; j < 2; j++)
            #pragma unroll
            for (int r = 0; r < 4; r++) {
                int row = m0 + wm * 32 + i * 16 + quad * 4 + r;
                int col = wn * 32 + j * 16 + l16;
                Wx[(size_t)row * 1024 + g * 256 + hh * 64 + col] = acc[i][j][r];
            }
}

// ---------------- layernorm over 256 with weight -----------------------------
__global__ void __launch_bounds__(256)
layernorm256(const float* __restrict__ x, const float* __restrict__ w, float* __restrict__ y) {
    int n = blockIdx.x, t = threadIdx.x;
    float v = x[(size_t)n * 256 + t];
    float s = v, s2 = v * v;
    #pragma unroll
    for (int off = 32; off; off >>= 1) { s += __shfl_xor(s, off); s2 += __shfl_xor(s2, off); }
    __shared__ float ps[4], ps2[4];
    if ((t & 63) == 0) { ps[t >> 6] = s; ps2[t >> 6] = s2; }
    __syncthreads();
    float S = ps[0] + ps[1] + ps[2] + ps[3];
    float S2 = ps2[0] + ps2[1] + ps2[2] + ps2[3];
    float mu = S / 256.f, var = S2 / 256.f - mu * mu;
    y[(size_t)n * 256 + t] = (v - mu) * rsqrtf(var + 1e-5f) * w[t];
}

// ---------------- post-LN + selu --------------------------------------------
__global__ void __launch_bounds__(256)
postln_selu(const float* __restrict__ x, const float* __restrict__ w, float* __restrict__ y) {
    int n = blockIdx.x, t = threadIdx.x;
    float v = x[(size_t)n * 256 + t];
    float s = v, s2 = v * v;
    #pragma unroll
    for (int off = 32; off; off >>= 1) { s += __shfl_xor(s, off); s2 += __shfl_xor(s2, off); }
    __shared__ float ps[4], ps2[4];
    if ((t & 63) == 0) { ps[t >> 6] = s; ps2[t >> 6] = s2; }
    __syncthreads();
    float S = ps[0] + ps[1] + ps[2] + ps[3];
    float S2 = ps2[0] + ps2[1] + ps2[2] + ps2[3];
    float mu = S / 256.f, var = S2 / 256.f - mu * mu;
    float yn = (v - mu) * rsqrtf(var + 1e-5f) * w[t];
    y[(size_t)n * 256 + t] = 1.0507009873554805f * (yn > 0.f ? yn : 1.6732632423543772f * (expf(yn) - 1.f));
}

// ---------------- mLSTM: causal conv (512 ch) + silu -------------------------
__global__ void conv_silu_m(const float* __restrict__ xi, const float* __restrict__ cw,
                            const float* __restrict__ cb, float* __restrict__ xca) {
    int idx = blockIdx.x * blockDim.x + threadIdx.x;
    if (idx >= NTOK * 512) return;
    int n = idx >> 9, c = idx & 511;
    int b = n / S_, s = n - b * S_;
    float y = cb[c];
    #pragma unroll
    for (int i = 0; i < 4; i++) {
        int sp = s - 3 + i;
        if (sp >= 0) y += xi[(size_t)(b * S_ + sp) * 1024 + c] * cw[c * 4 + i];
    }
    xca[idx] = siluf_(y);
}

// ---------------- mLSTM: block-diagonal headwise q,k,v (128 heads of 4) ------
__global__ void headwise_qkv(const float* __restrict__ xca, const float* __restrict__ xi,
                             const float* __restrict__ qw, const float* __restrict__ kw,
                             const float* __restrict__ vw,
                             float* __restrict__ qb, float* __restrict__ kb, float* __restrict__ vb) {
    int idx = blockIdx.x * blockDim.x + threadIdx.x;
    if (idx >= NTOK * 512) return;
    int n = idx >> 9, c = idx & 511;
    int hh = c >> 2, o = c & 3;
    float aq = 0, ak = 0, av = 0;
    #pragma unroll
    for (int d = 0; d < 4; d++) {
        float xc = xca[(size_t)n * 512 + hh * 4 + d];
        float xm = xi[(size_t)n * 1024 + hh * 4 + d];
        int wi = (hh * 4 + o) * 4 + d;
        aq += xc * qw[wi]; ak += xc * kw[wi]; av += xm * vw[wi];
    }
    qb[idx] = aq; kb[idx] = ak; vb[idx] = av;
}

// ---------------- mLSTM: ig/fg gates (one wave per (n,head,which)) -----------
__global__ void __launch_bounds__(256)
mlstm_gates(const float* __restrict__ qb, const float* __restrict__ kb, const float* __restrict__ vb,
            const float* __restrict__ igw, const float* __restrict__ igbias,
            const float* __restrict__ fgw, const float* __restrict__ fgbias,
            float* __restrict__ igo, float* __restrict__ fgo) {
    int gid = blockIdx.x * 256 + threadIdx.x;
    int wid = gid >> 6, lane = gid & 63;
    int which = wid & 1, hd = (wid >> 1) & 3, n = wid >> 3;
    if (n >= NTOK) return;
    const float* w = (which ? fgw : igw) + hd * 1536;
    float a = 0.f;
    for (int j = lane; j < 512; j += 64) {
        a += qb[(size_t)n * 512 + j] * w[j]
           + kb[(size_t)n * 512 + j] * w[512 + j]
           + vb[(size_t)n * 512 + j] * w[1024 + j];
    }
    #pragma unroll
    for (int off = 32; off; off >>= 1) a += __shfl_xor(a, off);
    if (lane == 0) {
        a += (which ? fgbias : igbias)[hd];
        (which ? fgo : igo)[(size_t)n * 4 + hd] = a;
    }
}

// ---------------- mLSTM: cumsum of logsigmoid(fg) + prefix max ---------------
__global__ void mlstm_cumsum(const float* __restrict__ fgo, const float* __restrict__ igo,
                             float* __restrict__ lfc, float* __restrict__ Mx) {
    int t = threadIdx.x;           // 256 threads = (b,h)
    int b = t >> 2, h = t & 3;
    float* lf = lfc + (b * 4 + h) * (S_ + 1);
    float c = 0.f, mx = -1e30f;
    lf[0] = 0.f;
    for (int s = 0; s < S_; s++) {
        float f = fgo[(size_t)(b * S_ + s) * 4 + h];
        c += logsigf_(f);
        lf[s + 1] = c;
        float g = igo[(size_t)(b * S_ + s) * 4 + h] - c;
        mx = fmaxf(mx, g);
        Mx[(b * 4 + h) * S_ + s] = mx;
    }
}

// ---------------- mLSTM: attention, one wave per query row -------------------
__global__ void __launch_bounds__(256)
mlstm_attn(const float* __restrict__ qb, const float* __restrict__ kb, const float* __restrict__ vb,
           const float* __restrict__ igb, const float* __restrict__ lfc, const float* __restrict__ Mx,
           float* __restrict__ outb) {
    int wv = threadIdx.x >> 6, lane = threadIdx.x & 63;
    int s = blockIdx.x * 4 + wv;
    if (s >= S_) return;
    int bh = blockIdx.y; int b = bh >> 2, h = bh & 3;
    size_t rowq = (size_t)(b * S_ + s) * 512 + h * 128;
    float q0 = qb[rowq + lane], q1 = qb[rowq + 64 + lane];
    const float* lf = lfc + bh * (S_ + 1);
    float lfs = lf[s + 1];
    float maxD = lfs + Mx[bh * S_ + s];
    float rowsum = 0.f, a0 = 0.f, a1 = 0.f;
    const float scale = 0.08838834764831845f;   // 1/sqrt(128)
    for (int t = 0; t <= s; t++) {
        size_t rt = (size_t)(b * S_ + t) * 512 + h * 128;
        float p = q0 * kb[rt + lane] + q1 * kb[rt + 64 + lane];
        #pragma unroll
        for (int off = 32; off; off >>= 1) p += __shfl_xor(p, off);
        float Cst = p * scale * expf(lfs - lf[t + 1] + igb[(size_t)(b * S_ + t) * 4 + h] - maxD);
        rowsum += Cst;
        a0 += Cst * vb[rt + lane];
        a1 += Cst * vb[rt + 64 + lane];
    }
    float nrm = fmaxf(fabsf(rowsum), expf(-maxD)) + 1e-6f;
    outb[rowq + lane] = a0 / nrm;
    outb[rowq + 64 + lane] = a1 / nrm;
}

// ---------------- mLSTM: per-head (128) layernorm, weight 512, in place ------
__global__ void __launch_bounds__(512)
mhln_m(float* __restrict__ hatt, const float* __restrict__ w) {
    int n = blockIdx.x, t = threadIdx.x;
    float v = hatt[(size_t)n * 512 + t];
    float s = v, s2 = v * v;
    #pragma unroll
    for (int off = 32; off; off >>= 1) { s += __shfl_xor(s, off); s2 += __shfl_xor(s2, off); }
    __shared__ float ps[8], ps2[8];
    if ((t & 63) == 0) { ps[t >> 6] = s; ps2[t >> 6] = s2; }
    __syncthreads();
    int hd = t >> 7;
    float S = ps[hd * 2] + ps[hd * 2 + 1], S2 = ps2[hd * 2] + ps2[hd * 2 + 1];
    float mu = S / 128.f, var = S2 / 128.f - mu * mu;
    hatt[(size_t)n * 512 + t] = (v - mu) * rsqrtf(var + 1e-5f) * w[t];
}

// ---------------- mLSTM: h_state = (hn + skip*xca)*silu(z), in place ---------
__global__ void hstate_m(float* __restrict__ hatt, const float* __restrict__ xca,
                         const float* __restrict__ xi, const float* __restrict__ skip) {
    int idx = blockIdx.x * blockDim.x + threadIdx.x;
    if (idx >= NTOK * 512) return;
    int n = idx >> 9, c = idx & 511;
    float z = xi[(size_t)n * 1024 + 512 + c];
    hatt[idx] = (hatt[idx] + skip[c] * xca[idx]) * siluf_(z);
}

// ---------------- sLSTM: causal conv (256 ch) + silu -------------------------
__global__ void conv_silu_s(const float* __restrict__ xln, const float* __restrict__ cw,
                            const float* __restrict__ cb, float* __restrict__ xc) {
    int idx = blockIdx.x * blockDim.x + threadIdx.x;
    if (idx >= NTOK * 256) return;
    int n = idx >> 8, c = idx & 255;
    int b = n / S_, s = n - b * S_;
    float y = cb[c];
    #pragma unroll
    for (int i = 0; i < 4; i++) {
        int sp = s - 3 + i;
        if (sp >= 0) y += xln[(size_t)(b * S_ + sp) * 256 + c] * cw[c * 4 + i];
    }
    xc[idx] = siluf_(y);
}

// ---------------- sLSTM: recurrence, one block per (b,head) ------------------
__global__ void __launch_bounds__(256)
slstm_rec(const float* __restrict__ Wx, const float* __restrict__ rw,
          const float* __restrict__ bias, float* __restrict__ ys) {
    int b = blockIdx.x >> 2, h = blockIdx.x & 3;
    int tid = threadIdx.x;
    int g = tid >> 6, o = tid & 63;
    float w[64];
    const float* wp = rw + (size_t)(((g * 4 + h) * 64 + o)) * 64;
    #pragma unroll
    for (int d = 0; d < 64; d++) w[d] = wp[d];
    float bi = bias[(g * 4 + h) * 64 + o];
    __shared__ float hs[64];
    __shared__ float raws[256];
    if (tid < 64) hs[tid] = 0.f;
    float c_ = 0.f, n_ = 0.f, m_ = 0.f;
    __syncthreads();
    for (int s = 0; s < S_; s++) {
        float acc = Wx[(size_t)(b * S_ + s) * 1024 + g * 256 + h * 64 + o] + bi;
        #pragma unroll
        for (int d = 0; d < 64; d++) acc += hs[d] * w[d];
        raws[tid] = acc;
        __syncthreads();
        if (tid < 64) {
            float ir = raws[tid], fr = raws[64 + tid], zr = raws[128 + tid], orr = raws[192 + tid];
            float lfpm = m_ + logsigf_(fr);
            float mn = fmaxf(ir, lfpm);
            float ig = expf(ir - mn), fg = expf(lfpm - mn);
            c_ = fg * c_ + ig * tanhf(zr);
            n_ = fg * n_ + ig;
            m_ = mn;
            float hn = sigmoidf_(orr) * (c_ / n_);
            hs[tid] = hn;
            ys[(size_t)(b * S_ + s) * 256 + h * 64 + tid] = hn;
        }
        __syncthreads();
    }
}

// ---------------- sLSTM: per-head (64) groupnorm + residual add --------------
__global__ void __launch_bounds__(256)
mhln_s_resid(const float* __restrict__ ys, const float* __restrict__ w, float* __restrict__ h) {
    int n = blockIdx.x, t = threadIdx.x;   // wave == head (64 dims)
    float v = ys[(size_t)n * 256 + t];
    float s = v, s2 = v * v;
    #pragma unroll
    for (int off = 32; off; off >>= 1) { s += __shfl_xor(s, off); s2 += __shfl_xor(s2, off); }
    float mu = s / 64.f, var = s2 / 64.f - mu * mu;
    h[(size_t)n * 256 + t] += (v - mu) * rsqrtf(var + 1e-5f) * w[t];
}

// ---------------- FFN: gelu(gate)*up -----------------------------------------
__global__ void ffn_act(const float* __restrict__ up, float* __restrict__ act) {
    int idx = blockIdx.x * blockDim.x + threadIdx.x;
    if (idx >= NTOK * 384) return;
    int n = idx / 384, j = idx - n * 384;
    float g = up[(size_t)n * 768 + j], u = up[(size_t)n * 768 + 384 + j];
    float t = tanhf(0.7978845608028654f * (g + 0.044715f * g * g * g));
    act[idx] = 0.5f * g * (1.f + t) * u;
}

// ---------------- pooling + heads --------------------------------------------
__global__ void pool_k(const float* __restrict__ a, float* __restrict__ pooled) {
    int b = blockIdx.x, e = threadIdx.x;
    float s = 0.f;
    for (int t = 0; t < S_; t++) s += a[(size_t)(b * S_ + t) * 256 + e];
    pooled[b * 256 + e] = s / (float)S_;
}

__global__ void heads_k(const float* __restrict__ pooled,
                        const float* __restrict__ we, const float* __restrict__ be,
                        const float* __restrict__ ws, const float* __restrict__ bs,
                        float* __restrict__ out) {
    int i = blockIdx.x * blockDim.x + threadIdx.x;
    if (i < B_ * 7) {
        int b = i / 7, o = i - b * 7;
        float a = be[o];
        for (int e = 0; e < 256; e++) a += pooled[b * 256 + e] * we[e * 7 + o];
        out[b * 7 + o] = a;
    } else if (i < B_ * 7 + B_ * 3) {
        int j = i - B_ * 7;
        int b = j / 3, o = j - b * 3;
        float a = bs[o];
        for (int e = 0; e < 256; e++) a += pooled[b * 256 + e] * ws[e * 3 + o];
        out[B_ * 7 + b * 3 + o] = a;
    }
}

// =============================================================================
extern "C" void kernel_launch(void* const* d_in, const int* in_sizes, int n_in,
                              void* d_out, int out_size, void* d_ws, size_t ws_size,
                              hipStream_t stream) {
    (void)in_sizes; (void)n_in; (void)out_size; (void)ws_size;
    const float* x          = (const float*)d_in[0];
    const float* w_down     = (const float*)d_in[1];
    const float* b_down     = (const float*)d_in[2];
    const float* m_ln_w     = (const float*)d_in[3];
    const float* m_proj_up  = (const float*)d_in[4];
    const float* m_conv_w   = (const float*)d_in[5];
    const float* m_conv_b   = (const float*)d_in[6];
    const float* m_q_w      = (const float*)d_in[7];
    const float* m_k_w      = (const float*)d_in[8];
    const float* m_v_w      = (const float*)d_in[9];
    const float* m_ig_w     = (const float*)d_in[10];
    const float* m_ig_b     = (const float*)d_in[11];
    const float* m_fg_w     = (const float*)d_in[12];
    const float* m_fg_b     = (const float*)d_in[13];
    const float* m_skip     = (const float*)d_in[14];
    const float* m_outnorm  = (const float*)d_in[15];
    const float* m_proj_dn  = (const float*)d_in[16];
    const float* s_ln_w     = (const float*)d_in[17];
    const float* s_conv_w   = (const float*)d_in[18];
    const float* s_conv_b   = (const float*)d_in[19];
    const float* s_gate_w   = (const float*)d_in[20];
    const float* s_rec_w    = (const float*)d_in[21];
    const float* s_bias     = (const float*)d_in[22];
    const float* s_gn_w     = (const float*)d_in[23];
    const float* s_ln2_w    = (const float*)d_in[24];
    const float* s_ffn_up   = (const float*)d_in[25];
    const float* s_ffn_dn   = (const float*)d_in[26];
    const float* post_ln_w  = (const float*)d_in[27];
    const float* w_emo      = (const float*)d_in[28];
    const float* b_emo      = (const float*)d_in[29];
    const float* w_sen      = (const float*)d_in[30];
    const float* b_sen      = (const float*)d_in[31];

    float* W    = (float*)d_ws;
    float* h    = W;                                   // NTOK*256
    float* lnb  = h    + (size_t)NTOK * 256;           // NTOK*256
    float* big0 = lnb  + (size_t)NTOK * 256;           // NTOK*1024 (xi / Wx / ffn-up)
    float* xca  = big0 + (size_t)NTOK * 1024;          // NTOK*512  (conv out)
    float* qb   = xca  + (size_t)NTOK * 512;           // NTOK*512
    float* kb   = qb   + (size_t)NTOK * 512;           // NTOK*512
    float* vb   = kb   + (size_t)NTOK * 512;           // NTOK*512
    float* hatt = vb   + (size_t)NTOK * 512;           // NTOK*512  (attn out / ys / ffn-act)
    float* igo  = hatt + (size_t)NTOK * 512;           // NTOK*4
    float* fgo  = igo  + (size_t)NTOK * 4;             // NTOK*4
    float* lfcb = fgo  + (size_t)NTOK * 4;             // 256*(S+1)
    float* Mxb  = lfcb + (size_t)256 * (S_ + 1);       // 256*S
    float* pooled = Mxb + (size_t)256 * S_;            // 64*256

    // embed: h = x @ w_down + b_down
    gemm_mfma<<<dim3(256 / 64, NTOK / 64), 256, 0, stream>>>(x, w_down, b_down, h, NTOK, 1024, 256, 0);

    int mi = 0, si = 0;
    for (int blk = 0; blk < 7; blk++) {
        if (blk == 1 || blk == 4) {
            // ---- sLSTM block ----
            layernorm256<<<NTOK, 256, 0, stream>>>(h, s_ln_w + si * 256, lnb);
            conv_silu_s<<<(NTOK * 256 + 255) / 256, 256, 0, stream>>>(lnb, s_conv_w + si * 1024, s_conv_b + si * 256, xca);
            slstm_wx_mfma<<<dim3(NTOK / 64, 16), 256, 0, stream>>>(xca, lnb, s_gate_w + (size_t)si * 65536, big0);
            slstm_rec<<<256, 256, 0, stream>>>(big0, s_rec_w + (size_t)si * 65536, s_bias + si * 1024, hatt);
            mhln_s_resid<<<NTOK, 256, 0, stream>>>(hatt, s_gn_w + si * 256, h);
            // ---- FFN ----
            layernorm256<<<NTOK, 256, 0, stream>>>(h, s_ln2_w + si * 256, lnb);
            gemm_mfma<<<dim3(768 / 64, NTOK / 64), 256, 0, stream>>>(lnb, s_ffn_up + (size_t)si * 256 * 768, nullptr, big0, NTOK, 256, 768, 0);
            ffn_act<<<(NTOK * 384 + 255) / 256, 256, 0, stream>>>(big0, hatt);
            gemm_mfma<<<dim3(256 / 64, NTOK / 64), 256, 0, stream>>>(hatt, s_ffn_dn + (size_t)si * 384 * 256, nullptr, h, NTOK, 384, 256, 1);
            si++;
        } else {
            // ---- mLSTM block ----
            layernorm256<<<NTOK, 256, 0, stream>>>(h, m_ln_w + mi * 256, lnb);
            gemm_mfma<<<dim3(1024 / 64, NTOK / 64), 256, 0, stream>>>(lnb, m_proj_up + (size_t)mi * 256 * 1024, nullptr, big0, NTOK, 256, 1024, 0);
            conv_silu_m<<<(NTOK * 512 + 255) / 256, 256, 0, stream>>>(big0, m_conv_w + mi * 2048, m_conv_b + mi * 512, xca);
            headwise_qkv<<<(NTOK * 512 + 255) / 256, 256, 0, stream>>>(xca, big0, m_q_w + mi * 2048, m_k_w + mi * 2048, m_v_w + mi * 2048, qb, kb, vb);
            mlstm_gates<<<NTOK * 2, 256, 0, stream>>>(qb, kb, vb, m_ig_w + mi * 6144, m_ig_b + mi * 4, m_fg_w + mi * 6144, m_fg_b + mi * 4, igo, fgo);
            mlstm_cumsum<<<1, 256, 0, stream>>>(fgo, igo, lfcb, Mxb);
            mlstm_attn<<<dim3((S_ + 3) / 4, 256), 256, 0, stream>>>(qb, kb, vb, igo, lfcb, Mxb, hatt);
            mhln_m<<<NTOK, 512, 0, stream>>>(hatt, m_outnorm + mi * 512);
            hstate_m<<<(NTOK * 512 + 255) / 256, 256, 0, stream>>>(hatt, xca, big0, m_skip + mi * 512);
            gemm_mfma<<<dim3(256 / 64, NTOK / 64), 256, 0, stream>>>(hatt, m_proj_dn + (size_t)mi * 512 * 256, nullptr, h, NTOK, 512, 256, 1);
            mi++;
        }
    }

    postln_selu<<<NTOK, 256, 0, stream>>>(h, post_ln_w, lnb);
    pool_k<<<B_, 256, 0, stream>>>(lnb, pooled);
    heads_k<<<3, 256, 0, stream>>>(pooled, w_emo, b_emo, w_sen, b_sen, (float*)d_out);
}

// Round 4
// 3136.654 us; speedup vs baseline: 2.0071x; 1.5023x over previous
//
#include <hip/hip_runtime.h>
#include <hip/hip_bf16.h>
#include <math.h>

// AudioModelV3: 7-block xLSTM (blocks 1,4 = sLSTM+FFN; others mLSTM).
// R4: mLSTM attention -> chunked MFMA flash-style kernel (one block per (b,h)).
// Decay weights: exp(lfs - lf[t+1] + ig[t] - maxD) == exp(g[t] - Mx[s]); norm
// is a per-row scalar applied after PV (linear), so no online rescaling.

#define B_    64
#define S_    199
#define E_    256
#define NTOK  (B_*S_)          // 12736 (= 199*64)
#define NQT   13               // ceil(199/16)

typedef __attribute__((ext_vector_type(8))) short short8;
typedef __attribute__((ext_vector_type(4))) float floatx4;

__device__ __forceinline__ float sigmoidf_(float x) { return 1.f / (1.f + expf(-x)); }
__device__ __forceinline__ float siluf_(float x) { return x / (1.f + expf(-x)); }
__device__ __forceinline__ float logsigf_(float x) { return fminf(x, 0.f) - log1pf(expf(-fabsf(x))); }

__device__ __forceinline__ unsigned short f2b(float f) {   // fp32 -> bf16 (RNE)
    union { float f; unsigned u; } v; v.f = f;
    unsigned r = (v.u + 0x7fffu + ((v.u >> 16) & 1u)) >> 16;
    return (unsigned short)r;
}
__device__ __forceinline__ short8 cvt8(const float* p) {
    union { unsigned short us[8]; short8 v; } t;
    #pragma unroll
    for (int i = 0; i < 8; i++) t.us[i] = f2b(p[i]);
    return t.v;
}

// ---------------- MFMA GEMM: C[M,N] = A[M,K] @ B[K,N] (+bias) (+=C) ----------
__global__ void __launch_bounds__(256)
gemm_mfma(const float* __restrict__ A, const float* __restrict__ Bw,
          const float* __restrict__ bias, float* __restrict__ C,
          int M, int K, int N, int accum) {
    __shared__ __align__(16) unsigned short As[64][40];
    __shared__ __align__(16) unsigned short Bs[64][40];
    int tid = threadIdx.x;
    int wave = tid >> 6, lane = tid & 63;
    int wm = wave >> 1, wn = wave & 1;
    int quad = lane >> 4, l16 = lane & 15;
    int m0 = blockIdx.y * 64, n0 = blockIdx.x * 64;
    floatx4 zero = {0.f, 0.f, 0.f, 0.f};
    floatx4 acc[2][2];
    acc[0][0] = zero; acc[0][1] = zero; acc[1][0] = zero; acc[1][1] = zero;
    int ar = tid >> 2, ac = (tid & 3) * 8;
    int bn = tid & 63, bk = (tid >> 6) * 8;
    for (int k0 = 0; k0 < K; k0 += 32) {
        {
            const float* ap = A + (size_t)(m0 + ar) * K + k0 + ac;
            union { unsigned short us[8]; uint4 v; } t;
            #pragma unroll
            for (int i = 0; i < 8; i++) t.us[i] = f2b(ap[i]);
            *(uint4*)&As[ar][ac] = t.v;
        }
        {
            const float* bp = Bw + (size_t)(k0 + bk) * N + n0 + bn;
            union { unsigned short us[8]; uint4 v; } t;
            #pragma unroll
            for (int i = 0; i < 8; i++) t.us[i] = f2b(bp[(size_t)i * N]);
            *(uint4*)&Bs[bn][bk] = t.v;
        }
        __syncthreads();
        short8 af[2], bf[2];
        #pragma unroll
        for (int i = 0; i < 2; i++) af[i] = *(const short8*)&As[wm * 32 + i * 16 + l16][quad * 8];
        #pragma unroll
        for (int j = 0; j < 2; j++) bf[j] = *(const short8*)&Bs[wn * 32 + j * 16 + l16][quad * 8];
        #pragma unroll
        for (int i = 0; i < 2; i++)
            #pragma unroll
            for (int j = 0; j < 2; j++)
                acc[i][j] = __builtin_amdgcn_mfma_f32_16x16x32_bf16(af[i], bf[j], acc[i][j], 0, 0, 0);
        __syncthreads();
    }
    #pragma unroll
    for (int i = 0; i < 2; i++)
        #pragma unroll
        for (int j = 0; j < 2; j++)
            #pragma unroll
            for (int r = 0; r < 4; r++) {
                int row = m0 + wm * 32 + i * 16 + quad * 4 + r;
                int col = n0 + wn * 32 + j * 16 + l16;
                float o = acc[i][j][r];
                if (bias) o += bias[col];
                float* cp = &C[(size_t)row * N + col];
                if (accum) o += *cp;
                *cp = o;
            }
}

// ---------------- sLSTM Wx as block-diagonal MFMA GEMM -----------------------
__global__ void __launch_bounds__(256)
slstm_wx_mfma(const float* __restrict__ xc, const float* __restrict__ xln,
              const float* __restrict__ gw, float* __restrict__ Wx) {
    __shared__ __align__(16) unsigned short As[64][40];
    __shared__ __align__(16) unsigned short Bs[64][40];
    int gh = blockIdx.y; int g = gh >> 2, hh = gh & 3;
    const float* src = (g < 2) ? xc : xln;
    const float* w = gw + (size_t)gh * 4096;
    int tid = threadIdx.x;
    int wave = tid >> 6, lane = tid & 63;
    int wm = wave >> 1, wn = wave & 1;
    int quad = lane >> 4, l16 = lane & 15;
    int m0 = blockIdx.x * 64;
    floatx4 zero = {0.f, 0.f, 0.f, 0.f};
    floatx4 acc[2][2];
    acc[0][0] = zero; acc[0][1] = zero; acc[1][0] = zero; acc[1][1] = zero;
    int ar = tid >> 2, ac = (tid & 3) * 8;
    int bn = tid & 63, bk = (tid >> 6) * 8;
    #pragma unroll
    for (int kt = 0; kt < 2; kt++) {
        int k0 = kt * 32;
        {
            const float* ap = src + (size_t)(m0 + ar) * 256 + hh * 64 + k0 + ac;
            union { unsigned short us[8]; uint4 v; } t;
            #pragma unroll
            for (int i = 0; i < 8; i++) t.us[i] = f2b(ap[i]);
            *(uint4*)&As[ar][ac] = t.v;
        }
        {
            const float* bp = w + (size_t)bn * 64 + k0 + bk;
            union { unsigned short us[8]; uint4 v; } t;
            #pragma unroll
            for (int i = 0; i < 8; i++) t.us[i] = f2b(bp[i]);
            *(uint4*)&Bs[bn][bk] = t.v;
        }
        __syncthreads();
        short8 af[2], bf[2];
        #pragma unroll
        for (int i = 0; i < 2; i++) af[i] = *(const short8*)&As[wm * 32 + i * 16 + l16][quad * 8];
        #pragma unroll
        for (int j = 0; j < 2; j++) bf[j] = *(const short8*)&Bs[wn * 32 + j * 16 + l16][quad * 8];
        #pragma unroll
        for (int i = 0; i < 2; i++)
            #pragma unroll
            for (int j = 0; j < 2; j++)
                acc[i][j] = __builtin_amdgcn_mfma_f32_16x16x32_bf16(af[i], bf[j], acc[i][j], 0, 0, 0);
        __syncthreads();
    }
    #pragma unroll
    for (int i = 0; i < 2; i++)
        #pragma unroll
        for (int j = 0; j < 2; j++)
            #pragma unroll
            for (int r = 0; r < 4; r++) {
                int row = m0 + wm * 32 + i * 16 + quad * 4 + r;
                int col = wn * 32 + j * 16 + l16;
                Wx[(size_t)row * 1024 + g * 256 + hh * 64 + col] = acc[i][j][r];
            }
}

// ---------------- layernorm over 256 with weight -----------------------------
__global__ void __launch_bounds__(256)
layernorm256(const float* __restrict__ x, const float* __restrict__ w, float* __restrict__ y) {
    int n = blockIdx.x, t = threadIdx.x;
    float v = x[(size_t)n * 256 + t];
    float s = v, s2 = v * v;
    #pragma unroll
    for (int off = 32; off; off >>= 1) { s += __shfl_xor(s, off); s2 += __shfl_xor(s2, off); }
    __shared__ float ps[4], ps2[4];
    if ((t & 63) == 0) { ps[t >> 6] = s; ps2[t >> 6] = s2; }
    __syncthreads();
    float S = ps[0] + ps[1] + ps[2] + ps[3];
    float S2 = ps2[0] + ps2[1] + ps2[2] + ps2[3];
    float mu = S / 256.f, var = S2 / 256.f - mu * mu;
    y[(size_t)n * 256 + t] = (v - mu) * rsqrtf(var + 1e-5f) * w[t];
}

// ---------------- post-LN + selu --------------------------------------------
__global__ void __launch_bounds__(256)
postln_selu(const float* __restrict__ x, const float* __restrict__ w, float* __restrict__ y) {
    int n = blockIdx.x, t = threadIdx.x;
    float v = x[(size_t)n * 256 + t];
    float s = v, s2 = v * v;
    #pragma unroll
    for (int off = 32; off; off >>= 1) { s += __shfl_xor(s, off); s2 += __shfl_xor(s2, off); }
    __shared__ float ps[4], ps2[4];
    if ((t & 63) == 0) { ps[t >> 6] = s; ps2[t >> 6] = s2; }
    __syncthreads();
    float S = ps[0] + ps[1] + ps[2] + ps[3];
    float S2 = ps2[0] + ps2[1] + ps2[2] + ps2[3];
    float mu = S / 256.f, var = S2 / 256.f - mu * mu;
    float yn = (v - mu) * rsqrtf(var + 1e-5f) * w[t];
    y[(size_t)n * 256 + t] = 1.0507009873554805f * (yn > 0.f ? yn : 1.6732632423543772f * (expf(yn) - 1.f));
}

// ---------------- mLSTM: causal conv (512 ch) + silu -------------------------
__global__ void conv_silu_m(const float* __restrict__ xi, const float* __restrict__ cw,
                            const float* __restrict__ cb, float* __restrict__ xca) {
    int idx = blockIdx.x * blockDim.x + threadIdx.x;
    if (idx >= NTOK * 512) return;
    int n = idx >> 9, c = idx & 511;
    int b = n / S_, s = n - b * S_;
    float y = cb[c];
    #pragma unroll
    for (int i = 0; i < 4; i++) {
        int sp = s - 3 + i;
        if (sp >= 0) y += xi[(size_t)(b * S_ + sp) * 1024 + c] * cw[c * 4 + i];
    }
    xca[idx] = siluf_(y);
}

// ---------------- mLSTM: block-diagonal headwise q,k,v -----------------------
__global__ void headwise_qkv(const float* __restrict__ xca, const float* __restrict__ xi,
                             const float* __restrict__ qw, const float* __restrict__ kw,
                             const float* __restrict__ vw,
                             float* __restrict__ qb, float* __restrict__ kb, float* __restrict__ vb) {
    int idx = blockIdx.x * blockDim.x + threadIdx.x;
    if (idx >= NTOK * 512) return;
    int n = idx >> 9, c = idx & 511;
    int hh = c >> 2, o = c & 3;
    float aq = 0, ak = 0, av = 0;
    #pragma unroll
    for (int d = 0; d < 4; d++) {
        float xc = xca[(size_t)n * 512 + hh * 4 + d];
        float xm = xi[(size_t)n * 1024 + hh * 4 + d];
        int wi = (hh * 4 + o) * 4 + d;
        aq += xc * qw[wi]; ak += xc * kw[wi]; av += xm * vw[wi];
    }
    qb[idx] = aq; kb[idx] = ak; vb[idx] = av;
}

// ---------------- mLSTM: ig/fg gates -----------------------------------------
__global__ void __launch_bounds__(256)
mlstm_gates(const float* __restrict__ qb, const float* __restrict__ kb, const float* __restrict__ vb,
            const float* __restrict__ igw, const float* __restrict__ igbias,
            const float* __restrict__ fgw, const float* __restrict__ fgbias,
            float* __restrict__ igo, float* __restrict__ fgo) {
    int gid = blockIdx.x * 256 + threadIdx.x;
    int wid = gid >> 6, lane = gid & 63;
    int which = wid & 1, hd = (wid >> 1) & 3, n = wid >> 3;
    if (n >= NTOK) return;
    const float* w = (which ? fgw : igw) + hd * 1536;
    float a = 0.f;
    for (int j = lane; j < 512; j += 64) {
        a += qb[(size_t)n * 512 + j] * w[j]
           + kb[(size_t)n * 512 + j] * w[512 + j]
           + vb[(size_t)n * 512 + j] * w[1024 + j];
    }
    #pragma unroll
    for (int off = 32; off; off >>= 1) a += __shfl_xor(a, off);
    if (lane == 0) {
        a += (which ? fgbias : igbias)[hd];
        (which ? fgo : igo)[(size_t)n * 4 + hd] = a;
    }
}

// ---------------- mLSTM: cumsum of logsigmoid(fg) + prefix max ---------------
__global__ void mlstm_cumsum(const float* __restrict__ fgo, const float* __restrict__ igo,
                             float* __restrict__ lfc, float* __restrict__ Mx) {
    int t = threadIdx.x;           // 256 threads = (b,h)
    int b = t >> 2, h = t & 3;
    float* lf = lfc + (b * 4 + h) * (S_ + 1);
    float c = 0.f, mx = -1e30f;
    lf[0] = 0.f;
    for (int s = 0; s < S_; s++) {
        float f = fgo[(size_t)(b * S_ + s) * 4 + h];
        c += logsigf_(f);
        lf[s + 1] = c;
        float g = igo[(size_t)(b * S_ + s) * 4 + h] - c;
        mx = fmaxf(mx, g);
        Mx[(b * 4 + h) * S_ + s] = mx;
    }
}

// ---------------- mLSTM attention: MFMA flash-style, one block per (b,h) -----
// Scores: D[s][t] = (Q K^T)/sqrt(128) * exp(g[t]-Mx[s]) (causal); rowsum ->
// nrm after all chunks; PV accumulated unnormalized; divide at store.
__global__ void __launch_bounds__(256, 1)
mlstm_attn_mfma(const float* __restrict__ qb, const float* __restrict__ kb, const float* __restrict__ vb,
                const float* __restrict__ igb, const float* __restrict__ lfc, const float* __restrict__ Mx,
                float* __restrict__ outb) {
    __shared__ __align__(16) unsigned short Kb[64 * 136];   // [t_local][d], pad 136
    __shared__ __align__(16) unsigned short Vt[128 * 72];   // [d][t_local], pad 72
    __shared__ __align__(16) unsigned short Pw[4][16 * 72]; // per-wave P tile
    __shared__ float gv[208], lfv[208], mxv[208];
    int bh = blockIdx.x; int b = bh >> 2, h = bh & 3;
    int tid = threadIdx.x, wave = tid >> 6, lane = tid & 63;
    int quad = lane >> 4, l16 = lane & 15;
    if (tid < 208) {
        if (tid < S_) {
            float lf1 = lfc[bh * (S_ + 1) + tid + 1];
            gv[tid] = igb[(size_t)(b * S_ + tid) * 4 + h] - lf1;
            lfv[tid] = lf1;
            mxv[tid] = Mx[bh * S_ + tid];
        } else { gv[tid] = 0.f; lfv[tid] = 0.f; mxv[tid] = 0.f; }
    }
    floatx4 zero = {0.f, 0.f, 0.f, 0.f};
    float rs[4][4];
    floatx4 accv[4][8];
    #pragma unroll
    for (int qi = 0; qi < 4; qi++) {
        #pragma unroll
        for (int r = 0; r < 4; r++) rs[qi][r] = 0.f;
        #pragma unroll
        for (int dt = 0; dt < 8; dt++) accv[qi][dt] = zero;
    }
    const float scale = 0.08838834764831845f;   // 1/sqrt(128)
    int trow = tid >> 4, d0 = (tid & 15) * 8;
    for (int c = 0; c < 4; c++) {
        __syncthreads();
        #pragma unroll
        for (int i = 0; i < 4; i++) {           // stage K,V chunk (64 t-steps)
            int tl = trow + 16 * i;
            int t = c * 64 + tl;
            union { unsigned short us[8]; uint4 v; } kk;
            unsigned short vv[8];
            if (t < S_) {
                const float* kp = kb + (size_t)(b * S_ + t) * 512 + h * 128 + d0;
                const float* vp = vb + (size_t)(b * S_ + t) * 512 + h * 128 + d0;
                #pragma unroll
                for (int ii = 0; ii < 8; ii++) { kk.us[ii] = f2b(kp[ii]); vv[ii] = f2b(vp[ii]); }
            } else {
                kk.v = (uint4){0, 0, 0, 0};
                #pragma unroll
                for (int ii = 0; ii < 8; ii++) vv[ii] = 0;
            }
            *(uint4*)&Kb[tl * 136 + d0] = kk.v;
            #pragma unroll
            for (int ii = 0; ii < 8; ii++) Vt[(d0 + ii) * 72 + tl] = vv[ii];
        }
        __syncthreads();
        for (int qi = 0; qi < 4; qi++) {
            int qt = wave + 4 * qi;
            if (qt >= NQT || qt < 4 * c) continue;   // causal: chunk c serves qt >= 4c
            // zero this wave's P tile (16x72 shorts = 144 uint4)
            uint4 z4 = {0, 0, 0, 0};
            for (int z = lane; z < 144; z += 64) ((uint4*)Pw[wave])[z] = z4;
            // Q fragments (A-layout, clamped row)
            int srow = qt * 16 + l16;
            const float* qp = qb + (size_t)(b * S_ + min(srow, S_ - 1)) * 512 + h * 128 + quad * 8;
            short8 af[4];
            #pragma unroll
            for (int ks = 0; ks < 4; ks++) af[ks] = cvt8(qp + 32 * ks);
            int ktmax_l = min(qt, 4 * c + 3) - 4 * c;
            for (int ktl = 0; ktl <= ktmax_l; ktl++) {
                floatx4 acc = zero;
                #pragma unroll
                for (int ks = 0; ks < 4; ks++) {
                    short8 bf = *(const short8*)&Kb[(ktl * 16 + l16) * 136 + quad * 8 + 32 * ks];
                    acc = __builtin_amdgcn_mfma_f32_16x16x32_bf16(af[ks], bf, acc, 0, 0, 0);
                }
                int tcol = c * 64 + ktl * 16 + l16;   // <= 207
                float gt = gv[tcol];
                #pragma unroll
                for (int r = 0; r < 4; r++) {
                    int s = qt * 16 + quad * 4 + r;    // <= 207
                    bool valid = (tcol <= s) && (tcol < S_);
                    float w = valid ? expf(gt - mxv[s]) : 0.f;
                    float p = acc[r] * scale * w;
                    rs[qi][r] += p;
                    Pw[wave][(quad * 4 + r) * 72 + ktl * 16 + l16] = f2b(p);
                }
            }
            // PV partial for this chunk (same-wave LDS RAW: in-order per wave)
            #pragma unroll
            for (int dt = 0; dt < 8; dt++) {
                floatx4 a = accv[qi][dt];
                #pragma unroll
                for (int ks = 0; ks < 2; ks++) {
                    short8 ap = *(const short8*)&Pw[wave][l16 * 72 + quad * 8 + 32 * ks];
                    short8 bp = *(const short8*)&Vt[(dt * 16 + l16) * 72 + quad * 8 + 32 * ks];
                    a = __builtin_amdgcn_mfma_f32_16x16x32_bf16(ap, bp, a, 0, 0, 0);
                }
                accv[qi][dt] = a;
            }
        }
    }
    // reduce rowsums across the 16 lanes of each quad, normalize, store
    for (int qi = 0; qi < 4; qi++) {
        int qt = wave + 4 * qi;
        if (qt >= NQT) continue;
        float nrm[4];
        #pragma unroll
        for (int r = 0; r < 4; r++) {
            float v = rs[qi][r];
            v += __shfl_xor(v, 1); v += __shfl_xor(v, 2);
            v += __shfl_xor(v, 4); v += __shfl_xor(v, 8);
            int s = qt * 16 + quad * 4 + r;
            nrm[r] = fmaxf(fabsf(v), expf(-(lfv[s] + mxv[s]))) + 1e-6f;
        }
        #pragma unroll
        for (int dt = 0; dt < 8; dt++)
            #pragma unroll
            for (int r = 0; r < 4; r++) {
                int s = qt * 16 + quad * 4 + r;
                if (s < S_)
                    outb[(size_t)(b * S_ + s) * 512 + h * 128 + dt * 16 + l16] = accv[qi][dt][r] / nrm[r];
            }
    }
}

// ---------------- mLSTM: per-head (128) layernorm, in place ------------------
__global__ void __launch_bounds__(512)
mhln_m(float* __restrict__ hatt, const float* __restrict__ w) {
    int n = blockIdx.x, t = threadIdx.x;
    float v = hatt[(size_t)n * 512 + t];
    float s = v, s2 = v * v;
    #pragma unroll
    for (int off = 32; off; off >>= 1) { s += __shfl_xor(s, off); s2 += __shfl_xor(s2, off); }
    __shared__ float ps[8], ps2[8];
    if ((t & 63) == 0) { ps[t >> 6] = s; ps2[t >> 6] = s2; }
    __syncthreads();
    int hd = t >> 7;
    float S = ps[hd * 2] + ps[hd * 2 + 1], S2 = ps2[hd * 2] + ps2[hd * 2 + 1];
    float mu = S / 128.f, var = S2 / 128.f - mu * mu;
    hatt[(size_t)n * 512 + t] = (v - mu) * rsqrtf(var + 1e-5f) * w[t];
}

// ---------------- mLSTM: h_state = (hn + skip*xca)*silu(z) -------------------
__global__ void hstate_m(float* __restrict__ hatt, const float* __restrict__ xca,
                         const float* __restrict__ xi, const float* __restrict__ skip) {
    int idx = blockIdx.x * blockDim.x + threadIdx.x;
    if (idx >= NTOK * 512) return;
    int n = idx >> 9, c = idx & 511;
    float z = xi[(size_t)n * 1024 + 512 + c];
    hatt[idx] = (hatt[idx] + skip[c] * xca[idx]) * siluf_(z);
}

// ---------------- sLSTM: causal conv (256 ch) + silu -------------------------
__global__ void conv_silu_s(const float* __restrict__ xln, const float* __restrict__ cw,
                            const float* __restrict__ cb, float* __restrict__ xc) {
    int idx = blockIdx.x * blockDim.x + threadIdx.x;
    if (idx >= NTOK * 256) return;
    int n = idx >> 8, c = idx & 255;
    int b = n / S_, s = n - b * S_;
    float y = cb[c];
    #pragma unroll
    for (int i = 0; i < 4; i++) {
        int sp = s - 3 + i;
        if (sp >= 0) y += xln[(size_t)(b * S_ + sp) * 256 + c] * cw[c * 4 + i];
    }
    xc[idx] = siluf_(y);
}

// ---------------- sLSTM: recurrence, one block per (b,head) ------------------
__global__ void __launch_bounds__(256)
slstm_rec(const float* __restrict__ Wx, const float* __restrict__ rw,
          const float* __restrict__ bias, float* __restrict__ ys) {
    int b = blockIdx.x >> 2, h = blockIdx.x & 3;
    int tid = threadIdx.x;
    int g = tid >> 6, o = tid & 63;
    float w[64];
    const float* wp = rw + (size_t)(((g * 4 + h) * 64 + o)) * 64;
    #pragma unroll
    for (int d = 0; d < 64; d++) w[d] = wp[d];
    float bi = bias[(g * 4 + h) * 64 + o];
    __shared__ float hs[64];
    __shared__ float raws[256];
    if (tid < 64) hs[tid] = 0.f;
    float c_ = 0.f, n_ = 0.f, m_ = 0.f;
    __syncthreads();
    for (int s = 0; s < S_; s++) {
        float acc = Wx[(size_t)(b * S_ + s) * 1024 + g * 256 + h * 64 + o] + bi;
        #pragma unroll
        for (int d = 0; d < 64; d++) acc += hs[d] * w[d];
        raws[tid] = acc;
        __syncthreads();
        if (tid < 64) {
            float ir = raws[tid], fr = raws[64 + tid], zr = raws[128 + tid], orr = raws[192 + tid];
            float lfpm = m_ + logsigf_(fr);
            float mn = fmaxf(ir, lfpm);
            float ig = expf(ir - mn), fg = expf(lfpm - mn);
            c_ = fg * c_ + ig * tanhf(zr);
            n_ = fg * n_ + ig;
            m_ = mn;
            float hn = sigmoidf_(orr) * (c_ / n_);
            hs[tid] = hn;
            ys[(size_t)(b * S_ + s) * 256 + h * 64 + tid] = hn;
        }
        __syncthreads();
    }
}

// ---------------- sLSTM: per-head (64) groupnorm + residual add --------------
__global__ void __launch_bounds__(256)
mhln_s_resid(const float* __restrict__ ys, const float* __restrict__ w, float* __restrict__ h) {
    int n = blockIdx.x, t = threadIdx.x;
    float v = ys[(size_t)n * 256 + t];
    float s = v, s2 = v * v;
    #pragma unroll
    for (int off = 32; off; off >>= 1) { s += __shfl_xor(s, off); s2 += __shfl_xor(s2, off); }
    float mu = s / 64.f, var = s2 / 64.f - mu * mu;
    h[(size_t)n * 256 + t] += (v - mu) * rsqrtf(var + 1e-5f) * w[t];
}

// ---------------- FFN: gelu(gate)*up -----------------------------------------
__global__ void ffn_act(const float* __restrict__ up, float* __restrict__ act) {
    int idx = blockIdx.x * blockDim.x + threadIdx.x;
    if (idx >= NTOK * 384) return;
    int n = idx / 384, j = idx - n * 384;
    float g = up[(size_t)n * 768 + j], u = up[(size_t)n * 768 + 384 + j];
    float t = tanhf(0.7978845608028654f * (g + 0.044715f * g * g * g));
    act[idx] = 0.5f * g * (1.f + t) * u;
}

// ---------------- pooling + heads --------------------------------------------
__global__ void pool_k(const float* __restrict__ a, float* __restrict__ pooled) {
    int b = blockIdx.x, e = threadIdx.x;
    float s = 0.f;
    for (int t = 0; t < S_; t++) s += a[(size_t)(b * S_ + t) * 256 + e];
    pooled[b * 256 + e] = s / (float)S_;
}

__global__ void heads_k(const float* __restrict__ pooled,
                        const float* __restrict__ we, const float* __restrict__ be,
                        const float* __restrict__ ws, const float* __restrict__ bs,
                        float* __restrict__ out) {
    int i = blockIdx.x * blockDim.x + threadIdx.x;
    if (i < B_ * 7) {
        int b = i / 7, o = i - b * 7;
        float a = be[o];
        for (int e = 0; e < 256; e++) a += pooled[b * 256 + e] * we[e * 7 + o];
        out[b * 7 + o] = a;
    } else if (i < B_ * 7 + B_ * 3) {
        int j = i - B_ * 7;
        int b = j / 3, o = j - b * 3;
        float a = bs[o];
        for (int e = 0; e < 256; e++) a += pooled[b * 256 + e] * ws[e * 3 + o];
        out[B_ * 7 + b * 3 + o] = a;
    }
}

// =============================================================================
extern "C" void kernel_launch(void* const* d_in, const int* in_sizes, int n_in,
                              void* d_out, int out_size, void* d_ws, size_t ws_size,
                              hipStream_t stream) {
    (void)in_sizes; (void)n_in; (void)out_size; (void)ws_size;
    const float* x          = (const float*)d_in[0];
    const float* w_down     = (const float*)d_in[1];
    const float* b_down     = (const float*)d_in[2];
    const float* m_ln_w     = (const float*)d_in[3];
    const float* m_proj_up  = (const float*)d_in[4];
    const float* m_conv_w   = (const float*)d_in[5];
    const float* m_conv_b   = (const float*)d_in[6];
    const float* m_q_w      = (const float*)d_in[7];
    const float* m_k_w      = (const float*)d_in[8];
    const float* m_v_w      = (const float*)d_in[9];
    const float* m_ig_w     = (const float*)d_in[10];
    const float* m_ig_b     = (const float*)d_in[11];
    const float* m_fg_w     = (const float*)d_in[12];
    const float* m_fg_b     = (const float*)d_in[13];
    const float* m_skip     = (const float*)d_in[14];
    const float* m_outnorm  = (const float*)d_in[15];
    const float* m_proj_dn  = (const float*)d_in[16];
    const float* s_ln_w     = (const float*)d_in[17];
    const float* s_conv_w   = (const float*)d_in[18];
    const float* s_conv_b   = (const float*)d_in[19];
    const float* s_gate_w   = (const float*)d_in[20];
    const float* s_rec_w    = (const float*)d_in[21];
    const float* s_bias     = (const float*)d_in[22];
    const float* s_gn_w     = (const float*)d_in[23];
    const float* s_ln2_w    = (const float*)d_in[24];
    const float* s_ffn_up   = (const float*)d_in[25];
    const float* s_ffn_dn   = (const float*)d_in[26];
    const float* post_ln_w  = (const float*)d_in[27];
    const float* w_emo      = (const float*)d_in[28];
    const float* b_emo      = (const float*)d_in[29];
    const float* w_sen      = (const float*)d_in[30];
    const float* b_sen      = (const float*)d_in[31];

    float* W    = (float*)d_ws;
    float* h    = W;
    float* lnb  = h    + (size_t)NTOK * 256;
    float* big0 = lnb  + (size_t)NTOK * 256;
    float* xca  = big0 + (size_t)NTOK * 1024;
    float* qb   = xca  + (size_t)NTOK * 512;
    float* kb   = qb   + (size_t)NTOK * 512;
    float* vb   = kb   + (size_t)NTOK * 512;
    float* hatt = vb   + (size_t)NTOK * 512;
    float* igo  = hatt + (size_t)NTOK * 512;
    float* fgo  = igo  + (size_t)NTOK * 4;
    float* lfcb = fgo  + (size_t)NTOK * 4;
    float* Mxb  = lfcb + (size_t)256 * (S_ + 1);
    float* pooled = Mxb + (size_t)256 * S_;

    gemm_mfma<<<dim3(256 / 64, NTOK / 64), 256, 0, stream>>>(x, w_down, b_down, h, NTOK, 1024, 256, 0);

    int mi = 0, si = 0;
    for (int blk = 0; blk < 7; blk++) {
        if (blk == 1 || blk == 4) {
            layernorm256<<<NTOK, 256, 0, stream>>>(h, s_ln_w + si * 256, lnb);
            conv_silu_s<<<(NTOK * 256 + 255) / 256, 256, 0, stream>>>(lnb, s_conv_w + si * 1024, s_conv_b + si * 256, xca);
            slstm_wx_mfma<<<dim3(NTOK / 64, 16), 256, 0, stream>>>(xca, lnb, s_gate_w + (size_t)si * 65536, big0);
            slstm_rec<<<256, 256, 0, stream>>>(big0, s_rec_w + (size_t)si * 65536, s_bias + si * 1024, hatt);
            mhln_s_resid<<<NTOK, 256, 0, stream>>>(hatt, s_gn_w + si * 256, h);
            layernorm256<<<NTOK, 256, 0, stream>>>(h, s_ln2_w + si * 256, lnb);
            gemm_mfma<<<dim3(768 / 64, NTOK / 64), 256, 0, stream>>>(lnb, s_ffn_up + (size_t)si * 256 * 768, nullptr, big0, NTOK, 256, 768, 0);
            ffn_act<<<(NTOK * 384 + 255) / 256, 256, 0, stream>>>(big0, hatt);
            gemm_mfma<<<dim3(256 / 64, NTOK / 64), 256, 0, stream>>>(hatt, s_ffn_dn + (size_t)si * 384 * 256, nullptr, h, NTOK, 384, 256, 1);
            si++;
        } else {
            layernorm256<<<NTOK, 256, 0, stream>>>(h, m_ln_w + mi * 256, lnb);
            gemm_mfma<<<dim3(1024 / 64, NTOK / 64), 256, 0, stream>>>(lnb, m_proj_up + (size_t)mi * 256 * 1024, nullptr, big0, NTOK, 256, 1024, 0);
            conv_silu_m<<<(NTOK * 512 + 255) / 256, 256, 0, stream>>>(big0, m_conv_w + mi * 2048, m_conv_b + mi * 512, xca);
            headwise_qkv<<<(NTOK * 512 + 255) / 256, 256, 0, stream>>>(xca, big0, m_q_w + mi * 2048, m_k_w + mi * 2048, m_v_w + mi * 2048, qb, kb, vb);
            mlstm_gates<<<NTOK * 2, 256, 0, stream>>>(qb, kb, vb, m_ig_w + mi * 6144, m_ig_b + mi * 4, m_fg_w + mi * 6144, m_fg_b + mi * 4, igo, fgo);
            mlstm_cumsum<<<1, 256, 0, stream>>>(fgo, igo, lfcb, Mxb);
            mlstm_attn_mfma<<<256, 256, 0, stream>>>(qb, kb, vb, igo, lfcb, Mxb, hatt);
            mhln_m<<<NTOK, 512, 0, stream>>>(hatt, m_outnorm + mi * 512);
            hstate_m<<<(NTOK * 512 + 255) / 256, 256, 0, stream>>>(hatt, xca, big0, m_skip + mi * 512);
            gemm_mfma<<<dim3(256 / 64, NTOK / 64), 256, 0, stream>>>(hatt, m_proj_dn + (size_t)mi * 512 * 256, nullptr, h, NTOK, 512, 256, 1);
            mi++;
        }
    }

    postln_selu<<<NTOK, 256, 0, stream>>>(h, post_ln_w, lnb);
    pool_k<<<B_, 256, 0, stream>>>(lnb, pooled);
    heads_k<<<3, 256, 0, stream>>>(pooled, w_emo, b_emo, w_sen, b_sen, (float*)d_out);
}

// Round 5
// 2395.436 us; speedup vs baseline: 2.6282x; 1.3094x over previous
//
#include <hip/hip_runtime.h>
#include <hip/hip_bf16.h>
#include <math.h>

// AudioModelV3: 7-block xLSTM (blocks 1,4 = sLSTM+FFN; others mLSTM).
// R5: slstm_rec -> weights truly in VGPRs (launch_bounds(256,1); was spilling
// at 48 VGPRs), Wx prefetch, float4 LDS dot, redundant gate compute.
// mlstm_cumsum -> wave-parallel shfl scan (was 1 serial block).

#define B_    64
#define S_    199
#define E_    256
#define NTOK  (B_*S_)          // 12736 (= 199*64)
#define NQT   13               // ceil(199/16)

typedef __attribute__((ext_vector_type(8))) short short8;
typedef __attribute__((ext_vector_type(4))) float floatx4;

__device__ __forceinline__ float sigmoidf_(float x) { return 1.f / (1.f + expf(-x)); }
__device__ __forceinline__ float siluf_(float x) { return x / (1.f + expf(-x)); }
__device__ __forceinline__ float logsigf_(float x) { return fminf(x, 0.f) - log1pf(expf(-fabsf(x))); }

__device__ __forceinline__ unsigned short f2b(float f) {   // fp32 -> bf16 (RNE)
    union { float f; unsigned u; } v; v.f = f;
    unsigned r = (v.u + 0x7fffu + ((v.u >> 16) & 1u)) >> 16;
    return (unsigned short)r;
}
__device__ __forceinline__ short8 cvt8(const float* p) {
    union { unsigned short us[8]; short8 v; } t;
    #pragma unroll
    for (int i = 0; i < 8; i++) t.us[i] = f2b(p[i]);
    return t.v;
}

// ---------------- MFMA GEMM: C[M,N] = A[M,K] @ B[K,N] (+bias) (+=C) ----------
__global__ void __launch_bounds__(256)
gemm_mfma(const float* __restrict__ A, const float* __restrict__ Bw,
          const float* __restrict__ bias, float* __restrict__ C,
          int M, int K, int N, int accum) {
    __shared__ __align__(16) unsigned short As[64][40];
    __shared__ __align__(16) unsigned short Bs[64][40];
    int tid = threadIdx.x;
    int wave = tid >> 6, lane = tid & 63;
    int wm = wave >> 1, wn = wave & 1;
    int quad = lane >> 4, l16 = lane & 15;
    int m0 = blockIdx.y * 64, n0 = blockIdx.x * 64;
    floatx4 zero = {0.f, 0.f, 0.f, 0.f};
    floatx4 acc[2][2];
    acc[0][0] = zero; acc[0][1] = zero; acc[1][0] = zero; acc[1][1] = zero;
    int ar = tid >> 2, ac = (tid & 3) * 8;
    int bn = tid & 63, bk = (tid >> 6) * 8;
    for (int k0 = 0; k0 < K; k0 += 32) {
        {
            const float* ap = A + (size_t)(m0 + ar) * K + k0 + ac;
            union { unsigned short us[8]; uint4 v; } t;
            #pragma unroll
            for (int i = 0; i < 8; i++) t.us[i] = f2b(ap[i]);
            *(uint4*)&As[ar][ac] = t.v;
        }
        {
            const float* bp = Bw + (size_t)(k0 + bk) * N + n0 + bn;
            union { unsigned short us[8]; uint4 v; } t;
            #pragma unroll
            for (int i = 0; i < 8; i++) t.us[i] = f2b(bp[(size_t)i * N]);
            *(uint4*)&Bs[bn][bk] = t.v;
        }
        __syncthreads();
        short8 af[2], bf[2];
        #pragma unroll
        for (int i = 0; i < 2; i++) af[i] = *(const short8*)&As[wm * 32 + i * 16 + l16][quad * 8];
        #pragma unroll
        for (int j = 0; j < 2; j++) bf[j] = *(const short8*)&Bs[wn * 32 + j * 16 + l16][quad * 8];
        #pragma unroll
        for (int i = 0; i < 2; i++)
            #pragma unroll
            for (int j = 0; j < 2; j++)
                acc[i][j] = __builtin_amdgcn_mfma_f32_16x16x32_bf16(af[i], bf[j], acc[i][j], 0, 0, 0);
        __syncthreads();
    }
    #pragma unroll
    for (int i = 0; i < 2; i++)
        #pragma unroll
        for (int j = 0; j < 2; j++)
            #pragma unroll
            for (int r = 0; r < 4; r++) {
                int row = m0 + wm * 32 + i * 16 + quad * 4 + r;
                int col = n0 + wn * 32 + j * 16 + l16;
                float o = acc[i][j][r];
                if (bias) o += bias[col];
                float* cp = &C[(size_t)row * N + col];
                if (accum) o += *cp;
                *cp = o;
            }
}

// ---------------- sLSTM Wx as block-diagonal MFMA GEMM -----------------------
__global__ void __launch_bounds__(256)
slstm_wx_mfma(const float* __restrict__ xc, const float* __restrict__ xln,
              const float* __restrict__ gw, float* __restrict__ Wx) {
    __shared__ __align__(16) unsigned short As[64][40];
    __shared__ __align__(16) unsigned short Bs[64][40];
    int gh = blockIdx.y; int g = gh >> 2, hh = gh & 3;
    const float* src = (g < 2) ? xc : xln;
    const float* w = gw + (size_t)gh * 4096;
    int tid = threadIdx.x;
    int wave = tid >> 6, lane = tid & 63;
    int wm = wave >> 1, wn = wave & 1;
    int quad = lane >> 4, l16 = lane & 15;
    int m0 = blockIdx.x * 64;
    floatx4 zero = {0.f, 0.f, 0.f, 0.f};
    floatx4 acc[2][2];
    acc[0][0] = zero; acc[0][1] = zero; acc[1][0] = zero; acc[1][1] = zero;
    int ar = tid >> 2, ac = (tid & 3) * 8;
    int bn = tid & 63, bk = (tid >> 6) * 8;
    #pragma unroll
    for (int kt = 0; kt < 2; kt++) {
        int k0 = kt * 32;
        {
            const float* ap = src + (size_t)(m0 + ar) * 256 + hh * 64 + k0 + ac;
            union { unsigned short us[8]; uint4 v; } t;
            #pragma unroll
            for (int i = 0; i < 8; i++) t.us[i] = f2b(ap[i]);
            *(uint4*)&As[ar][ac] = t.v;
        }
        {
            const float* bp = w + (size_t)bn * 64 + k0 + bk;
            union { unsigned short us[8]; uint4 v; } t;
            #pragma unroll
            for (int i = 0; i < 8; i++) t.us[i] = f2b(bp[i]);
            *(uint4*)&Bs[bn][bk] = t.v;
        }
        __syncthreads();
        short8 af[2], bf[2];
        #pragma unroll
        for (int i = 0; i < 2; i++) af[i] = *(const short8*)&As[wm * 32 + i * 16 + l16][quad * 8];
        #pragma unroll
        for (int j = 0; j < 2; j++) bf[j] = *(const short8*)&Bs[wn * 32 + j * 16 + l16][quad * 8];
        #pragma unroll
        for (int i = 0; i < 2; i++)
            #pragma unroll
            for (int j = 0; j < 2; j++)
                acc[i][j] = __builtin_amdgcn_mfma_f32_16x16x32_bf16(af[i], bf[j], acc[i][j], 0, 0, 0);
        __syncthreads();
    }
    #pragma unroll
    for (int i = 0; i < 2; i++)
        #pragma unroll
        for (int j = 0; j < 2; j++)
            #pragma unroll
            for (int r = 0; r < 4; r++) {
                int row = m0 + wm * 32 + i * 16 + quad * 4 + r;
                int col = wn * 32 + j * 16 + l16;
                Wx[(size_t)row * 1024 + g * 256 + hh * 64 + col] = acc[i][j][r];
            }
}

// ---------------- layernorm over 256 with weight -----------------------------
__global__ void __launch_bounds__(256)
layernorm256(const float* __restrict__ x, const float* __restrict__ w, float* __restrict__ y) {
    int n = blockIdx.x, t = threadIdx.x;
    float v = x[(size_t)n * 256 + t];
    float s = v, s2 = v * v;
    #pragma unroll
    for (int off = 32; off; off >>= 1) { s += __shfl_xor(s, off); s2 += __shfl_xor(s2, off); }
    __shared__ float ps[4], ps2[4];
    if ((t & 63) == 0) { ps[t >> 6] = s; ps2[t >> 6] = s2; }
    __syncthreads();
    float S = ps[0] + ps[1] + ps[2] + ps[3];
    float S2 = ps2[0] + ps2[1] + ps2[2] + ps2[3];
    float mu = S / 256.f, var = S2 / 256.f - mu * mu;
    y[(size_t)n * 256 + t] = (v - mu) * rsqrtf(var + 1e-5f) * w[t];
}

// ---------------- post-LN + selu --------------------------------------------
__global__ void __launch_bounds__(256)
postln_selu(const float* __restrict__ x, const float* __restrict__ w, float* __restrict__ y) {
    int n = blockIdx.x, t = threadIdx.x;
    float v = x[(size_t)n * 256 + t];
    float s = v, s2 = v * v;
    #pragma unroll
    for (int off = 32; off; off >>= 1) { s += __shfl_xor(s, off); s2 += __shfl_xor(s2, off); }
    __shared__ float ps[4], ps2[4];
    if ((t & 63) == 0) { ps[t >> 6] = s; ps2[t >> 6] = s2; }
    __syncthreads();
    float S = ps[0] + ps[1] + ps[2] + ps[3];
    float S2 = ps2[0] + ps2[1] + ps2[2] + ps2[3];
    float mu = S / 256.f, var = S2 / 256.f - mu * mu;
    float yn = (v - mu) * rsqrtf(var + 1e-5f) * w[t];
    y[(size_t)n * 256 + t] = 1.0507009873554805f * (yn > 0.f ? yn : 1.6732632423543772f * (expf(yn) - 1.f));
}

// ---------------- mLSTM: causal conv (512 ch) + silu -------------------------
__global__ void conv_silu_m(const float* __restrict__ xi, const float* __restrict__ cw,
                            const float* __restrict__ cb, float* __restrict__ xca) {
    int idx = blockIdx.x * blockDim.x + threadIdx.x;
    if (idx >= NTOK * 512) return;
    int n = idx >> 9, c = idx & 511;
    int b = n / S_, s = n - b * S_;
    float y = cb[c];
    #pragma unroll
    for (int i = 0; i < 4; i++) {
        int sp = s - 3 + i;
        if (sp >= 0) y += xi[(size_t)(b * S_ + sp) * 1024 + c] * cw[c * 4 + i];
    }
    xca[idx] = siluf_(y);
}

// ---------------- mLSTM: block-diagonal headwise q,k,v -----------------------
__global__ void headwise_qkv(const float* __restrict__ xca, const float* __restrict__ xi,
                             const float* __restrict__ qw, const float* __restrict__ kw,
                             const float* __restrict__ vw,
                             float* __restrict__ qb, float* __restrict__ kb, float* __restrict__ vb) {
    int idx = blockIdx.x * blockDim.x + threadIdx.x;
    if (idx >= NTOK * 512) return;
    int n = idx >> 9, c = idx & 511;
    int hh = c >> 2, o = c & 3;
    float aq = 0, ak = 0, av = 0;
    #pragma unroll
    for (int d = 0; d < 4; d++) {
        float xc = xca[(size_t)n * 512 + hh * 4 + d];
        float xm = xi[(size_t)n * 1024 + hh * 4 + d];
        int wi = (hh * 4 + o) * 4 + d;
        aq += xc * qw[wi]; ak += xc * kw[wi]; av += xm * vw[wi];
    }
    qb[idx] = aq; kb[idx] = ak; vb[idx] = av;
}

// ---------------- mLSTM: ig/fg gates -----------------------------------------
__global__ void __launch_bounds__(256)
mlstm_gates(const float* __restrict__ qb, const float* __restrict__ kb, const float* __restrict__ vb,
            const float* __restrict__ igw, const float* __restrict__ igbias,
            const float* __restrict__ fgw, const float* __restrict__ fgbias,
            float* __restrict__ igo, float* __restrict__ fgo) {
    int gid = blockIdx.x * 256 + threadIdx.x;
    int wid = gid >> 6, lane = gid & 63;
    int which = wid & 1, hd = (wid >> 1) & 3, n = wid >> 3;
    if (n >= NTOK) return;
    const float* w = (which ? fgw : igw) + hd * 1536;
    float a = 0.f;
    for (int j = lane; j < 512; j += 64) {
        a += qb[(size_t)n * 512 + j] * w[j]
           + kb[(size_t)n * 512 + j] * w[512 + j]
           + vb[(size_t)n * 512 + j] * w[1024 + j];
    }
    #pragma unroll
    for (int off = 32; off; off >>= 1) a += __shfl_xor(a, off);
    if (lane == 0) {
        a += (which ? fgbias : igbias)[hd];
        (which ? fgo : igo)[(size_t)n * 4 + hd] = a;
    }
}

// ---------------- mLSTM: cumsum + prefix-max, wave-parallel shfl scan --------
// 64 blocks x 4 waves; wave = (b,h); lane covers s in [4*lane, 4*lane+4).
__global__ void __launch_bounds__(256)
mlstm_cumsum(const float* __restrict__ fgo, const float* __restrict__ igo,
             float* __restrict__ lfc, float* __restrict__ Mx) {
    int bh = blockIdx.x * 4 + (threadIdx.x >> 6);
    int lane = threadIdx.x & 63;
    int b = bh >> 2, h = bh & 3;
    // local inclusive cumsum of logsigmoid(fg)
    float v[4]; float lsum = 0.f;
    #pragma unroll
    for (int i = 0; i < 4; i++) {
        int s = lane * 4 + i;
        float f = (s < S_) ? fgo[(size_t)(b * S_ + s) * 4 + h] : 0.f;
        lsum += logsigf_(f);
        v[i] = lsum;
    }
    // wave inclusive scan of lane totals
    float x = lsum;
    #pragma unroll
    for (int off = 1; off < 64; off <<= 1) {
        float y = __shfl_up(x, off);
        if (lane >= off) x += y;
    }
    float excl = x - lsum;
    float lf1[4];
    #pragma unroll
    for (int i = 0; i < 4; i++) lf1[i] = excl + v[i];
    if (lane == 0) lfc[bh * (S_ + 1)] = 0.f;
    #pragma unroll
    for (int i = 0; i < 4; i++) {
        int s = lane * 4 + i;
        if (s < S_) lfc[bh * (S_ + 1) + s + 1] = lf1[i];
    }
    // prefix max of g[s] = ig[s] - lf1[s]
    float gm[4]; float lmax = -1e30f;
    #pragma unroll
    for (int i = 0; i < 4; i++) {
        int s = lane * 4 + i;
        float ig_ = (s < S_) ? igo[(size_t)(b * S_ + s) * 4 + h] : -1e30f;
        float gg = ig_ - lf1[i];
        lmax = fmaxf(lmax, gg);
        gm[i] = lmax;
    }
    float xm = lmax;
    #pragma unroll
    for (int off = 1; off < 64; off <<= 1) {
        float y = __shfl_up(xm, off);
        if (lane >= off) xm = fmaxf(xm, y);
    }
    float exclm = __shfl_up(xm, 1);
    if (lane == 0) exclm = -1e30f;
    #pragma unroll
    for (int i = 0; i < 4; i++) {
        int s = lane * 4 + i;
        if (s < S_) Mx[bh * S_ + s] = fmaxf(exclm, gm[i]);
    }
}

// ---------------- mLSTM attention: MFMA flash-style, one block per (b,h) -----
__global__ void __launch_bounds__(256, 1)
mlstm_attn_mfma(const float* __restrict__ qb, const float* __restrict__ kb, const float* __restrict__ vb,
                const float* __restrict__ igb, const float* __restrict__ lfc, const float* __restrict__ Mx,
                float* __restrict__ outb) {
    __shared__ __align__(16) unsigned short Kb[64 * 136];   // [t_local][d], pad 136
    __shared__ __align__(16) unsigned short Vt[128 * 72];   // [d][t_local], pad 72
    __shared__ __align__(16) unsigned short Pw[4][16 * 72]; // per-wave P tile
    __shared__ float gv[208], lfv[208], mxv[208];
    int bh = blockIdx.x; int b = bh >> 2, h = bh & 3;
    int tid = threadIdx.x, wave = tid >> 6, lane = tid & 63;
    int quad = lane >> 4, l16 = lane & 15;
    if (tid < 208) {
        if (tid < S_) {
            float lf1 = lfc[bh * (S_ + 1) + tid + 1];
            gv[tid] = igb[(size_t)(b * S_ + tid) * 4 + h] - lf1;
            lfv[tid] = lf1;
            mxv[tid] = Mx[bh * S_ + tid];
        } else { gv[tid] = 0.f; lfv[tid] = 0.f; mxv[tid] = 0.f; }
    }
    floatx4 zero = {0.f, 0.f, 0.f, 0.f};
    float rs[4][4];
    floatx4 accv[4][8];
    #pragma unroll
    for (int qi = 0; qi < 4; qi++) {
        #pragma unroll
        for (int r = 0; r < 4; r++) rs[qi][r] = 0.f;
        #pragma unroll
        for (int dt = 0; dt < 8; dt++) accv[qi][dt] = zero;
    }
    const float scale = 0.08838834764831845f;   // 1/sqrt(128)
    int trow = tid >> 4, d0 = (tid & 15) * 8;
    for (int c = 0; c < 4; c++) {
        __syncthreads();
        #pragma unroll
        for (int i = 0; i < 4; i++) {           // stage K,V chunk (64 t-steps)
            int tl = trow + 16 * i;
            int t = c * 64 + tl;
            union { unsigned short us[8]; uint4 v; } kk;
            unsigned short vv[8];
            if (t < S_) {
                const float* kp = kb + (size_t)(b * S_ + t) * 512 + h * 128 + d0;
                const float* vp = vb + (size_t)(b * S_ + t) * 512 + h * 128 + d0;
                #pragma unroll
                for (int ii = 0; ii < 8; ii++) { kk.us[ii] = f2b(kp[ii]); vv[ii] = f2b(vp[ii]); }
            } else {
                kk.v = (uint4){0, 0, 0, 0};
                #pragma unroll
                for (int ii = 0; ii < 8; ii++) vv[ii] = 0;
            }
            *(uint4*)&Kb[tl * 136 + d0] = kk.v;
            #pragma unroll
            for (int ii = 0; ii < 8; ii++) Vt[(d0 + ii) * 72 + tl] = vv[ii];
        }
        __syncthreads();
        for (int qi = 0; qi < 4; qi++) {
            int qt = wave + 4 * qi;
            if (qt >= NQT || qt < 4 * c) continue;
            uint4 z4 = {0, 0, 0, 0};
            for (int z = lane; z < 144; z += 64) ((uint4*)Pw[wave])[z] = z4;
            int srow = qt * 16 + l16;
            const float* qp = qb + (size_t)(b * S_ + min(srow, S_ - 1)) * 512 + h * 128 + quad * 8;
            short8 af[4];
            #pragma unroll
            for (int ks = 0; ks < 4; ks++) af[ks] = cvt8(qp + 32 * ks);
            int ktmax_l = min(qt, 4 * c + 3) - 4 * c;
            for (int ktl = 0; ktl <= ktmax_l; ktl++) {
                floatx4 acc = zero;
                #pragma unroll
                for (int ks = 0; ks < 4; ks++) {
                    short8 bf = *(const short8*)&Kb[(ktl * 16 + l16) * 136 + quad * 8 + 32 * ks];
                    acc = __builtin_amdgcn_mfma_f32_16x16x32_bf16(af[ks], bf, acc, 0, 0, 0);
                }
                int tcol = c * 64 + ktl * 16 + l16;
                float gt = gv[tcol];
                #pragma unroll
                for (int r = 0; r < 4; r++) {
                    int s = qt * 16 + quad * 4 + r;
                    bool valid = (tcol <= s) && (tcol < S_);
                    float w = valid ? expf(gt - mxv[s]) : 0.f;
                    float p = acc[r] * scale * w;
                    rs[qi][r] += p;
                    Pw[wave][(quad * 4 + r) * 72 + ktl * 16 + l16] = f2b(p);
                }
            }
            #pragma unroll
            for (int dt = 0; dt < 8; dt++) {
                floatx4 a = accv[qi][dt];
                #pragma unroll
                for (int ks = 0; ks < 2; ks++) {
                    short8 ap = *(const short8*)&Pw[wave][l16 * 72 + quad * 8 + 32 * ks];
                    short8 bp = *(const short8*)&Vt[(dt * 16 + l16) * 72 + quad * 8 + 32 * ks];
                    a = __builtin_amdgcn_mfma_f32_16x16x32_bf16(ap, bp, a, 0, 0, 0);
                }
                accv[qi][dt] = a;
            }
        }
    }
    for (int qi = 0; qi < 4; qi++) {
        int qt = wave + 4 * qi;
        if (qt >= NQT) continue;
        float nrm[4];
        #pragma unroll
        for (int r = 0; r < 4; r++) {
            float v = rs[qi][r];
            v += __shfl_xor(v, 1); v += __shfl_xor(v, 2);
            v += __shfl_xor(v, 4); v += __shfl_xor(v, 8);
            int s = qt * 16 + quad * 4 + r;
            nrm[r] = fmaxf(fabsf(v), expf(-(lfv[s] + mxv[s]))) + 1e-6f;
        }
        #pragma unroll
        for (int dt = 0; dt < 8; dt++)
            #pragma unroll
            for (int r = 0; r < 4; r++) {
                int s = qt * 16 + quad * 4 + r;
                if (s < S_)
                    outb[(size_t)(b * S_ + s) * 512 + h * 128 + dt * 16 + l16] = accv[qi][dt][r] / nrm[r];
            }
    }
}

// ---------------- mLSTM: per-head (128) layernorm, in place ------------------
__global__ void __launch_bounds__(512)
mhln_m(float* __restrict__ hatt, const float* __restrict__ w) {
    int n = blockIdx.x, t = threadIdx.x;
    float v = hatt[(size_t)n * 512 + t];
    float s = v, s2 = v * v;
    #pragma unroll
    for (int off = 32; off; off >>= 1) { s += __shfl_xor(s, off); s2 += __shfl_xor(s2, off); }
    __shared__ float ps[8], ps2[8];
    if ((t & 63) == 0) { ps[t >> 6] = s; ps2[t >> 6] = s2; }
    __syncthreads();
    int hd = t >> 7;
    float S = ps[hd * 2] + ps[hd * 2 + 1], S2 = ps2[hd * 2] + ps2[hd * 2 + 1];
    float mu = S / 128.f, var = S2 / 128.f - mu * mu;
    hatt[(size_t)n * 512 + t] = (v - mu) * rsqrtf(var + 1e-5f) * w[t];
}

// ---------------- mLSTM: h_state = (hn + skip*xca)*silu(z) -------------------
__global__ void hstate_m(float* __restrict__ hatt, const float* __restrict__ xca,
                         const float* __restrict__ xi, const float* __restrict__ skip) {
    int idx = blockIdx.x * blockDim.x + threadIdx.x;
    if (idx >= NTOK * 512) return;
    int n = idx >> 9, c = idx & 511;
    float z = xi[(size_t)n * 1024 + 512 + c];
    hatt[idx] = (hatt[idx] + skip[c] * xca[idx]) * siluf_(z);
}

// ---------------- sLSTM: causal conv (256 ch) + silu -------------------------
__global__ void conv_silu_s(const float* __restrict__ xln, const float* __restrict__ cw,
                            const float* __restrict__ cb, float* __restrict__ xc) {
    int idx = blockIdx.x * blockDim.x + threadIdx.x;
    if (idx >= NTOK * 256) return;
    int n = idx >> 8, c = idx & 255;
    int b = n / S_, s = n - b * S_;
    float y = cb[c];
    #pragma unroll
    for (int i = 0; i < 4; i++) {
        int sp = s - 3 + i;
        if (sp >= 0) y += xln[(size_t)(b * S_ + sp) * 256 + c] * cw[c * 4 + i];
    }
    xc[idx] = siluf_(y);
}

// ---------------- sLSTM: recurrence, one block per (b,head) ------------------
// 4 waves = 4 gates; lane o owns R[g][o][0..63] in 64 VGPRs (launch_bounds
// (256,1) -> up to 512 VGPRs, no spill). Wx prefetched one step ahead.
// Gate update computed redundantly on all waves (state in regs); wave 0 stores.
__global__ void __launch_bounds__(256, 1)
slstm_rec(const float* __restrict__ Wx, const float* __restrict__ rw,
          const float* __restrict__ bias, float* __restrict__ ys) {
    int b = blockIdx.x >> 2, h = blockIdx.x & 3;
    int tid = threadIdx.x;
    int g = tid >> 6, o = tid & 63;
    float w[64];
    const float* wp = rw + (size_t)(((g * 4 + h) * 64 + o)) * 64;
    #pragma unroll
    for (int d = 0; d < 64; d++) w[d] = wp[d];
    float bi = bias[(g * 4 + h) * 64 + o];
    __shared__ __align__(16) float hs[64];
    __shared__ float raws[4][64];
    if (tid < 64) hs[tid] = 0.f;
    float c_ = 0.f, n_ = 0.f, m_ = 0.f;
    size_t wxbase = (size_t)(b * S_) * 1024 + g * 256 + h * 64 + o;
    float wx_cur = Wx[wxbase];
    __syncthreads();
    for (int s = 0; s < S_; s++) {
        float wx_next = (s + 1 < S_) ? Wx[wxbase + (size_t)(s + 1) * 1024] : 0.f;
        float a0 = 0.f, a1 = 0.f, a2 = 0.f, a3 = 0.f;
        #pragma unroll
        for (int d4 = 0; d4 < 16; d4++) {
            float4 hv = *(const float4*)&hs[d4 * 4];
            a0 += hv.x * w[4 * d4 + 0];
            a1 += hv.y * w[4 * d4 + 1];
            a2 += hv.z * w[4 * d4 + 2];
            a3 += hv.w * w[4 * d4 + 3];
        }
        raws[g][o] = (a0 + a1) + (a2 + a3) + wx_cur + bi;
        __syncthreads();
        float ir = raws[0][o], fr = raws[1][o], zr = raws[2][o], orr = raws[3][o];
        float lfpm = m_ + logsigf_(fr);
        float mn = fmaxf(ir, lfpm);
        float ig = expf(ir - mn), fg = expf(lfpm - mn);
        c_ = fg * c_ + ig * tanhf(zr);
        n_ = fg * n_ + ig;
        m_ = mn;
        float hn = sigmoidf_(orr) * (c_ / n_);
        if (g == 0) {
            hs[o] = hn;
            ys[(size_t)(b * S_ + s) * 256 + h * 64 + o] = hn;
        }
        __syncthreads();
        wx_cur = wx_next;
    }
}

// ---------------- sLSTM: per-head (64) groupnorm + residual add --------------
__global__ void __launch_bounds__(256)
mhln_s_resid(const float* __restrict__ ys, const float* __restrict__ w, float* __restrict__ h) {
    int n = blockIdx.x, t = threadIdx.x;
    float v = ys[(size_t)n * 256 + t];
    float s = v, s2 = v * v;
    #pragma unroll
    for (int off = 32; off; off >>= 1) { s += __shfl_xor(s, off); s2 += __shfl_xor(s2, off); }
    float mu = s / 64.f, var = s2 / 64.f - mu * mu;
    h[(size_t)n * 256 + t] += (v - mu) * rsqrtf(var + 1e-5f) * w[t];
}

// ---------------- FFN: gelu(gate)*up -----------------------------------------
__global__ void ffn_act(const float* __restrict__ up, float* __restrict__ act) {
    int idx = blockIdx.x * blockDim.x + threadIdx.x;
    if (idx >= NTOK * 384) return;
    int n = idx / 384, j = idx - n * 384;
    float g = up[(size_t)n * 768 + j], u = up[(size_t)n * 768 + 384 + j];
    float t = tanhf(0.7978845608028654f * (g + 0.044715f * g * g * g));
    act[idx] = 0.5f * g * (1.f + t) * u;
}

// ---------------- pooling + heads --------------------------------------------
__global__ void pool_k(const float* __restrict__ a, float* __restrict__ pooled) {
    int b = blockIdx.x, e = threadIdx.x;
    float s = 0.f;
    for (int t = 0; t < S_; t++) s += a[(size_t)(b * S_ + t) * 256 + e];
    pooled[b * 256 + e] = s / (float)S_;
}

__global__ void heads_k(const float* __restrict__ pooled,
                        const float* __restrict__ we, const float* __restrict__ be,
                        const float* __restrict__ ws, const float* __restrict__ bs,
                        float* __restrict__ out) {
    int i = blockIdx.x * blockDim.x + threadIdx.x;
    if (i < B_ * 7) {
        int b = i / 7, o = i - b * 7;
        float a = be[o];
        for (int e = 0; e < 256; e++) a += pooled[b * 256 + e] * we[e * 7 + o];
        out[b * 7 + o] = a;
    } else if (i < B_ * 7 + B_ * 3) {
        int j = i - B_ * 7;
        int b = j / 3, o = j - b * 3;
        float a = bs[o];
        for (int e = 0; e < 256; e++) a += pooled[b * 256 + e] * ws[e * 3 + o];
        out[B_ * 7 + b * 3 + o] = a;
    }
}

// =============================================================================
extern "C" void kernel_launch(void* const* d_in, const int* in_sizes, int n_in,
                              void* d_out, int out_size, void* d_ws, size_t ws_size,
                              hipStream_t stream) {
    (void)in_sizes; (void)n_in; (void)out_size; (void)ws_size;
    const float* x          = (const float*)d_in[0];
    const float* w_down     = (const float*)d_in[1];
    const float* b_down     = (const float*)d_in[2];
    const float* m_ln_w     = (const float*)d_in[3];
    const float* m_proj_up  = (const float*)d_in[4];
    const float* m_conv_w   = (const float*)d_in[5];
    const float* m_conv_b   = (const float*)d_in[6];
    const float* m_q_w      = (const float*)d_in[7];
    const float* m_k_w      = (const float*)d_in[8];
    const float* m_v_w      = (const float*)d_in[9];
    const float* m_ig_w     = (const float*)d_in[10];
    const float* m_ig_b     = (const float*)d_in[11];
    const float* m_fg_w     = (const float*)d_in[12];
    const float* m_fg_b     = (const float*)d_in[13];
    const float* m_skip     = (const float*)d_in[14];
    const float* m_outnorm  = (const float*)d_in[15];
    const float* m_proj_dn  = (const float*)d_in[16];
    const float* s_ln_w     = (const float*)d_in[17];
    const float* s_conv_w   = (const float*)d_in[18];
    const float* s_conv_b   = (const float*)d_in[19];
    const float* s_gate_w   = (const float*)d_in[20];
    const float* s_rec_w    = (const float*)d_in[21];
    const float* s_bias     = (const float*)d_in[22];
    const float* s_gn_w     = (const float*)d_in[23];
    const float* s_ln2_w    = (const float*)d_in[24];
    const float* s_ffn_up   = (const float*)d_in[25];
    const float* s_ffn_dn   = (const float*)d_in[26];
    const float* post_ln_w  = (const float*)d_in[27];
    const float* w_emo      = (const float*)d_in[28];
    const float* b_emo      = (const float*)d_in[29];
    const float* w_sen      = (const float*)d_in[30];
    const float* b_sen      = (const float*)d_in[31];

    float* W    = (float*)d_ws;
    float* h    = W;
    float* lnb  = h    + (size_t)NTOK * 256;
    float* big0 = lnb  + (size_t)NTOK * 256;
    float* xca  = big0 + (size_t)NTOK * 1024;
    float* qb   = xca  + (size_t)NTOK * 512;
    float* kb   = qb   + (size_t)NTOK * 512;
    float* vb   = kb   + (size_t)NTOK * 512;
    float* hatt = vb   + (size_t)NTOK * 512;
    float* igo  = hatt + (size_t)NTOK * 512;
    float* fgo  = igo  + (size_t)NTOK * 4;
    float* lfcb = fgo  + (size_t)NTOK * 4;
    float* Mxb  = lfcb + (size_t)256 * (S_ + 1);
    float* pooled = Mxb + (size_t)256 * S_;

    gemm_mfma<<<dim3(256 / 64, NTOK / 64), 256, 0, stream>>>(x, w_down, b_down, h, NTOK, 1024, 256, 0);

    int mi = 0, si = 0;
    for (int blk = 0; blk < 7; blk++) {
        if (blk == 1 || blk == 4) {
            layernorm256<<<NTOK, 256, 0, stream>>>(h, s_ln_w + si * 256, lnb);
            conv_silu_s<<<(NTOK * 256 + 255) / 256, 256, 0, stream>>>(lnb, s_conv_w + si * 1024, s_conv_b + si * 256, xca);
            slstm_wx_mfma<<<dim3(NTOK / 64, 16), 256, 0, stream>>>(xca, lnb, s_gate_w + (size_t)si * 65536, big0);
            slstm_rec<<<256, 256, 0, stream>>>(big0, s_rec_w + (size_t)si * 65536, s_bias + si * 1024, hatt);
            mhln_s_resid<<<NTOK, 256, 0, stream>>>(hatt, s_gn_w + si * 256, h);
            layernorm256<<<NTOK, 256, 0, stream>>>(h, s_ln2_w + si * 256, lnb);
            gemm_mfma<<<dim3(768 / 64, NTOK / 64), 256, 0, stream>>>(lnb, s_ffn_up + (size_t)si * 256 * 768, nullptr, big0, NTOK, 256, 768, 0);
            ffn_act<<<(NTOK * 384 + 255) / 256, 256, 0, stream>>>(big0, hatt);
            gemm_mfma<<<dim3(256 / 64, NTOK / 64), 256, 0, stream>>>(hatt, s_ffn_dn + (size_t)si * 384 * 256, nullptr, h, NTOK, 384, 256, 1);
            si++;
        } else {
            layernorm256<<<NTOK, 256, 0, stream>>>(h, m_ln_w + mi * 256, lnb);
            gemm_mfma<<<dim3(1024 / 64, NTOK / 64), 256, 0, stream>>>(lnb, m_proj_up + (size_t)mi * 256 * 1024, nullptr, big0, NTOK, 256, 1024, 0);
            conv_silu_m<<<(NTOK * 512 + 255) / 256, 256, 0, stream>>>(big0, m_conv_w + mi * 2048, m_conv_b + mi * 512, xca);
            headwise_qkv<<<(NTOK * 512 + 255) / 256, 256, 0, stream>>>(xca, big0, m_q_w + mi * 2048, m_k_w + mi * 2048, m_v_w + mi * 2048, qb, kb, vb);
            mlstm_gates<<<NTOK * 2, 256, 0, stream>>>(qb, kb, vb, m_ig_w + mi * 6144, m_ig_b + mi * 4, m_fg_w + mi * 6144, m_fg_b + mi * 4, igo, fgo);
            mlstm_cumsum<<<64, 256, 0, stream>>>(fgo, igo, lfcb, Mxb);
            mlstm_attn_mfma<<<256, 256, 0, stream>>>(qb, kb, vb, igo, lfcb, Mxb, hatt);
            mhln_m<<<NTOK, 512, 0, stream>>>(hatt, m_outnorm + mi * 512);
            hstate_m<<<(NTOK * 512 + 255) / 256, 256, 0, stream>>>(hatt, xca, big0, m_skip + mi * 512);
            gemm_mfma<<<dim3(256 / 64, NTOK / 64), 256, 0, stream>>>(hatt, m_proj_dn + (size_t)mi * 512 * 256, nullptr, h, NTOK, 512, 256, 1);
            mi++;
        }
    }

    postln_selu<<<NTOK, 256, 0, stream>>>(h, post_ln_w, lnb);
    pool_k<<<B_, 256, 0, stream>>>(lnb, pooled);
    heads_k<<<3, 256, 0, stream>>>(pooled, w_emo, b_emo, w_sen, b_sen, (float*)d_out);
}

// Round 6
// 2289.491 us; speedup vs baseline: 2.7498x; 1.0463x over previous
//
#include <hip/hip_runtime.h>
#include <hip/hip_bf16.h>
#include <math.h>

// AudioModelV3: 7-block xLSTM (blocks 1,4 = sLSTM+FFN; others mLSTM).
// R6: (1) bf16-native GEMM path: weights pre-packed to bf16 once, producers
// write bf16 activations, gemm_bf 64x128 tile with no f2b in K-loop.
// (2) slstm_rec split-K: 512 thr, w[32]/thread (fits 64-VGPR budget; R5's
// w[64] spilled at VGPR_Count=56), shfl_xor combine.

#define B_    64
#define S_    199
#define E_    256
#define NTOK  (B_*S_)          // 12736 (= 199*64)
#define NQT   13               // ceil(199/16)

typedef __attribute__((ext_vector_type(8))) short short8;
typedef __attribute__((ext_vector_type(4))) float floatx4;
typedef unsigned short ushort_t;

__device__ __forceinline__ float sigmoidf_(float x) { return 1.f / (1.f + expf(-x)); }
__device__ __forceinline__ float siluf_(float x) { return x / (1.f + expf(-x)); }
__device__ __forceinline__ float logsigf_(float x) { return fminf(x, 0.f) - log1pf(expf(-fabsf(x))); }

__device__ __forceinline__ ushort_t f2b(float f) {   // fp32 -> bf16 (RNE)
    union { float f; unsigned u; } v; v.f = f;
    unsigned r = (v.u + 0x7fffu + ((v.u >> 16) & 1u)) >> 16;
    return (ushort_t)r;
}
__device__ __forceinline__ float bf2f(ushort_t u) {
    union { unsigned u; float f; } v; v.u = ((unsigned)u) << 16;
    return v.f;
}
__device__ __forceinline__ short8 cvt8(const float* p) {
    union { ushort_t us[8]; short8 v; } t;
    #pragma unroll
    for (int i = 0; i < 8; i++) t.us[i] = f2b(p[i]);
    return t.v;
}

// ---------------- fp32 -> bf16 convert (weights pack / x) --------------------
__global__ void cvt_bf(const float* __restrict__ in, ushort_t* __restrict__ out, int n4) {
    int i = blockIdx.x * 256 + threadIdx.x;
    if (i >= n4) return;
    float4 v = *(const float4*)&in[i * 4];
    union { ushort_t us[4]; uint2 u; } t;
    t.us[0] = f2b(v.x); t.us[1] = f2b(v.y); t.us[2] = f2b(v.z); t.us[3] = f2b(v.w);
    *(uint2*)&out[i * 4] = t.u;
}

// ---------------- bf16 MFMA GEMM: C[M,N] = A[M,K] @ B[K,N] (+bias)(+=C) ------
// Tile 64(M)x128(N), BK=32. 4 waves 2x2; wave tile 32x64 = 2x4 MFMA 16x16x32.
// A,B bf16 in global; no conversions in the K-loop.
__global__ void __launch_bounds__(256)
gemm_bf(const ushort_t* __restrict__ A, const ushort_t* __restrict__ Bw,
        const float* __restrict__ bias, float* __restrict__ C,
        int M, int K, int N, int accum) {
    __shared__ __align__(16) ushort_t As[64][40];
    __shared__ __align__(16) ushort_t Bs[128][40];
    int tid = threadIdx.x;
    int wave = tid >> 6, lane = tid & 63;
    int wm = wave >> 1, wn = wave & 1;
    int quad = lane >> 4, l16 = lane & 15;
    int m0 = blockIdx.y * 64, n0 = blockIdx.x * 128;
    floatx4 zero = {0.f, 0.f, 0.f, 0.f};
    floatx4 acc[2][4];
    #pragma unroll
    for (int i = 0; i < 2; i++)
        #pragma unroll
        for (int j = 0; j < 4; j++) acc[i][j] = zero;
    int ar = tid >> 2, ac = (tid & 3) * 8;       // A stage: 8 elems/thread
    int bn = tid & 127, bkg = (tid >> 7) * 16;   // B stage: 16 elems/thread
    for (int k0 = 0; k0 < K; k0 += 32) {
        *(uint4*)&As[ar][ac] = *(const uint4*)(A + (size_t)(m0 + ar) * K + k0 + ac);
        {
            const ushort_t* bp = Bw + (size_t)(k0 + bkg) * N + n0 + bn;
            union { ushort_t us[16]; uint4 v[2]; } t;
            #pragma unroll
            for (int i = 0; i < 16; i++) t.us[i] = bp[(size_t)i * N];
            *(uint4*)&Bs[bn][bkg] = t.v[0];
            *(uint4*)&Bs[bn][bkg + 8] = t.v[1];
        }
        __syncthreads();
        short8 af[2], bf[4];
        #pragma unroll
        for (int i = 0; i < 2; i++) af[i] = *(const short8*)&As[wm * 32 + i * 16 + l16][quad * 8];
        #pragma unroll
        for (int j = 0; j < 4; j++) bf[j] = *(const short8*)&Bs[wn * 64 + j * 16 + l16][quad * 8];
        #pragma unroll
        for (int i = 0; i < 2; i++)
            #pragma unroll
            for (int j = 0; j < 4; j++)
                acc[i][j] = __builtin_amdgcn_mfma_f32_16x16x32_bf16(af[i], bf[j], acc[i][j], 0, 0, 0);
        __syncthreads();
    }
    #pragma unroll
    for (int i = 0; i < 2; i++)
        #pragma unroll
        for (int j = 0; j < 4; j++)
            #pragma unroll
            for (int r = 0; r < 4; r++) {
                int row = m0 + wm * 32 + i * 16 + quad * 4 + r;
                int col = n0 + wn * 64 + j * 16 + l16;
                float o = acc[i][j][r];
                if (bias) o += bias[col];
                float* cp = &C[(size_t)row * N + col];
                if (accum) o += *cp;
                *cp = o;
            }
}

// ---------------- fp32-A MFMA GEMM (embed only) ------------------------------
__global__ void __launch_bounds__(256)
gemm_mfma(const float* __restrict__ A, const float* __restrict__ Bw,
          const float* __restrict__ bias, float* __restrict__ C,
          int M, int K, int N, int accum) {
    __shared__ __align__(16) ushort_t As[64][40];
    __shared__ __align__(16) ushort_t Bs[64][40];
    int tid = threadIdx.x;
    int wave = tid >> 6, lane = tid & 63;
    int wm = wave >> 1, wn = wave & 1;
    int quad = lane >> 4, l16 = lane & 15;
    int m0 = blockIdx.y * 64, n0 = blockIdx.x * 64;
    floatx4 zero = {0.f, 0.f, 0.f, 0.f};
    floatx4 acc[2][2];
    acc[0][0] = zero; acc[0][1] = zero; acc[1][0] = zero; acc[1][1] = zero;
    int ar = tid >> 2, ac = (tid & 3) * 8;
    int bn = tid & 63, bk = (tid >> 6) * 8;
    for (int k0 = 0; k0 < K; k0 += 32) {
        {
            const float* ap = A + (size_t)(m0 + ar) * K + k0 + ac;
            union { ushort_t us[8]; uint4 v; } t;
            #pragma unroll
            for (int i = 0; i < 8; i++) t.us[i] = f2b(ap[i]);
            *(uint4*)&As[ar][ac] = t.v;
        }
        {
            const float* bp = Bw + (size_t)(k0 + bk) * N + n0 + bn;
            union { ushort_t us[8]; uint4 v; } t;
            #pragma unroll
            for (int i = 0; i < 8; i++) t.us[i] = f2b(bp[(size_t)i * N]);
            *(uint4*)&Bs[bn][bk] = t.v;
        }
        __syncthreads();
        short8 af[2], bf[2];
        #pragma unroll
        for (int i = 0; i < 2; i++) af[i] = *(const short8*)&As[wm * 32 + i * 16 + l16][quad * 8];
        #pragma unroll
        for (int j = 0; j < 2; j++) bf[j] = *(const short8*)&Bs[wn * 32 + j * 16 + l16][quad * 8];
        #pragma unroll
        for (int i = 0; i < 2; i++)
            #pragma unroll
            for (int j = 0; j < 2; j++)
                acc[i][j] = __builtin_amdgcn_mfma_f32_16x16x32_bf16(af[i], bf[j], acc[i][j], 0, 0, 0);
        __syncthreads();
    }
    #pragma unroll
    for (int i = 0; i < 2; i++)
        #pragma unroll
        for (int j = 0; j < 2; j++)
            #pragma unroll
            for (int r = 0; r < 4; r++) {
                int row = m0 + wm * 32 + i * 16 + quad * 4 + r;
                int col = n0 + wn * 32 + j * 16 + l16;
                float o = acc[i][j][r];
                if (bias) o += bias[col];
                float* cp = &C[(size_t)row * N + col];
                if (accum) o += *cp;
                *cp = o;
            }
}

// ---------------- sLSTM Wx as block-diagonal MFMA GEMM (bf16 A) --------------
__global__ void __launch_bounds__(256)
slstm_wx_mfma(const ushort_t* __restrict__ xc, const ushort_t* __restrict__ xln,
              const float* __restrict__ gw, float* __restrict__ Wx) {
    __shared__ __align__(16) ushort_t As[64][40];
    __shared__ __align__(16) ushort_t Bs[64][40];
    int gh = blockIdx.y; int g = gh >> 2, hh = gh & 3;
    const ushort_t* src = (g < 2) ? xc : xln;
    const float* w = gw + (size_t)gh * 4096;
    int tid = threadIdx.x;
    int wave = tid >> 6, lane = tid & 63;
    int wm = wave >> 1, wn = wave & 1;
    int quad = lane >> 4, l16 = lane & 15;
    int m0 = blockIdx.x * 64;
    floatx4 zero = {0.f, 0.f, 0.f, 0.f};
    floatx4 acc[2][2];
    acc[0][0] = zero; acc[0][1] = zero; acc[1][0] = zero; acc[1][1] = zero;
    int ar = tid >> 2, ac = (tid & 3) * 8;
    int bn = tid & 63, bk = (tid >> 6) * 8;
    #pragma unroll
    for (int kt = 0; kt < 2; kt++) {
        int k0 = kt * 32;
        *(uint4*)&As[ar][ac] = *(const uint4*)(src + (size_t)(m0 + ar) * 256 + hh * 64 + k0 + ac);
        {
            const float* bp = w + (size_t)bn * 64 + k0 + bk;
            union { ushort_t us[8]; uint4 v; } t;
            #pragma unroll
            for (int i = 0; i < 8; i++) t.us[i] = f2b(bp[i]);
            *(uint4*)&Bs[bn][bk] = t.v;
        }
        __syncthreads();
        short8 af[2], bf[2];
        #pragma unroll
        for (int i = 0; i < 2; i++) af[i] = *(const short8*)&As[wm * 32 + i * 16 + l16][quad * 8];
        #pragma unroll
        for (int j = 0; j < 2; j++) bf[j] = *(const short8*)&Bs[wn * 32 + j * 16 + l16][quad * 8];
        #pragma unroll
        for (int i = 0; i < 2; i++)
            #pragma unroll
            for (int j = 0; j < 2; j++)
                acc[i][j] = __builtin_amdgcn_mfma_f32_16x16x32_bf16(af[i], bf[j], acc[i][j], 0, 0, 0);
        __syncthreads();
    }
    #pragma unroll
    for (int i = 0; i < 2; i++)
        #pragma unroll
        for (int j = 0; j < 2; j++)
            #pragma unroll
            for (int r = 0; r < 4; r++) {
                int row = m0 + wm * 32 + i * 16 + quad * 4 + r;
                int col = wn * 32 + j * 16 + l16;
                Wx[(size_t)row * 1024 + g * 256 + hh * 64 + col] = acc[i][j][r];
            }
}

// ---------------- layernorm over 256, bf16 output ----------------------------
__global__ void __launch_bounds__(256)
layernorm256(const float* __restrict__ x, const float* __restrict__ w, ushort_t* __restrict__ y) {
    int n = blockIdx.x, t = threadIdx.x;
    float v = x[(size_t)n * 256 + t];
    float s = v, s2 = v * v;
    #pragma unroll
    for (int off = 32; off; off >>= 1) { s += __shfl_xor(s, off); s2 += __shfl_xor(s2, off); }
    __shared__ float ps[4], ps2[4];
    if ((t & 63) == 0) { ps[t >> 6] = s; ps2[t >> 6] = s2; }
    __syncthreads();
    float S = ps[0] + ps[1] + ps[2] + ps[3];
    float S2 = ps2[0] + ps2[1] + ps2[2] + ps2[3];
    float mu = S / 256.f, var = S2 / 256.f - mu * mu;
    y[(size_t)n * 256 + t] = f2b((v - mu) * rsqrtf(var + 1e-5f) * w[t]);
}

// ---------------- post-LN + selu (fp32 out) ---------------------------------
__global__ void __launch_bounds__(256)
postln_selu(const float* __restrict__ x, const float* __restrict__ w, float* __restrict__ y) {
    int n = blockIdx.x, t = threadIdx.x;
    float v = x[(size_t)n * 256 + t];
    float s = v, s2 = v * v;
    #pragma unroll
    for (int off = 32; off; off >>= 1) { s += __shfl_xor(s, off); s2 += __shfl_xor(s2, off); }
    __shared__ float ps[4], ps2[4];
    if ((t & 63) == 0) { ps[t >> 6] = s; ps2[t >> 6] = s2; }
    __syncthreads();
    float S = ps[0] + ps[1] + ps[2] + ps[3];
    float S2 = ps2[0] + ps2[1] + ps2[2] + ps2[3];
    float mu = S / 256.f, var = S2 / 256.f - mu * mu;
    float yn = (v - mu) * rsqrtf(var + 1e-5f) * w[t];
    y[(size_t)n * 256 + t] = 1.0507009873554805f * (yn > 0.f ? yn : 1.6732632423543772f * (expf(yn) - 1.f));
}

// ---------------- mLSTM: causal conv (512 ch) + silu -------------------------
__global__ void conv_silu_m(const float* __restrict__ xi, const float* __restrict__ cw,
                            const float* __restrict__ cb, float* __restrict__ xca) {
    int idx = blockIdx.x * blockDim.x + threadIdx.x;
    if (idx >= NTOK * 512) return;
    int n = idx >> 9, c = idx & 511;
    int b = n / S_, s = n - b * S_;
    float y = cb[c];
    #pragma unroll
    for (int i = 0; i < 4; i++) {
        int sp = s - 3 + i;
        if (sp >= 0) y += xi[(size_t)(b * S_ + sp) * 1024 + c] * cw[c * 4 + i];
    }
    xca[idx] = siluf_(y);
}

// ---------------- mLSTM: block-diagonal headwise q,k,v -----------------------
__global__ void headwise_qkv(const float* __restrict__ xca, const float* __restrict__ xi,
                             const float* __restrict__ qw, const float* __restrict__ kw,
                             const float* __restrict__ vw,
                             float* __restrict__ qb, float* __restrict__ kb, float* __restrict__ vb) {
    int idx = blockIdx.x * blockDim.x + threadIdx.x;
    if (idx >= NTOK * 512) return;
    int n = idx >> 9, c = idx & 511;
    int hh = c >> 2, o = c & 3;
    float aq = 0, ak = 0, av = 0;
    #pragma unroll
    for (int d = 0; d < 4; d++) {
        float xc = xca[(size_t)n * 512 + hh * 4 + d];
        float xm = xi[(size_t)n * 1024 + hh * 4 + d];
        int wi = (hh * 4 + o) * 4 + d;
        aq += xc * qw[wi]; ak += xc * kw[wi]; av += xm * vw[wi];
    }
    qb[idx] = aq; kb[idx] = ak; vb[idx] = av;
}

// ---------------- mLSTM: ig/fg gates -----------------------------------------
__global__ void __launch_bounds__(256)
mlstm_gates(const float* __restrict__ qb, const float* __restrict__ kb, const float* __restrict__ vb,
            const float* __restrict__ igw, const float* __restrict__ igbias,
            const float* __restrict__ fgw, const float* __restrict__ fgbias,
            float* __restrict__ igo, float* __restrict__ fgo) {
    int gid = blockIdx.x * 256 + threadIdx.x;
    int wid = gid >> 6, lane = gid & 63;
    int which = wid & 1, hd = (wid >> 1) & 3, n = wid >> 3;
    if (n >= NTOK) return;
    const float* w = (which ? fgw : igw) + hd * 1536;
    float a = 0.f;
    for (int j = lane; j < 512; j += 64) {
        a += qb[(size_t)n * 512 + j] * w[j]
           + kb[(size_t)n * 512 + j] * w[512 + j]
           + vb[(size_t)n * 512 + j] * w[1024 + j];
    }
    #pragma unroll
    for (int off = 32; off; off >>= 1) a += __shfl_xor(a, off);
    if (lane == 0) {
        a += (which ? fgbias : igbias)[hd];
        (which ? fgo : igo)[(size_t)n * 4 + hd] = a;
    }
}

// ---------------- mLSTM: cumsum + prefix-max, wave-parallel shfl scan --------
__global__ void __launch_bounds__(256)
mlstm_cumsum(const float* __restrict__ fgo, const float* __restrict__ igo,
             float* __restrict__ lfc, float* __restrict__ Mx) {
    int bh = blockIdx.x * 4 + (threadIdx.x >> 6);
    int lane = threadIdx.x & 63;
    int b = bh >> 2, h = bh & 3;
    float v[4]; float lsum = 0.f;
    #pragma unroll
    for (int i = 0; i < 4; i++) {
        int s = lane * 4 + i;
        float f = (s < S_) ? fgo[(size_t)(b * S_ + s) * 4 + h] : 0.f;
        lsum += logsigf_(f);
        v[i] = lsum;
    }
    float x = lsum;
    #pragma unroll
    for (int off = 1; off < 64; off <<= 1) {
        float y = __shfl_up(x, off);
        if (lane >= off) x += y;
    }
    float excl = x - lsum;
    float lf1[4];
    #pragma unroll
    for (int i = 0; i < 4; i++) lf1[i] = excl + v[i];
    if (lane == 0) lfc[bh * (S_ + 1)] = 0.f;
    #pragma unroll
    for (int i = 0; i < 4; i++) {
        int s = lane * 4 + i;
        if (s < S_) lfc[bh * (S_ + 1) + s + 1] = lf1[i];
    }
    float gm[4]; float lmax = -1e30f;
    #pragma unroll
    for (int i = 0; i < 4; i++) {
        int s = lane * 4 + i;
        float ig_ = (s < S_) ? igo[(size_t)(b * S_ + s) * 4 + h] : -1e30f;
        float gg = ig_ - lf1[i];
        lmax = fmaxf(lmax, gg);
        gm[i] = lmax;
    }
    float xm = lmax;
    #pragma unroll
    for (int off = 1; off < 64; off <<= 1) {
        float y = __shfl_up(xm, off);
        if (lane >= off) xm = fmaxf(xm, y);
    }
    float exclm = __shfl_up(xm, 1);
    if (lane == 0) exclm = -1e30f;
    #pragma unroll
    for (int i = 0; i < 4; i++) {
        int s = lane * 4 + i;
        if (s < S_) Mx[bh * S_ + s] = fmaxf(exclm, gm[i]);
    }
}

// ---------------- mLSTM attention: MFMA flash-style, one block per (b,h) -----
__global__ void __launch_bounds__(256, 1)
mlstm_attn_mfma(const float* __restrict__ qb, const float* __restrict__ kb, const float* __restrict__ vb,
                const float* __restrict__ igb, const float* __restrict__ lfc, const float* __restrict__ Mx,
                float* __restrict__ outb) {
    __shared__ __align__(16) ushort_t Kb[64 * 136];
    __shared__ __align__(16) ushort_t Vt[128 * 72];
    __shared__ __align__(16) ushort_t Pw[4][16 * 72];
    __shared__ float gv[208], lfv[208], mxv[208];
    int bh = blockIdx.x; int b = bh >> 2, h = bh & 3;
    int tid = threadIdx.x, wave = tid >> 6, lane = tid & 63;
    int quad = lane >> 4, l16 = lane & 15;
    if (tid < 208) {
        if (tid < S_) {
            float lf1 = lfc[bh * (S_ + 1) + tid + 1];
            gv[tid] = igb[(size_t)(b * S_ + tid) * 4 + h] - lf1;
            lfv[tid] = lf1;
            mxv[tid] = Mx[bh * S_ + tid];
        } else { gv[tid] = 0.f; lfv[tid] = 0.f; mxv[tid] = 0.f; }
    }
    floatx4 zero = {0.f, 0.f, 0.f, 0.f};
    float rs[4][4];
    floatx4 accv[4][8];
    #pragma unroll
    for (int qi = 0; qi < 4; qi++) {
        #pragma unroll
        for (int r = 0; r < 4; r++) rs[qi][r] = 0.f;
        #pragma unroll
        for (int dt = 0; dt < 8; dt++) accv[qi][dt] = zero;
    }
    const float scale = 0.08838834764831845f;
    int trow = tid >> 4, d0 = (tid & 15) * 8;
    for (int c = 0; c < 4; c++) {
        __syncthreads();
        #pragma unroll
        for (int i = 0; i < 4; i++) {
            int tl = trow + 16 * i;
            int t = c * 64 + tl;
            union { ushort_t us[8]; uint4 v; } kk;
            ushort_t vv[8];
            if (t < S_) {
                const float* kp = kb + (size_t)(b * S_ + t) * 512 + h * 128 + d0;
                const float* vp = vb + (size_t)(b * S_ + t) * 512 + h * 128 + d0;
                #pragma unroll
                for (int ii = 0; ii < 8; ii++) { kk.us[ii] = f2b(kp[ii]); vv[ii] = f2b(vp[ii]); }
            } else {
                kk.v = (uint4){0, 0, 0, 0};
                #pragma unroll
                for (int ii = 0; ii < 8; ii++) vv[ii] = 0;
            }
            *(uint4*)&Kb[tl * 136 + d0] = kk.v;
            #pragma unroll
            for (int ii = 0; ii < 8; ii++) Vt[(d0 + ii) * 72 + tl] = vv[ii];
        }
        __syncthreads();
        for (int qi = 0; qi < 4; qi++) {
            int qt = wave + 4 * qi;
            if (qt >= NQT || qt < 4 * c) continue;
            uint4 z4 = {0, 0, 0, 0};
            for (int z = lane; z < 144; z += 64) ((uint4*)Pw[wave])[z] = z4;
            int srow = qt * 16 + l16;
            const float* qp = qb + (size_t)(b * S_ + min(srow, S_ - 1)) * 512 + h * 128 + quad * 8;
            short8 af[4];
            #pragma unroll
            for (int ks = 0; ks < 4; ks++) af[ks] = cvt8(qp + 32 * ks);
            int ktmax_l = min(qt, 4 * c + 3) - 4 * c;
            for (int ktl = 0; ktl <= ktmax_l; ktl++) {
                floatx4 acc = zero;
                #pragma unroll
                for (int ks = 0; ks < 4; ks++) {
                    short8 bf = *(const short8*)&Kb[(ktl * 16 + l16) * 136 + quad * 8 + 32 * ks];
                    acc = __builtin_amdgcn_mfma_f32_16x16x32_bf16(af[ks], bf, acc, 0, 0, 0);
                }
                int tcol = c * 64 + ktl * 16 + l16;
                float gt = gv[tcol];
                #pragma unroll
                for (int r = 0; r < 4; r++) {
                    int s = qt * 16 + quad * 4 + r;
                    bool valid = (tcol <= s) && (tcol < S_);
                    float w = valid ? expf(gt - mxv[s]) : 0.f;
                    float p = acc[r] * scale * w;
                    rs[qi][r] += p;
                    Pw[wave][(quad * 4 + r) * 72 + ktl * 16 + l16] = f2b(p);
                }
            }
            #pragma unroll
            for (int dt = 0; dt < 8; dt++) {
                floatx4 a = accv[qi][dt];
                #pragma unroll
                for (int ks = 0; ks < 2; ks++) {
                    short8 ap = *(const short8*)&Pw[wave][l16 * 72 + quad * 8 + 32 * ks];
                    short8 bp = *(const short8*)&Vt[(dt * 16 + l16) * 72 + quad * 8 + 32 * ks];
                    a = __builtin_amdgcn_mfma_f32_16x16x32_bf16(ap, bp, a, 0, 0, 0);
                }
                accv[qi][dt] = a;
            }
        }
    }
    for (int qi = 0; qi < 4; qi++) {
        int qt = wave + 4 * qi;
        if (qt >= NQT) continue;
        float nrm[4];
        #pragma unroll
        for (int r = 0; r < 4; r++) {
            float v = rs[qi][r];
            v += __shfl_xor(v, 1); v += __shfl_xor(v, 2);
            v += __shfl_xor(v, 4); v += __shfl_xor(v, 8);
            int s = qt * 16 + quad * 4 + r;
            nrm[r] = fmaxf(fabsf(v), expf(-(lfv[s] + mxv[s]))) + 1e-6f;
        }
        #pragma unroll
        for (int dt = 0; dt < 8; dt++)
            #pragma unroll
            for (int r = 0; r < 4; r++) {
                int s = qt * 16 + quad * 4 + r;
                if (s < S_)
                    outb[(size_t)(b * S_ + s) * 512 + h * 128 + dt * 16 + l16] = accv[qi][dt][r] / nrm[r];
            }
    }
}

// ---------------- mLSTM: per-head (128) layernorm, in place ------------------
__global__ void __launch_bounds__(512)
mhln_m(float* __restrict__ hatt, const float* __restrict__ w) {
    int n = blockIdx.x, t = threadIdx.x;
    float v = hatt[(size_t)n * 512 + t];
    float s = v, s2 = v * v;
    #pragma unroll
    for (int off = 32; off; off >>= 1) { s += __shfl_xor(s, off); s2 += __shfl_xor(s2, off); }
    __shared__ float ps[8], ps2[8];
    if ((t & 63) == 0) { ps[t >> 6] = s; ps2[t >> 6] = s2; }
    __syncthreads();
    int hd = t >> 7;
    float S = ps[hd * 2] + ps[hd * 2 + 1], S2 = ps2[hd * 2] + ps2[hd * 2 + 1];
    float mu = S / 128.f, var = S2 / 128.f - mu * mu;
    hatt[(size_t)n * 512 + t] = (v - mu) * rsqrtf(var + 1e-5f) * w[t];
}

// ---------------- mLSTM: h_state -> bf16 out ---------------------------------
__global__ void hstate_m(const float* __restrict__ hatt, const float* __restrict__ xca,
                         const float* __restrict__ xi, const float* __restrict__ skip,
                         ushort_t* __restrict__ out16) {
    int idx = blockIdx.x * blockDim.x + threadIdx.x;
    if (idx >= NTOK * 512) return;
    int n = idx >> 9, c = idx & 511;
    float z = xi[(size_t)n * 1024 + 512 + c];
    out16[idx] = f2b((hatt[idx] + skip[c] * xca[idx]) * siluf_(z));
}

// ---------------- sLSTM: causal conv (256 ch) + silu, bf16 in/out ------------
__global__ void conv_silu_s(const ushort_t* __restrict__ xln, const float* __restrict__ cw,
                            const float* __restrict__ cb, ushort_t* __restrict__ xc) {
    int idx = blockIdx.x * blockDim.x + threadIdx.x;
    if (idx >= NTOK * 256) return;
    int n = idx >> 8, c = idx & 255;
    int b = n / S_, s = n - b * S_;
    float y = cb[c];
    #pragma unroll
    for (int i = 0; i < 4; i++) {
        int sp = s - 3 + i;
        if (sp >= 0) y += bf2f(xln[(size_t)(b * S_ + sp) * 256 + c]) * cw[c * 4 + i];
    }
    xc[idx] = f2b(siluf_(y));
}

// ---------------- sLSTM: recurrence, split-K (512 thr, w[32]/thread) ---------
__global__ void __launch_bounds__(512)
slstm_rec(const float* __restrict__ Wx, const float* __restrict__ rw,
          const float* __restrict__ bias, float* __restrict__ ys) {
    int b = blockIdx.x >> 2, h = blockIdx.x & 3;
    int tid = threadIdx.x;
    int g = tid >> 7;            // gate
    int o = (tid >> 1) & 63;     // output dim
    int kh = tid & 1;            // k-half
    float w[32];
    const float* wp = rw + (size_t)(((g * 4 + h) * 64 + o)) * 64 + kh * 32;
    #pragma unroll
    for (int d = 0; d < 32; d++) w[d] = wp[d];
    float bi = bias[(g * 4 + h) * 64 + o];
    __shared__ __align__(16) float hs[64];
    __shared__ float raws[4][64];
    if (tid < 64) hs[tid] = 0.f;
    float c_ = 0.f, n_ = 0.f, m_ = 0.f;
    size_t wxbase = (size_t)(b * S_) * 1024 + g * 256 + h * 64 + o;
    float wx_cur = Wx[wxbase];
    __syncthreads();
    for (int s = 0; s < S_; s++) {
        float wx_next = (s + 1 < S_) ? Wx[wxbase + (size_t)(s + 1) * 1024] : 0.f;
        float a0 = 0.f, a1 = 0.f, a2 = 0.f, a3 = 0.f;
        const float* hb = hs + kh * 32;
        #pragma unroll
        for (int d4 = 0; d4 < 8; d4++) {
            float4 hv = *(const float4*)&hb[d4 * 4];
            a0 += hv.x * w[4 * d4 + 0];
            a1 += hv.y * w[4 * d4 + 1];
            a2 += hv.z * w[4 * d4 + 2];
            a3 += hv.w * w[4 * d4 + 3];
        }
        float a = (a0 + a1) + (a2 + a3);
        a += __shfl_xor(a, 1);
        if (kh == 0) raws[g][o] = a + wx_cur + bi;
        __syncthreads();
        float ir = raws[0][o], fr = raws[1][o], zr = raws[2][o], orr = raws[3][o];
        float lfpm = m_ + logsigf_(fr);
        float mn = fmaxf(ir, lfpm);
        float ig = expf(ir - mn), fg = expf(lfpm - mn);
        c_ = fg * c_ + ig * tanhf(zr);
        n_ = fg * n_ + ig;
        m_ = mn;
        float hn = sigmoidf_(orr) * (c_ / n_);
        if (g == 0 && kh == 0) {
            hs[o] = hn;
            ys[(size_t)(b * S_ + s) * 256 + h * 64 + o] = hn;
        }
        __syncthreads();
        wx_cur = wx_next;
    }
}

// ---------------- sLSTM: per-head (64) groupnorm + residual add --------------
__global__ void __launch_bounds__(256)
mhln_s_resid(const float* __restrict__ ys, const float* __restrict__ w, float* __restrict__ h) {
    int n = blockIdx.x, t = threadIdx.x;
    float v = ys[(size_t)n * 256 + t];
    float s = v, s2 = v * v;
    #pragma unroll
    for (int off = 32; off; off >>= 1) { s += __shfl_xor(s, off); s2 += __shfl_xor(s2, off); }
    float mu = s / 64.f, var = s2 / 64.f - mu * mu;
    h[(size_t)n * 256 + t] += (v - mu) * rsqrtf(var + 1e-5f) * w[t];
}

// ---------------- FFN: gelu(gate)*up -> bf16 ---------------------------------
__global__ void ffn_act(const float* __restrict__ up, ushort_t* __restrict__ act) {
    int idx = blockIdx.x * blockDim.x + threadIdx.x;
    if (idx >= NTOK * 384) return;
    int n = idx / 384, j = idx - n * 384;
    float g = up[(size_t)n * 768 + j], u = up[(size_t)n * 768 + 384 + j];
    float t = tanhf(0.7978845608028654f * (g + 0.044715f * g * g * g));
    act[idx] = f2b(0.5f * g * (1.f + t) * u);
}

// ---------------- pooling + heads --------------------------------------------
__global__ void pool_k(const float* __restrict__ a, float* __restrict__ pooled) {
    int b = blockIdx.x, e = threadIdx.x;
    float s = 0.f;
    for (int t = 0; t < S_; t++) s += a[(size_t)(b * S_ + t) * 256 + e];
    pooled[b * 256 + e] = s / (float)S_;
}

__global__ void heads_k(const float* __restrict__ pooled,
                        const float* __restrict__ we, const float* __restrict__ be,
                        const float* __restrict__ ws, const float* __restrict__ bs,
                        float* __restrict__ out) {
    int i = blockIdx.x * blockDim.x + threadIdx.x;
    if (i < B_ * 7) {
        int b = i / 7, o = i - b * 7;
        float a = be[o];
        for (int e = 0; e < 256; e++) a += pooled[b * 256 + e] * we[e * 7 + o];
        out[b * 7 + o] = a;
    } else if (i < B_ * 7 + B_ * 3) {
        int j = i - B_ * 7;
        int b = j / 3, o = j - b * 3;
        float a = bs[o];
        for (int e = 0; e < 256; e++) a += pooled[b * 256 + e] * ws[e * 3 + o];
        out[B_ * 7 + b * 3 + o] = a;
    }
}

// =============================================================================
extern "C" void kernel_launch(void* const* d_in, const int* in_sizes, int n_in,
                              void* d_out, int out_size, void* d_ws, size_t ws_size,
                              hipStream_t stream) {
    (void)in_sizes; (void)n_in; (void)out_size; (void)ws_size;
    const float* x          = (const float*)d_in[0];
    const float* w_down     = (const float*)d_in[1];
    const float* b_down     = (const float*)d_in[2];
    const float* m_ln_w     = (const float*)d_in[3];
    const float* m_proj_up  = (const float*)d_in[4];
    const float* m_conv_w   = (const float*)d_in[5];
    const float* m_conv_b   = (const float*)d_in[6];
    const float* m_q_w      = (const float*)d_in[7];
    const float* m_k_w      = (const float*)d_in[8];
    const float* m_v_w      = (const float*)d_in[9];
    const float* m_ig_w     = (const float*)d_in[10];
    const float* m_ig_b     = (const float*)d_in[11];
    const float* m_fg_w     = (const float*)d_in[12];
    const float* m_fg_b     = (const float*)d_in[13];
    const float* m_skip     = (const float*)d_in[14];
    const float* m_outnorm  = (const float*)d_in[15];
    const float* m_proj_dn  = (const float*)d_in[16];
    const float* s_ln_w     = (const float*)d_in[17];
    const float* s_conv_w   = (const float*)d_in[18];
    const float* s_conv_b   = (const float*)d_in[19];
    const float* s_gate_w   = (const float*)d_in[20];
    const float* s_rec_w    = (const float*)d_in[21];
    const float* s_bias     = (const float*)d_in[22];
    const float* s_gn_w     = (const float*)d_in[23];
    const float* s_ln2_w    = (const float*)d_in[24];
    const float* s_ffn_up   = (const float*)d_in[25];
    const float* s_ffn_dn   = (const float*)d_in[26];
    const float* post_ln_w  = (const float*)d_in[27];
    const float* w_emo      = (const float*)d_in[28];
    const float* b_emo      = (const float*)d_in[29];
    const float* w_sen      = (const float*)d_in[30];
    const float* b_sen      = (const float*)d_in[31];

    float* W    = (float*)d_ws;
    float* h    = W;
    float* lnb  = h    + (size_t)NTOK * 256;
    float* big0 = lnb  + (size_t)NTOK * 256;
    float* xca  = big0 + (size_t)NTOK * 1024;
    float* qb   = xca  + (size_t)NTOK * 512;
    float* kb   = qb   + (size_t)NTOK * 512;
    float* vb   = kb   + (size_t)NTOK * 512;
    float* hatt = vb   + (size_t)NTOK * 512;
    float* igo  = hatt + (size_t)NTOK * 512;
    float* fgo  = igo  + (size_t)NTOK * 4;
    float* lfcb = fgo  + (size_t)NTOK * 4;
    float* Mxb  = lfcb + (size_t)256 * (S_ + 1);
    float* pooled = Mxb + (size_t)256 * S_;
    // bf16 overlays / pack region
    ushort_t* lnb16 = (ushort_t*)lnb;                  // N*256 bf16 (LN out)
    ushort_t* hat16 = (ushort_t*)kb;                   // N*512 bf16 (gemm-A; kb free by then)
    ushort_t* xc16  = (ushort_t*)vb;                   // N*256 bf16 (sLSTM conv out)
    ushort_t* wpk   = (ushort_t*)(pooled + 64 * 256);  // packed weights, ~2.56M bf16
    ushort_t* wp_pu = wpk;                             // 5*256*1024
    ushort_t* wp_pd = wp_pu + 5 * 262144;              // 5*512*256
    ushort_t* wp_fu = wp_pd + 5 * 131072;              // 2*256*768
    ushort_t* wp_fd = wp_fu + 2 * 196608;              // 2*384*256

    // pack weights to bf16 (same work every call; graph-safe)
    cvt_bf<<<(5 * 262144 / 4 + 255) / 256, 256, 0, stream>>>(m_proj_up, wp_pu, 5 * 262144 / 4);
    cvt_bf<<<(5 * 131072 / 4 + 255) / 256, 256, 0, stream>>>(m_proj_dn, wp_pd, 5 * 131072 / 4);
    cvt_bf<<<(2 * 196608 / 4 + 255) / 256, 256, 0, stream>>>(s_ffn_up, wp_fu, 2 * 196608 / 4);
    cvt_bf<<<(2 * 98304 / 4 + 255) / 256, 256, 0, stream>>>(s_ffn_dn, wp_fd, 2 * 98304 / 4);

    gemm_mfma<<<dim3(256 / 64, NTOK / 64), 256, 0, stream>>>(x, w_down, b_down, h, NTOK, 1024, 256, 0);

    int mi = 0, si = 0;
    for (int blk = 0; blk < 7; blk++) {
        if (blk == 1 || blk == 4) {
            layernorm256<<<NTOK, 256, 0, stream>>>(h, s_ln_w + si * 256, lnb16);
            conv_silu_s<<<(NTOK * 256 + 255) / 256, 256, 0, stream>>>(lnb16, s_conv_w + si * 1024, s_conv_b + si * 256, xc16);
            slstm_wx_mfma<<<dim3(NTOK / 64, 16), 256, 0, stream>>>(xc16, lnb16, s_gate_w + (size_t)si * 65536, big0);
            slstm_rec<<<256, 512, 0, stream>>>(big0, s_rec_w + (size_t)si * 65536, s_bias + si * 1024, hatt);
            mhln_s_resid<<<NTOK, 256, 0, stream>>>(hatt, s_gn_w + si * 256, h);
            layernorm256<<<NTOK, 256, 0, stream>>>(h, s_ln2_w + si * 256, lnb16);
            gemm_bf<<<dim3(768 / 128, NTOK / 64), 256, 0, stream>>>(lnb16, wp_fu + (size_t)si * 196608, nullptr, big0, NTOK, 256, 768, 0);
            ffn_act<<<(NTOK * 384 + 255) / 256, 256, 0, stream>>>(big0, hat16);
            gemm_bf<<<dim3(256 / 128, NTOK / 64), 256, 0, stream>>>(hat16, wp_fd + (size_t)si * 98304, nullptr, h, NTOK, 384, 256, 1);
            si++;
        } else {
            layernorm256<<<NTOK, 256, 0, stream>>>(h, m_ln_w + mi * 256, lnb16);
            gemm_bf<<<dim3(1024 / 128, NTOK / 64), 256, 0, stream>>>(lnb16, wp_pu + (size_t)mi * 262144, nullptr, big0, NTOK, 256, 1024, 0);
            conv_silu_m<<<(NTOK * 512 + 255) / 256, 256, 0, stream>>>(big0, m_conv_w + mi * 2048, m_conv_b + mi * 512, xca);
            headwise_qkv<<<(NTOK * 512 + 255) / 256, 256, 0, stream>>>(xca, big0, m_q_w + mi * 2048, m_k_w + mi * 2048, m_v_w + mi * 2048, qb, kb, vb);
            mlstm_gates<<<NTOK * 2, 256, 0, stream>>>(qb, kb, vb, m_ig_w + mi * 6144, m_ig_b + mi * 4, m_fg_w + mi * 6144, m_fg_b + mi * 4, igo, fgo);
            mlstm_cumsum<<<64, 256, 0, stream>>>(fgo, igo, lfcb, Mxb);
            mlstm_attn_mfma<<<256, 256, 0, stream>>>(qb, kb, vb, igo, lfcb, Mxb, hatt);
            mhln_m<<<NTOK, 512, 0, stream>>>(hatt, m_outnorm + mi * 512);
            hstate_m<<<(NTOK * 512 + 255) / 256, 256, 0, stream>>>(hatt, xca, big0, m_skip + mi * 512, hat16);
            gemm_bf<<<dim3(256 / 128, NTOK / 64), 256, 0, stream>>>(hat16, wp_pd + (size_t)mi * 131072, nullptr, h, NTOK, 512, 256, 1);
            mi++;
        }
    }

    postln_selu<<<NTOK, 256, 0, stream>>>(h, post_ln_w, xca);
    pool_k<<<B_, 256, 0, stream>>>(xca, pooled);
    heads_k<<<3, 256, 0, stream>>>(pooled, w_emo, b_emo, w_sen, b_sen, (float*)d_out);
}

// Round 7
// 1988.798 us; speedup vs baseline: 3.1655x; 1.1512x over previous
//
#include <hip/hip_runtime.h>
#include <hip/hip_bf16.h>
#include <math.h>

// AudioModelV3: 7-block xLSTM (blocks 1,4 = sLSTM+FFN; others mLSTM).
// R7: (1) slstm_rec weights -> LDS (compiler refused VGPR residency twice:
// VGPR_Count 56 w/ w[64], 36 w/ w[32] => it streams from L2 every step).
// (2) bf16 q/k/v + fusions: conv+headwise -> fused_qkv; gates read row once;
// mhln+hstate fused, writes bf16 GEMM input.

#define B_    64
#define S_    199
#define E_    256
#define NTOK  (B_*S_)          // 12736
#define NQT   13               // ceil(199/16)

typedef __attribute__((ext_vector_type(8))) short short8;
typedef __attribute__((ext_vector_type(4))) float floatx4;
typedef unsigned short ushort_t;

__device__ __forceinline__ float sigmoidf_(float x) { return 1.f / (1.f + expf(-x)); }
__device__ __forceinline__ float siluf_(float x) { return x / (1.f + expf(-x)); }
__device__ __forceinline__ float logsigf_(float x) { return fminf(x, 0.f) - log1pf(expf(-fabsf(x))); }

__device__ __forceinline__ ushort_t f2b(float f) {   // fp32 -> bf16 (RNE)
    union { float f; unsigned u; } v; v.f = f;
    unsigned r = (v.u + 0x7fffu + ((v.u >> 16) & 1u)) >> 16;
    return (ushort_t)r;
}
__device__ __forceinline__ float bf2f(ushort_t u) {
    union { unsigned u; float f; } v; v.u = ((unsigned)u) << 16;
    return v.f;
}
__device__ __forceinline__ void unp2(unsigned d, float& lo, float& hi) {
    union { unsigned u; float f; } a, b;
    a.u = d << 16; b.u = d & 0xffff0000u;
    lo = a.f; hi = b.f;
}

// ---------------- fp32 -> bf16 convert (weight pack) -------------------------
__global__ void cvt_bf(const float* __restrict__ in, ushort_t* __restrict__ out, int n4) {
    int i = blockIdx.x * 256 + threadIdx.x;
    if (i >= n4) return;
    float4 v = *(const float4*)&in[i * 4];
    union { ushort_t us[4]; uint2 u; } t;
    t.us[0] = f2b(v.x); t.us[1] = f2b(v.y); t.us[2] = f2b(v.z); t.us[3] = f2b(v.w);
    *(uint2*)&out[i * 4] = t.u;
}

// ---------------- bf16 MFMA GEMM: C[M,N] = A[M,K] @ B[K,N] (+bias)(+=C) ------
__global__ void __launch_bounds__(256)
gemm_bf(const ushort_t* __restrict__ A, const ushort_t* __restrict__ Bw,
        const float* __restrict__ bias, float* __restrict__ C,
        int M, int K, int N, int accum) {
    __shared__ __align__(16) ushort_t As[64][40];
    __shared__ __align__(16) ushort_t Bs[128][40];
    int tid = threadIdx.x;
    int wave = tid >> 6, lane = tid & 63;
    int wm = wave >> 1, wn = wave & 1;
    int quad = lane >> 4, l16 = lane & 15;
    int m0 = blockIdx.y * 64, n0 = blockIdx.x * 128;
    floatx4 zero = {0.f, 0.f, 0.f, 0.f};
    floatx4 acc[2][4];
    #pragma unroll
    for (int i = 0; i < 2; i++)
        #pragma unroll
        for (int j = 0; j < 4; j++) acc[i][j] = zero;
    int ar = tid >> 2, ac = (tid & 3) * 8;
    int bn = tid & 127, bkg = (tid >> 7) * 16;
    for (int k0 = 0; k0 < K; k0 += 32) {
        *(uint4*)&As[ar][ac] = *(const uint4*)(A + (size_t)(m0 + ar) * K + k0 + ac);
        {
            const ushort_t* bp = Bw + (size_t)(k0 + bkg) * N + n0 + bn;
            union { ushort_t us[16]; uint4 v[2]; } t;
            #pragma unroll
            for (int i = 0; i < 16; i++) t.us[i] = bp[(size_t)i * N];
            *(uint4*)&Bs[bn][bkg] = t.v[0];
            *(uint4*)&Bs[bn][bkg + 8] = t.v[1];
        }
        __syncthreads();
        short8 af[2], bf[4];
        #pragma unroll
        for (int i = 0; i < 2; i++) af[i] = *(const short8*)&As[wm * 32 + i * 16 + l16][quad * 8];
        #pragma unroll
        for (int j = 0; j < 4; j++) bf[j] = *(const short8*)&Bs[wn * 64 + j * 16 + l16][quad * 8];
        #pragma unroll
        for (int i = 0; i < 2; i++)
            #pragma unroll
            for (int j = 0; j < 4; j++)
                acc[i][j] = __builtin_amdgcn_mfma_f32_16x16x32_bf16(af[i], bf[j], acc[i][j], 0, 0, 0);
        __syncthreads();
    }
    #pragma unroll
    for (int i = 0; i < 2; i++)
        #pragma unroll
        for (int j = 0; j < 4; j++)
            #pragma unroll
            for (int r = 0; r < 4; r++) {
                int row = m0 + wm * 32 + i * 16 + quad * 4 + r;
                int col = n0 + wn * 64 + j * 16 + l16;
                float o = acc[i][j][r];
                if (bias) o += bias[col];
                float* cp = &C[(size_t)row * N + col];
                if (accum) o += *cp;
                *cp = o;
            }
}

// ---------------- fp32-A MFMA GEMM (embed only) ------------------------------
__global__ void __launch_bounds__(256)
gemm_mfma(const float* __restrict__ A, const float* __restrict__ Bw,
          const float* __restrict__ bias, float* __restrict__ C,
          int M, int K, int N, int accum) {
    __shared__ __align__(16) ushort_t As[64][40];
    __shared__ __align__(16) ushort_t Bs[64][40];
    int tid = threadIdx.x;
    int wave = tid >> 6, lane = tid & 63;
    int wm = wave >> 1, wn = wave & 1;
    int quad = lane >> 4, l16 = lane & 15;
    int m0 = blockIdx.y * 64, n0 = blockIdx.x * 64;
    floatx4 zero = {0.f, 0.f, 0.f, 0.f};
    floatx4 acc[2][2];
    acc[0][0] = zero; acc[0][1] = zero; acc[1][0] = zero; acc[1][1] = zero;
    int ar = tid >> 2, ac = (tid & 3) * 8;
    int bn = tid & 63, bk = (tid >> 6) * 8;
    for (int k0 = 0; k0 < K; k0 += 32) {
        {
            const float* ap = A + (size_t)(m0 + ar) * K + k0 + ac;
            union { ushort_t us[8]; uint4 v; } t;
            #pragma unroll
            for (int i = 0; i < 8; i++) t.us[i] = f2b(ap[i]);
            *(uint4*)&As[ar][ac] = t.v;
        }
        {
            const float* bp = Bw + (size_t)(k0 + bk) * N + n0 + bn;
            union { ushort_t us[8]; uint4 v; } t;
            #pragma unroll
            for (int i = 0; i < 8; i++) t.us[i] = f2b(bp[(size_t)i * N]);
            *(uint4*)&Bs[bn][bk] = t.v;
        }
        __syncthreads();
        short8 af[2], bf[2];
        #pragma unroll
        for (int i = 0; i < 2; i++) af[i] = *(const short8*)&As[wm * 32 + i * 16 + l16][quad * 8];
        #pragma unroll
        for (int j = 0; j < 2; j++) bf[j] = *(const short8*)&Bs[wn * 32 + j * 16 + l16][quad * 8];
        #pragma unroll
        for (int i = 0; i < 2; i++)
            #pragma unroll
            for (int j = 0; j < 2; j++)
                acc[i][j] = __builtin_amdgcn_mfma_f32_16x16x32_bf16(af[i], bf[j], acc[i][j], 0, 0, 0);
        __syncthreads();
    }
    #pragma unroll
    for (int i = 0; i < 2; i++)
        #pragma unroll
        for (int j = 0; j < 2; j++)
            #pragma unroll
            for (int r = 0; r < 4; r++) {
                int row = m0 + wm * 32 + i * 16 + quad * 4 + r;
                int col = n0 + wn * 32 + j * 16 + l16;
                float o = acc[i][j][r];
                if (bias) o += bias[col];
                float* cp = &C[(size_t)row * N + col];
                if (accum) o += *cp;
                *cp = o;
            }
}

// ---------------- sLSTM Wx as block-diagonal MFMA GEMM (bf16 A) --------------
__global__ void __launch_bounds__(256)
slstm_wx_mfma(const ushort_t* __restrict__ xc, const ushort_t* __restrict__ xln,
              const float* __restrict__ gw, float* __restrict__ Wx) {
    __shared__ __align__(16) ushort_t As[64][40];
    __shared__ __align__(16) ushort_t Bs[64][40];
    int gh = blockIdx.y; int g = gh >> 2, hh = gh & 3;
    const ushort_t* src = (g < 2) ? xc : xln;
    const float* w = gw + (size_t)gh * 4096;
    int tid = threadIdx.x;
    int wave = tid >> 6, lane = tid & 63;
    int wm = wave >> 1, wn = wave & 1;
    int quad = lane >> 4, l16 = lane & 15;
    int m0 = blockIdx.x * 64;
    floatx4 zero = {0.f, 0.f, 0.f, 0.f};
    floatx4 acc[2][2];
    acc[0][0] = zero; acc[0][1] = zero; acc[1][0] = zero; acc[1][1] = zero;
    int ar = tid >> 2, ac = (tid & 3) * 8;
    int bn = tid & 63, bk = (tid >> 6) * 8;
    #pragma unroll
    for (int kt = 0; kt < 2; kt++) {
        int k0 = kt * 32;
        *(uint4*)&As[ar][ac] = *(const uint4*)(src + (size_t)(m0 + ar) * 256 + hh * 64 + k0 + ac);
        {
            const float* bp = w + (size_t)bn * 64 + k0 + bk;
            union { ushort_t us[8]; uint4 v; } t;
            #pragma unroll
            for (int i = 0; i < 8; i++) t.us[i] = f2b(bp[i]);
            *(uint4*)&Bs[bn][bk] = t.v;
        }
        __syncthreads();
        short8 af[2], bf[2];
        #pragma unroll
        for (int i = 0; i < 2; i++) af[i] = *(const short8*)&As[wm * 32 + i * 16 + l16][quad * 8];
        #pragma unroll
        for (int j = 0; j < 2; j++) bf[j] = *(const short8*)&Bs[wn * 32 + j * 16 + l16][quad * 8];
        #pragma unroll
        for (int i = 0; i < 2; i++)
            #pragma unroll
            for (int j = 0; j < 2; j++)
                acc[i][j] = __builtin_amdgcn_mfma_f32_16x16x32_bf16(af[i], bf[j], acc[i][j], 0, 0, 0);
        __syncthreads();
    }
    #pragma unroll
    for (int i = 0; i < 2; i++)
        #pragma unroll
        for (int j = 0; j < 2; j++)
            #pragma unroll
            for (int r = 0; r < 4; r++) {
                int row = m0 + wm * 32 + i * 16 + quad * 4 + r;
                int col = wn * 32 + j * 16 + l16;
                Wx[(size_t)row * 1024 + g * 256 + hh * 64 + col] = acc[i][j][r];
            }
}

// ---------------- layernorm over 256, bf16 output ----------------------------
__global__ void __launch_bounds__(256)
layernorm256(const float* __restrict__ x, const float* __restrict__ w, ushort_t* __restrict__ y) {
    int n = blockIdx.x, t = threadIdx.x;
    float v = x[(size_t)n * 256 + t];
    float s = v, s2 = v * v;
    #pragma unroll
    for (int off = 32; off; off >>= 1) { s += __shfl_xor(s, off); s2 += __shfl_xor(s2, off); }
    __shared__ float ps[4], ps2[4];
    if ((t & 63) == 0) { ps[t >> 6] = s; ps2[t >> 6] = s2; }
    __syncthreads();
    float S = ps[0] + ps[1] + ps[2] + ps[3];
    float S2 = ps2[0] + ps2[1] + ps2[2] + ps2[3];
    float mu = S / 256.f, var = S2 / 256.f - mu * mu;
    y[(size_t)n * 256 + t] = f2b((v - mu) * rsqrtf(var + 1e-5f) * w[t]);
}

// ---------------- post-LN + selu (fp32 out) ---------------------------------
__global__ void __launch_bounds__(256)
postln_selu(const float* __restrict__ x, const float* __restrict__ w, float* __restrict__ y) {
    int n = blockIdx.x, t = threadIdx.x;
    float v = x[(size_t)n * 256 + t];
    float s = v, s2 = v * v;
    #pragma unroll
    for (int off = 32; off; off >>= 1) { s += __shfl_xor(s, off); s2 += __shfl_xor(s2, off); }
    __shared__ float ps[4], ps2[4];
    if ((t & 63) == 0) { ps[t >> 6] = s; ps2[t >> 6] = s2; }
    __syncthreads();
    float S = ps[0] + ps[1] + ps[2] + ps[3];
    float S2 = ps2[0] + ps2[1] + ps2[2] + ps2[3];
    float mu = S / 256.f, var = S2 / 256.f - mu * mu;
    float yn = (v - mu) * rsqrtf(var + 1e-5f) * w[t];
    y[(size_t)n * 256 + t] = 1.0507009873554805f * (yn > 0.f ? yn : 1.6732632423543772f * (expf(yn) - 1.f));
}

// ---------------- mLSTM: fused conv+silu+headwise qkv (bf16 out) -------------
// One thread per (n, hh): 4 conv channels + 4 q,k,v outputs each.
__global__ void __launch_bounds__(256)
fused_qkv(const float* __restrict__ xi, const float* __restrict__ cw,
          const float* __restrict__ cb,
          const float* __restrict__ qw, const float* __restrict__ kw,
          const float* __restrict__ vw,
          float* __restrict__ xca,
          ushort_t* __restrict__ q16, ushort_t* __restrict__ k16, ushort_t* __restrict__ v16) {
    int idx = blockIdx.x * 256 + threadIdx.x;
    if (idx >= NTOK * 128) return;
    int n = idx >> 7, hh = idx & 127;
    int b = n / S_, s = n - b * S_;
    int c0 = hh * 4;
    float4 hist[4];
    #pragma unroll
    for (int i = 0; i < 4; i++) {
        int sp = s - 3 + i;
        if (sp >= 0) hist[i] = *(const float4*)(xi + (size_t)(b * S_ + sp) * 1024 + c0);
        else hist[i] = (float4){0.f, 0.f, 0.f, 0.f};
    }
    float xm[4] = {hist[3].x, hist[3].y, hist[3].z, hist[3].w};
    float xc4[4];
    #pragma unroll
    for (int d = 0; d < 4; d++) {
        float y = cb[c0 + d];
        const float* cwp = cw + (c0 + d) * 4;
        y += hist[0].x * 0.f;  // (placeholder removed by compiler)
        float hv[4] = { d==0?hist[0].x:(d==1?hist[0].y:(d==2?hist[0].z:hist[0].w)),
                        d==0?hist[1].x:(d==1?hist[1].y:(d==2?hist[1].z:hist[1].w)),
                        d==0?hist[2].x:(d==1?hist[2].y:(d==2?hist[2].z:hist[2].w)),
                        xm[d] };
        #pragma unroll
        for (int i = 0; i < 4; i++) y += hv[i] * cwp[i];
        xc4[d] = siluf_(y);
    }
    *(float4*)(xca + (size_t)n * 512 + c0) = (float4){xc4[0], xc4[1], xc4[2], xc4[3]};
    union { ushort_t us[4]; uint2 u; } qo, ko, vo;
    #pragma unroll
    for (int o = 0; o < 4; o++) {
        const float* qp = qw + (c0 + o) * 4;
        const float* kp = kw + (c0 + o) * 4;
        const float* vp = vw + (c0 + o) * 4;
        float aq = 0.f, ak = 0.f, av = 0.f;
        #pragma unroll
        for (int d = 0; d < 4; d++) {
            aq += xc4[d] * qp[d];
            ak += xc4[d] * kp[d];
            av += xm[d] * vp[d];
        }
        qo.us[o] = f2b(aq); ko.us[o] = f2b(ak); vo.us[o] = f2b(av);
    }
    *(uint2*)(q16 + (size_t)n * 512 + c0) = qo.u;
    *(uint2*)(k16 + (size_t)n * 512 + c0) = ko.u;
    *(uint2*)(v16 + (size_t)n * 512 + c0) = vo.u;
}

// ---------------- mLSTM: ig/fg gates, one wave per token ---------------------
__global__ void __launch_bounds__(256)
gates2(const ushort_t* __restrict__ qb, const ushort_t* __restrict__ kb, const ushort_t* __restrict__ vb,
       const float* __restrict__ igw, const float* __restrict__ igbias,
       const float* __restrict__ fgw, const float* __restrict__ fgbias,
       float* __restrict__ igo, float* __restrict__ fgo) {
    int n = blockIdx.x * 4 + (threadIdx.x >> 6);
    int lane = threadIdx.x & 63;
    uint4 q4 = *(const uint4*)(qb + (size_t)n * 512 + lane * 8);
    uint4 k4 = *(const uint4*)(kb + (size_t)n * 512 + lane * 8);
    uint4 v4 = *(const uint4*)(vb + (size_t)n * 512 + lane * 8);
    float q[8], k[8], v[8];
    unp2(q4.x, q[0], q[1]); unp2(q4.y, q[2], q[3]); unp2(q4.z, q[4], q[5]); unp2(q4.w, q[6], q[7]);
    unp2(k4.x, k[0], k[1]); unp2(k4.y, k[2], k[3]); unp2(k4.z, k[4], k[5]); unp2(k4.w, k[6], k[7]);
    unp2(v4.x, v[0], v[1]); unp2(v4.y, v[2], v[3]); unp2(v4.z, v[4], v[5]); unp2(v4.w, v[6], v[7]);
    float acc[8];
    #pragma unroll
    for (int hd = 0; hd < 4; hd++)
        #pragma unroll
        for (int wh = 0; wh < 2; wh++) {
            const float* w = (wh ? fgw : igw) + hd * 1536 + lane * 8;
            float a = 0.f;
            #pragma unroll
            for (int i = 0; i < 8; i++) a += q[i] * w[i];
            #pragma unroll
            for (int i = 0; i < 8; i++) a += k[i] * w[512 + i];
            #pragma unroll
            for (int i = 0; i < 8; i++) a += v[i] * w[1024 + i];
            acc[hd * 2 + wh] = a;
        }
    #pragma unroll
    for (int t = 0; t < 8; t++) {
        float a = acc[t];
        #pragma unroll
        for (int off = 32; off; off >>= 1) a += __shfl_xor(a, off);
        if (lane == 0) {
            int hd = t >> 1, wh = t & 1;
            a += (wh ? fgbias : igbias)[hd];
            (wh ? fgo : igo)[(size_t)n * 4 + hd] = a;
        }
    }
}

// ---------------- mLSTM: cumsum + prefix-max, wave-parallel shfl scan --------
__global__ void __launch_bounds__(256)
mlstm_cumsum(const float* __restrict__ fgo, const float* __restrict__ igo,
             float* __restrict__ lfc, float* __restrict__ Mx) {
    int bh = blockIdx.x * 4 + (threadIdx.x >> 6);
    int lane = threadIdx.x & 63;
    int b = bh >> 2, h = bh & 3;
    float v[4]; float lsum = 0.f;
    #pragma unroll
    for (int i = 0; i < 4; i++) {
        int s = lane * 4 + i;
        float f = (s < S_) ? fgo[(size_t)(b * S_ + s) * 4 + h] : 0.f;
        lsum += logsigf_(f);
        v[i] = lsum;
    }
    float x = lsum;
    #pragma unroll
    for (int off = 1; off < 64; off <<= 1) {
        float y = __shfl_up(x, off);
        if (lane >= off) x += y;
    }
    float excl = x - lsum;
    float lf1[4];
    #pragma unroll
    for (int i = 0; i < 4; i++) lf1[i] = excl + v[i];
    if (lane == 0) lfc[bh * (S_ + 1)] = 0.f;
    #pragma unroll
    for (int i = 0; i < 4; i++) {
        int s = lane * 4 + i;
        if (s < S_) lfc[bh * (S_ + 1) + s + 1] = lf1[i];
    }
    float gm[4]; float lmax = -1e30f;
    #pragma unroll
    for (int i = 0; i < 4; i++) {
        int s = lane * 4 + i;
        float ig_ = (s < S_) ? igo[(size_t)(b * S_ + s) * 4 + h] : -1e30f;
        float gg = ig_ - lf1[i];
        lmax = fmaxf(lmax, gg);
        gm[i] = lmax;
    }
    float xm = lmax;
    #pragma unroll
    for (int off = 1; off < 64; off <<= 1) {
        float y = __shfl_up(xm, off);
        if (lane >= off) xm = fmaxf(xm, y);
    }
    float exclm = __shfl_up(xm, 1);
    if (lane == 0) exclm = -1e30f;
    #pragma unroll
    for (int i = 0; i < 4; i++) {
        int s = lane * 4 + i;
        if (s < S_) Mx[bh * S_ + s] = fmaxf(exclm, gm[i]);
    }
}

// ---------------- mLSTM attention: MFMA flash-style, bf16 inputs -------------
__global__ void __launch_bounds__(256, 1)
mlstm_attn_mfma(const ushort_t* __restrict__ qb, const ushort_t* __restrict__ kb, const ushort_t* __restrict__ vb,
                const float* __restrict__ igb, const float* __restrict__ lfc, const float* __restrict__ Mx,
                float* __restrict__ outb) {
    __shared__ __align__(16) ushort_t Kb[64 * 136];
    __shared__ __align__(16) ushort_t Vt[128 * 72];
    __shared__ __align__(16) ushort_t Pw[4][16 * 72];
    __shared__ float gv[208], lfv[208], mxv[208];
    int bh = blockIdx.x; int b = bh >> 2, h = bh & 3;
    int tid = threadIdx.x, wave = tid >> 6, lane = tid & 63;
    int quad = lane >> 4, l16 = lane & 15;
    if (tid < 208) {
        if (tid < S_) {
            float lf1 = lfc[bh * (S_ + 1) + tid + 1];
            gv[tid] = igb[(size_t)(b * S_ + tid) * 4 + h] - lf1;
            lfv[tid] = lf1;
            mxv[tid] = Mx[bh * S_ + tid];
        } else { gv[tid] = 0.f; lfv[tid] = 0.f; mxv[tid] = 0.f; }
    }
    floatx4 zero = {0.f, 0.f, 0.f, 0.f};
    float rs[4][4];
    floatx4 accv[4][8];
    #pragma unroll
    for (int qi = 0; qi < 4; qi++) {
        #pragma unroll
        for (int r = 0; r < 4; r++) rs[qi][r] = 0.f;
        #pragma unroll
        for (int dt = 0; dt < 8; dt++) accv[qi][dt] = zero;
    }
    const float scale = 0.08838834764831845f;
    int trow = tid >> 4, d0 = (tid & 15) * 8;
    for (int c = 0; c < 4; c++) {
        __syncthreads();
        #pragma unroll
        for (int i = 0; i < 4; i++) {
            int tl = trow + 16 * i;
            int t = c * 64 + tl;
            union { ushort_t us[8]; uint4 v; } kk, vv;
            if (t < S_) {
                kk.v = *(const uint4*)(kb + (size_t)(b * S_ + t) * 512 + h * 128 + d0);
                vv.v = *(const uint4*)(vb + (size_t)(b * S_ + t) * 512 + h * 128 + d0);
            } else {
                kk.v = (uint4){0, 0, 0, 0};
                vv.v = (uint4){0, 0, 0, 0};
            }
            *(uint4*)&Kb[tl * 136 + d0] = kk.v;
            #pragma unroll
            for (int ii = 0; ii < 8; ii++) Vt[(d0 + ii) * 72 + tl] = vv.us[ii];
        }
        __syncthreads();
        for (int qi = 0; qi < 4; qi++) {
            int qt = wave + 4 * qi;
            if (qt >= NQT || qt < 4 * c) continue;
            uint4 z4 = {0, 0, 0, 0};
            for (int z = lane; z < 144; z += 64) ((uint4*)Pw[wave])[z] = z4;
            int srow = qt * 16 + l16;
            const ushort_t* qp = qb + (size_t)(b * S_ + min(srow, S_ - 1)) * 512 + h * 128 + quad * 8;
            short8 af[4];
            #pragma unroll
            for (int ks = 0; ks < 4; ks++) af[ks] = *(const short8*)(qp + 32 * ks);
            int ktmax_l = min(qt, 4 * c + 3) - 4 * c;
            for (int ktl = 0; ktl <= ktmax_l; ktl++) {
                floatx4 acc = zero;
                #pragma unroll
                for (int ks = 0; ks < 4; ks++) {
                    short8 bf = *(const short8*)&Kb[(ktl * 16 + l16) * 136 + quad * 8 + 32 * ks];
                    acc = __builtin_amdgcn_mfma_f32_16x16x32_bf16(af[ks], bf, acc, 0, 0, 0);
                }
                int tcol = c * 64 + ktl * 16 + l16;
                float gt = gv[tcol];
                #pragma unroll
                for (int r = 0; r < 4; r++) {
                    int s = qt * 16 + quad * 4 + r;
                    bool valid = (tcol <= s) && (tcol < S_);
                    float w = valid ? expf(gt - mxv[s]) : 0.f;
                    float p = acc[r] * scale * w;
                    rs[qi][r] += p;
                    Pw[wave][(quad * 4 + r) * 72 + ktl * 16 + l16] = f2b(p);
                }
            }
            #pragma unroll
            for (int dt = 0; dt < 8; dt++) {
                floatx4 a = accv[qi][dt];
                #pragma unroll
                for (int ks = 0; ks < 2; ks++) {
                    short8 ap = *(const short8*)&Pw[wave][l16 * 72 + quad * 8 + 32 * ks];
                    short8 bp = *(const short8*)&Vt[(dt * 16 + l16) * 72 + quad * 8 + 32 * ks];
                    a = __builtin_amdgcn_mfma_f32_16x16x32_bf16(ap, bp, a, 0, 0, 0);
                }
                accv[qi][dt] = a;
            }
        }
    }
    for (int qi = 0; qi < 4; qi++) {
        int qt = wave + 4 * qi;
        if (qt >= NQT) continue;
        float nrm[4];
        #pragma unroll
        for (int r = 0; r < 4; r++) {
            float v = rs[qi][r];
            v += __shfl_xor(v, 1); v += __shfl_xor(v, 2);
            v += __shfl_xor(v, 4); v += __shfl_xor(v, 8);
            int s = qt * 16 + quad * 4 + r;
            nrm[r] = fmaxf(fabsf(v), expf(-(lfv[s] + mxv[s]))) + 1e-6f;
        }
        #pragma unroll
        for (int dt = 0; dt < 8; dt++)
            #pragma unroll
            for (int r = 0; r < 4; r++) {
                int s = qt * 16 + quad * 4 + r;
                if (s < S_)
                    outb[(size_t)(b * S_ + s) * 512 + h * 128 + dt * 16 + l16] = accv[qi][dt][r] / nrm[r];
            }
    }
}

// ---------------- mLSTM: fused per-head LN + h_state -> bf16 -----------------
__global__ void __launch_bounds__(512)
mhln_hstate(const float* __restrict__ hatt, const float* __restrict__ w,
            const float* __restrict__ xca, const float* __restrict__ xi,
            const float* __restrict__ skip, ushort_t* __restrict__ out16) {
    int n = blockIdx.x, t = threadIdx.x;
    float v = hatt[(size_t)n * 512 + t];
    float s = v, s2 = v * v;
    #pragma unroll
    for (int off = 32; off; off >>= 1) { s += __shfl_xor(s, off); s2 += __shfl_xor(s2, off); }
    __shared__ float ps[8], ps2[8];
    if ((t & 63) == 0) { ps[t >> 6] = s; ps2[t >> 6] = s2; }
    __syncthreads();
    int hd = t >> 7;
    float S = ps[hd * 2] + ps[hd * 2 + 1], S2 = ps2[hd * 2] + ps2[hd * 2 + 1];
    float mu = S / 128.f, var = S2 / 128.f - mu * mu;
    float hn = (v - mu) * rsqrtf(var + 1e-5f) * w[t];
    float z = xi[(size_t)n * 1024 + 512 + t];
    out16[(size_t)n * 512 + t] = f2b((hn + skip[t] * xca[(size_t)n * 512 + t]) * siluf_(z));
}

// ---------------- sLSTM: causal conv (256 ch) + silu, bf16 in/out ------------
__global__ void conv_silu_s(const ushort_t* __restrict__ xln, const float* __restrict__ cw,
                            const float* __restrict__ cb, ushort_t* __restrict__ xc) {
    int idx = blockIdx.x * blockDim.x + threadIdx.x;
    if (idx >= NTOK * 256) return;
    int n = idx >> 8, c = idx & 255;
    int b = n / S_, s = n - b * S_;
    float y = cb[c];
    #pragma unroll
    for (int i = 0; i < 4; i++) {
        int sp = s - 3 + i;
        if (sp >= 0) y += bf2f(xln[(size_t)(b * S_ + sp) * 256 + c]) * cw[c * 4 + i];
    }
    xc[idx] = f2b(siluf_(y));
}

// ---------------- sLSTM: recurrence, weights in LDS --------------------------
// 512 thr: (g = tid>>7, o = (tid>>1)&63, kh = tid&1). Weight rows in LDS with
// 36-float stride => lane*36 ≡ lane*4 (mod 32 banks): canonical conflict-free
// b128 pattern. Compiler refused VGPR residency (R5: 56 VGPR w/ w[64]).
__global__ void __launch_bounds__(512)
slstm_rec(const float* __restrict__ Wx, const float* __restrict__ rw,
          const float* __restrict__ bias, float* __restrict__ ys) {
    __shared__ __align__(16) float wl[512 * 36];
    __shared__ __align__(16) float hs[64];
    __shared__ float raws[4][64];
    int b = blockIdx.x >> 2, h = blockIdx.x & 3;
    int tid = threadIdx.x;
    int g = tid >> 7, o = (tid >> 1) & 63, kh = tid & 1;
    const float* wp = rw + (size_t)(((g * 4 + h) * 64 + o)) * 64 + kh * 32;
    float* myrow = wl + tid * 36;
    #pragma unroll
    for (int i = 0; i < 8; i++) *(float4*)&myrow[i * 4] = *(const float4*)&wp[i * 4];
    float bi = bias[(g * 4 + h) * 64 + o];
    if (tid < 64) hs[tid] = 0.f;
    float c_ = 0.f, n_ = 0.f, m_ = 0.f;
    size_t wxbase = (size_t)(b * S_) * 1024 + g * 256 + h * 64 + o;
    float wx_cur = Wx[wxbase];
    __syncthreads();
    for (int s = 0; s < S_; s++) {
        float wx_next = (s + 1 < S_) ? Wx[wxbase + (size_t)(s + 1) * 1024] : 0.f;
        float a0 = 0.f, a1 = 0.f, a2 = 0.f, a3 = 0.f;
        #pragma unroll
        for (int d4 = 0; d4 < 8; d4++) {
            float4 wv = *(const float4*)&myrow[d4 * 4];
            float4 hv = *(const float4*)&hs[kh * 32 + d4 * 4];
            a0 += hv.x * wv.x;
            a1 += hv.y * wv.y;
            a2 += hv.z * wv.z;
            a3 += hv.w * wv.w;
        }
        float a = (a0 + a1) + (a2 + a3);
        a += __shfl_xor(a, 1);
        if (kh == 0) raws[g][o] = a + wx_cur + bi;
        __syncthreads();
        float ir = raws[0][o], fr = raws[1][o], zr = raws[2][o], orr = raws[3][o];
        float lfpm = m_ + logsigf_(fr);
        float mn = fmaxf(ir, lfpm);
        float ig = expf(ir - mn), fg = expf(lfpm - mn);
        c_ = fg * c_ + ig * tanhf(zr);
        n_ = fg * n_ + ig;
        m_ = mn;
        float hn = sigmoidf_(orr) * (c_ / n_);
        if (g == 0 && kh == 0) {
            hs[o] = hn;
            ys[(size_t)(b * S_ + s) * 256 + h * 64 + o] = hn;
        }
        __syncthreads();
        wx_cur = wx_next;
    }
}

// ---------------- sLSTM: per-head (64) groupnorm + residual add --------------
__global__ void __launch_bounds__(256)
mhln_s_resid(const float* __restrict__ ys, const float* __restrict__ w, float* __restrict__ h) {
    int n = blockIdx.x, t = threadIdx.x;
    float v = ys[(size_t)n * 256 + t];
    float s = v, s2 = v * v;
    #pragma unroll
    for (int off = 32; off; off >>= 1) { s += __shfl_xor(s, off); s2 += __shfl_xor(s2, off); }
    float mu = s / 64.f, var = s2 / 64.f - mu * mu;
    h[(size_t)n * 256 + t] += (v - mu) * rsqrtf(var + 1e-5f) * w[t];
}

// ---------------- FFN: gelu(gate)*up -> bf16 ---------------------------------
__global__ void ffn_act(const float* __restrict__ up, ushort_t* __restrict__ act) {
    int idx = blockIdx.x * blockDim.x + threadIdx.x;
    if (idx >= NTOK * 384) return;
    int n = idx / 384, j = idx - n * 384;
    float g = up[(size_t)n * 768 + j], u = up[(size_t)n * 768 + 384 + j];
    float t = tanhf(0.7978845608028654f * (g + 0.044715f * g * g * g));
    act[idx] = f2b(0.5f * g * (1.f + t) * u);
}

// ---------------- pooling + heads --------------------------------------------
__global__ void pool_k(const float* __restrict__ a, float* __restrict__ pooled) {
    int b = blockIdx.x, e = threadIdx.x;
    float s = 0.f;
    for (int t = 0; t < S_; t++) s += a[(size_t)(b * S_ + t) * 256 + e];
    pooled[b * 256 + e] = s / (float)S_;
}

__global__ void heads_k(const float* __restrict__ pooled,
                        const float* __restrict__ we, const float* __restrict__ be,
                        const float* __restrict__ ws, const float* __restrict__ bs,
                        float* __restrict__ out) {
    int i = blockIdx.x * blockDim.x + threadIdx.x;
    if (i < B_ * 7) {
        int b = i / 7, o = i - b * 7;
        float a = be[o];
        for (int e = 0; e < 256; e++) a += pooled[b * 256 + e] * we[e * 7 + o];
        out[b * 7 + o] = a;
    } else if (i < B_ * 7 + B_ * 3) {
        int j = i - B_ * 7;
        int b = j / 3, o = j - b * 3;
        float a = bs[o];
        for (int e = 0; e < 256; e++) a += pooled[b * 256 + e] * ws[e * 3 + o];
        out[B_ * 7 + b * 3 + o] = a;
    }
}

// =============================================================================
extern "C" void kernel_launch(void* const* d_in, const int* in_sizes, int n_in,
                              void* d_out, int out_size, void* d_ws, size_t ws_size,
                              hipStream_t stream) {
    (void)in_sizes; (void)n_in; (void)out_size; (void)ws_size;
    const float* x          = (const float*)d_in[0];
    const float* w_down     = (const float*)d_in[1];
    const float* b_down     = (const float*)d_in[2];
    const float* m_ln_w     = (const float*)d_in[3];
    const float* m_proj_up  = (const float*)d_in[4];
    const float* m_conv_w   = (const float*)d_in[5];
    const float* m_conv_b   = (const float*)d_in[6];
    const float* m_q_w      = (const float*)d_in[7];
    const float* m_k_w      = (const float*)d_in[8];
    const float* m_v_w      = (const float*)d_in[9];
    const float* m_ig_w     = (const float*)d_in[10];
    const float* m_ig_b     = (const float*)d_in[11];
    const float* m_fg_w     = (const float*)d_in[12];
    const float* m_fg_b     = (const float*)d_in[13];
    const float* m_skip     = (const float*)d_in[14];
    const float* m_outnorm  = (const float*)d_in[15];
    const float* m_proj_dn  = (const float*)d_in[16];
    const float* s_ln_w     = (const float*)d_in[17];
    const float* s_conv_w   = (const float*)d_in[18];
    const float* s_conv_b   = (const float*)d_in[19];
    const float* s_gate_w   = (const float*)d_in[20];
    const float* s_rec_w    = (const float*)d_in[21];
    const float* s_bias     = (const float*)d_in[22];
    const float* s_gn_w     = (const float*)d_in[23];
    const float* s_ln2_w    = (const float*)d_in[24];
    const float* s_ffn_up   = (const float*)d_in[25];
    const float* s_ffn_dn   = (const float*)d_in[26];
    const float* post_ln_w  = (const float*)d_in[27];
    const float* w_emo      = (const float*)d_in[28];
    const float* b_emo      = (const float*)d_in[29];
    const float* w_sen      = (const float*)d_in[30];
    const float* b_sen      = (const float*)d_in[31];

    float* W    = (float*)d_ws;
    float* h    = W;
    float* lnb  = h    + (size_t)NTOK * 256;
    float* big0 = lnb  + (size_t)NTOK * 256;
    float* xca  = big0 + (size_t)NTOK * 1024;
    float* qb   = xca  + (size_t)NTOK * 512;
    float* kb   = qb   + (size_t)NTOK * 512;
    float* vb   = kb   + (size_t)NTOK * 512;
    float* hatt = vb   + (size_t)NTOK * 512;
    float* igo  = hatt + (size_t)NTOK * 512;
    float* fgo  = igo  + (size_t)NTOK * 4;
    float* lfcb = fgo  + (size_t)NTOK * 4;
    float* Mxb  = lfcb + (size_t)256 * (S_ + 1);
    float* pooled = Mxb + (size_t)256 * S_;
    // bf16 overlays
    ushort_t* lnb16 = (ushort_t*)lnb;                  // NTOK*256
    ushort_t* qb16  = (ushort_t*)qb;                   // NTOK*512 (first half of qb slot)
    ushort_t* kb16  = (ushort_t*)kb;
    ushort_t* vb16  = (ushort_t*)vb;
    ushort_t* hat16 = qb16 + (size_t)NTOK * 512;       // upper half of qb slot
    ushort_t* xc16  = (ushort_t*)(vb16 + (size_t)NTOK * 512);  // upper half of vb slot (sLSTM)
    ushort_t* wpk   = (ushort_t*)(pooled + 64 * 256);
    ushort_t* wp_pu = wpk;                             // 5*256*1024
    ushort_t* wp_pd = wp_pu + 5 * 262144;              // 5*512*256
    ushort_t* wp_fu = wp_pd + 5 * 131072;              // 2*256*768
    ushort_t* wp_fd = wp_fu + 2 * 196608;              // 2*384*256

    cvt_bf<<<(5 * 262144 / 4 + 255) / 256, 256, 0, stream>>>(m_proj_up, wp_pu, 5 * 262144 / 4);
    cvt_bf<<<(5 * 131072 / 4 + 255) / 256, 256, 0, stream>>>(m_proj_dn, wp_pd, 5 * 131072 / 4);
    cvt_bf<<<(2 * 196608 / 4 + 255) / 256, 256, 0, stream>>>(s_ffn_up, wp_fu, 2 * 196608 / 4);
    cvt_bf<<<(2 * 98304 / 4 + 255) / 256, 256, 0, stream>>>(s_ffn_dn, wp_fd, 2 * 98304 / 4);

    gemm_mfma<<<dim3(256 / 64, NTOK / 64), 256, 0, stream>>>(x, w_down, b_down, h, NTOK, 1024, 256, 0);

    int mi = 0, si = 0;
    for (int blk = 0; blk < 7; blk++) {
        if (blk == 1 || blk == 4) {
            layernorm256<<<NTOK, 256, 0, stream>>>(h, s_ln_w + si * 256, lnb16);
            conv_silu_s<<<(NTOK * 256 + 255) / 256, 256, 0, stream>>>(lnb16, s_conv_w + si * 1024, s_conv_b + si * 256, xc16);
            slstm_wx_mfma<<<dim3(NTOK / 64, 16), 256, 0, stream>>>(xc16, lnb16, s_gate_w + (size_t)si * 65536, big0);
            slstm_rec<<<256, 512, 0, stream>>>(big0, s_rec_w + (size_t)si * 65536, s_bias + si * 1024, hatt);
            mhln_s_resid<<<NTOK, 256, 0, stream>>>(hatt, s_gn_w + si * 256, h);
            layernorm256<<<NTOK, 256, 0, stream>>>(h, s_ln2_w + si * 256, lnb16);
            gemm_bf<<<dim3(768 / 128, NTOK / 64), 256, 0, stream>>>(lnb16, wp_fu + (size_t)si * 196608, nullptr, big0, NTOK, 256, 768, 0);
            ffn_act<<<(NTOK * 384 + 255) / 256, 256, 0, stream>>>(big0, hat16);
            gemm_bf<<<dim3(256 / 128, NTOK / 64), 256, 0, stream>>>(hat16, wp_fd + (size_t)si * 98304, nullptr, h, NTOK, 384, 256, 1);
            si++;
        } else {
            layernorm256<<<NTOK, 256, 0, stream>>>(h, m_ln_w + mi * 256, lnb16);
            gemm_bf<<<dim3(1024 / 128, NTOK / 64), 256, 0, stream>>>(lnb16, wp_pu + (size_t)mi * 262144, nullptr, big0, NTOK, 256, 1024, 0);
            fused_qkv<<<(NTOK * 128 + 255) / 256, 256, 0, stream>>>(big0, m_conv_w + mi * 2048, m_conv_b + mi * 512,
                                                                    m_q_w + mi * 2048, m_k_w + mi * 2048, m_v_w + mi * 2048,
                                                                    xca, qb16, kb16, vb16);
            gates2<<<NTOK / 4, 256, 0, stream>>>(qb16, kb16, vb16, m_ig_w + mi * 6144, m_ig_b + mi * 4,
                                                 m_fg_w + mi * 6144, m_fg_b + mi * 4, igo, fgo);
            mlstm_cumsum<<<64, 256, 0, stream>>>(fgo, igo, lfcb, Mxb);
            mlstm_attn_mfma<<<256, 256, 0, stream>>>(qb16, kb16, vb16, igo, lfcb, Mxb, hatt);
            mhln_hstate<<<NTOK, 512, 0, stream>>>(hatt, m_outnorm + mi * 512, xca, big0, m_skip + mi * 512, hat16);
            gemm_bf<<<dim3(256 / 128, NTOK / 64), 256, 0, stream>>>(hat16, wp_pd + (size_t)mi * 131072, nullptr, h, NTOK, 512, 256, 1);
            mi++;
        }
    }

    postln_selu<<<NTOK, 256, 0, stream>>>(h, post_ln_w, xca);
    pool_k<<<B_, 256, 0, stream>>>(xca, pooled);
    heads_k<<<3, 256, 0, stream>>>(pooled, w_emo, b_emo, w_sen, b_sen, (float*)d_out);
}

// Round 8
// 1919.030 us; speedup vs baseline: 3.2806x; 1.0364x over previous
//
#include <hip/hip_runtime.h>
#include <hip/hip_bf16.h>
#include <math.h>

// AudioModelV3: 7-block xLSTM (blocks 1,4 = sLSTM+FFN; others mLSTM).
// R8: slstm_rec weights pinned into VGPRs via empty asm (compiler refused
// residency 3x and re-streamed every step: 64KB/step from LDS/L2 = the wall).
// sLSTM epilogue fused (gn+resid+LN2 in one pass). cvt_bf x4 -> cvt_all.

#define B_    64
#define S_    199
#define E_    256
#define NTOK  (B_*S_)          // 12736
#define NQT   13               // ceil(199/16)

typedef __attribute__((ext_vector_type(8))) short short8;
typedef __attribute__((ext_vector_type(4))) float floatx4;
typedef unsigned short ushort_t;

__device__ __forceinline__ float sigmoidf_(float x) { return 1.f / (1.f + expf(-x)); }
__device__ __forceinline__ float siluf_(float x) { return x / (1.f + expf(-x)); }
__device__ __forceinline__ float logsigf_(float x) { return fminf(x, 0.f) - log1pf(expf(-fabsf(x))); }

__device__ __forceinline__ ushort_t f2b(float f) {   // fp32 -> bf16 (RNE)
    union { float f; unsigned u; } v; v.f = f;
    unsigned r = (v.u + 0x7fffu + ((v.u >> 16) & 1u)) >> 16;
    return (ushort_t)r;
}
__device__ __forceinline__ float bf2f(ushort_t u) {
    union { unsigned u; float f; } v; v.u = ((unsigned)u) << 16;
    return v.f;
}
__device__ __forceinline__ void unp2(unsigned d, float& lo, float& hi) {
    union { unsigned u; float f; } a, b;
    a.u = d << 16; b.u = d & 0xffff0000u;
    lo = a.f; hi = b.f;
}

// ---------------- fp32 -> bf16 pack of all GEMM weights (one launch) ---------
// Segments (in f32 elems): pu 5*262144 | pd 5*131072 | fu 2*196608 | fd 2*98304
__global__ void cvt_all(const float* __restrict__ pu, const float* __restrict__ pd,
                        const float* __restrict__ fu, const float* __restrict__ fd,
                        ushort_t* __restrict__ out, int n4) {
    int i = blockIdx.x * 256 + threadIdx.x;
    if (i >= n4) return;
    int e = i * 4;
    const float* src;
    if (e < 1310720)      src = pu + e;
    else if (e < 1966080) src = pd + (e - 1310720);
    else if (e < 2359296) src = fu + (e - 1966080);
    else                  src = fd + (e - 2359296);
    float4 v = *(const float4*)src;
    union { ushort_t us[4]; uint2 u; } t;
    t.us[0] = f2b(v.x); t.us[1] = f2b(v.y); t.us[2] = f2b(v.z); t.us[3] = f2b(v.w);
    *(uint2*)&out[e] = t.u;
}

// ---------------- bf16 MFMA GEMM: C[M,N] = A[M,K] @ B[K,N] (+bias)(+=C) ------
__global__ void __launch_bounds__(256)
gemm_bf(const ushort_t* __restrict__ A, const ushort_t* __restrict__ Bw,
        const float* __restrict__ bias, float* __restrict__ C,
        int M, int K, int N, int accum) {
    __shared__ __align__(16) ushort_t As[64][40];
    __shared__ __align__(16) ushort_t Bs[128][40];
    int tid = threadIdx.x;
    int wave = tid >> 6, lane = tid & 63;
    int wm = wave >> 1, wn = wave & 1;
    int quad = lane >> 4, l16 = lane & 15;
    int m0 = blockIdx.y * 64, n0 = blockIdx.x * 128;
    floatx4 zero = {0.f, 0.f, 0.f, 0.f};
    floatx4 acc[2][4];
    #pragma unroll
    for (int i = 0; i < 2; i++)
        #pragma unroll
        for (int j = 0; j < 4; j++) acc[i][j] = zero;
    int ar = tid >> 2, ac = (tid & 3) * 8;
    int bn = tid & 127, bkg = (tid >> 7) * 16;
    for (int k0 = 0; k0 < K; k0 += 32) {
        *(uint4*)&As[ar][ac] = *(const uint4*)(A + (size_t)(m0 + ar) * K + k0 + ac);
        {
            const ushort_t* bp = Bw + (size_t)(k0 + bkg) * N + n0 + bn;
            union { ushort_t us[16]; uint4 v[2]; } t;
            #pragma unroll
            for (int i = 0; i < 16; i++) t.us[i] = bp[(size_t)i * N];
            *(uint4*)&Bs[bn][bkg] = t.v[0];
            *(uint4*)&Bs[bn][bkg + 8] = t.v[1];
        }
        __syncthreads();
        short8 af[2], bf[4];
        #pragma unroll
        for (int i = 0; i < 2; i++) af[i] = *(const short8*)&As[wm * 32 + i * 16 + l16][quad * 8];
        #pragma unroll
        for (int j = 0; j < 4; j++) bf[j] = *(const short8*)&Bs[wn * 64 + j * 16 + l16][quad * 8];
        #pragma unroll
        for (int i = 0; i < 2; i++)
            #pragma unroll
            for (int j = 0; j < 4; j++)
                acc[i][j] = __builtin_amdgcn_mfma_f32_16x16x32_bf16(af[i], bf[j], acc[i][j], 0, 0, 0);
        __syncthreads();
    }
    #pragma unroll
    for (int i = 0; i < 2; i++)
        #pragma unroll
        for (int j = 0; j < 4; j++)
            #pragma unroll
            for (int r = 0; r < 4; r++) {
                int row = m0 + wm * 32 + i * 16 + quad * 4 + r;
                int col = n0 + wn * 64 + j * 16 + l16;
                float o = acc[i][j][r];
                if (bias) o += bias[col];
                float* cp = &C[(size_t)row * N + col];
                if (accum) o += *cp;
                *cp = o;
            }
}

// ---------------- fp32-A MFMA GEMM (embed only) ------------------------------
__global__ void __launch_bounds__(256)
gemm_mfma(const float* __restrict__ A, const float* __restrict__ Bw,
          const float* __restrict__ bias, float* __restrict__ C,
          int M, int K, int N, int accum) {
    __shared__ __align__(16) ushort_t As[64][40];
    __shared__ __align__(16) ushort_t Bs[64][40];
    int tid = threadIdx.x;
    int wave = tid >> 6, lane = tid & 63;
    int wm = wave >> 1, wn = wave & 1;
    int quad = lane >> 4, l16 = lane & 15;
    int m0 = blockIdx.y * 64, n0 = blockIdx.x * 64;
    floatx4 zero = {0.f, 0.f, 0.f, 0.f};
    floatx4 acc[2][2];
    acc[0][0] = zero; acc[0][1] = zero; acc[1][0] = zero; acc[1][1] = zero;
    int ar = tid >> 2, ac = (tid & 3) * 8;
    int bn = tid & 63, bk = (tid >> 6) * 8;
    for (int k0 = 0; k0 < K; k0 += 32) {
        {
            const float* ap = A + (size_t)(m0 + ar) * K + k0 + ac;
            union { ushort_t us[8]; uint4 v; } t;
            #pragma unroll
            for (int i = 0; i < 8; i++) t.us[i] = f2b(ap[i]);
            *(uint4*)&As[ar][ac] = t.v;
        }
        {
            const float* bp = Bw + (size_t)(k0 + bk) * N + n0 + bn;
            union { ushort_t us[8]; uint4 v; } t;
            #pragma unroll
            for (int i = 0; i < 8; i++) t.us[i] = f2b(bp[(size_t)i * N]);
            *(uint4*)&Bs[bn][bk] = t.v;
        }
        __syncthreads();
        short8 af[2], bf[2];
        #pragma unroll
        for (int i = 0; i < 2; i++) af[i] = *(const short8*)&As[wm * 32 + i * 16 + l16][quad * 8];
        #pragma unroll
        for (int j = 0; j < 2; j++) bf[j] = *(const short8*)&Bs[wn * 32 + j * 16 + l16][quad * 8];
        #pragma unroll
        for (int i = 0; i < 2; i++)
            #pragma unroll
            for (int j = 0; j < 2; j++)
                acc[i][j] = __builtin_amdgcn_mfma_f32_16x16x32_bf16(af[i], bf[j], acc[i][j], 0, 0, 0);
        __syncthreads();
    }
    #pragma unroll
    for (int i = 0; i < 2; i++)
        #pragma unroll
        for (int j = 0; j < 2; j++)
            #pragma unroll
            for (int r = 0; r < 4; r++) {
                int row = m0 + wm * 32 + i * 16 + quad * 4 + r;
                int col = n0 + wn * 32 + j * 16 + l16;
                float o = acc[i][j][r];
                if (bias) o += bias[col];
                float* cp = &C[(size_t)row * N + col];
                if (accum) o += *cp;
                *cp = o;
            }
}

// ---------------- sLSTM Wx as block-diagonal MFMA GEMM (bf16 A) --------------
__global__ void __launch_bounds__(256)
slstm_wx_mfma(const ushort_t* __restrict__ xc, const ushort_t* __restrict__ xln,
              const float* __restrict__ gw, float* __restrict__ Wx) {
    __shared__ __align__(16) ushort_t As[64][40];
    __shared__ __align__(16) ushort_t Bs[64][40];
    int gh = blockIdx.y; int g = gh >> 2, hh = gh & 3;
    const ushort_t* src = (g < 2) ? xc : xln;
    const float* w = gw + (size_t)gh * 4096;
    int tid = threadIdx.x;
    int wave = tid >> 6, lane = tid & 63;
    int wm = wave >> 1, wn = wave & 1;
    int quad = lane >> 4, l16 = lane & 15;
    int m0 = blockIdx.x * 64;
    floatx4 zero = {0.f, 0.f, 0.f, 0.f};
    floatx4 acc[2][2];
    acc[0][0] = zero; acc[0][1] = zero; acc[1][0] = zero; acc[1][1] = zero;
    int ar = tid >> 2, ac = (tid & 3) * 8;
    int bn = tid & 63, bk = (tid >> 6) * 8;
    #pragma unroll
    for (int kt = 0; kt < 2; kt++) {
        int k0 = kt * 32;
        *(uint4*)&As[ar][ac] = *(const uint4*)(src + (size_t)(m0 + ar) * 256 + hh * 64 + k0 + ac);
        {
            const float* bp = w + (size_t)bn * 64 + k0 + bk;
            union { ushort_t us[8]; uint4 v; } t;
            #pragma unroll
            for (int i = 0; i < 8; i++) t.us[i] = f2b(bp[i]);
            *(uint4*)&Bs[bn][bk] = t.v;
        }
        __syncthreads();
        short8 af[2], bf[2];
        #pragma unroll
        for (int i = 0; i < 2; i++) af[i] = *(const short8*)&As[wm * 32 + i * 16 + l16][quad * 8];
        #pragma unroll
        for (int j = 0; j < 2; j++) bf[j] = *(const short8*)&Bs[wn * 32 + j * 16 + l16][quad * 8];
        #pragma unroll
        for (int i = 0; i < 2; i++)
            #pragma unroll
            for (int j = 0; j < 2; j++)
                acc[i][j] = __builtin_amdgcn_mfma_f32_16x16x32_bf16(af[i], bf[j], acc[i][j], 0, 0, 0);
        __syncthreads();
    }
    #pragma unroll
    for (int i = 0; i < 2; i++)
        #pragma unroll
        for (int j = 0; j < 2; j++)
            #pragma unroll
            for (int r = 0; r < 4; r++) {
                int row = m0 + wm * 32 + i * 16 + quad * 4 + r;
                int col = wn * 32 + j * 16 + l16;
                Wx[(size_t)row * 1024 + g * 256 + hh * 64 + col] = acc[i][j][r];
            }
}

// ---------------- layernorm over 256, bf16 output ----------------------------
__global__ void __launch_bounds__(256)
layernorm256(const float* __restrict__ x, const float* __restrict__ w, ushort_t* __restrict__ y) {
    int n = blockIdx.x, t = threadIdx.x;
    float v = x[(size_t)n * 256 + t];
    float s = v, s2 = v * v;
    #pragma unroll
    for (int off = 32; off; off >>= 1) { s += __shfl_xor(s, off); s2 += __shfl_xor(s2, off); }
    __shared__ float ps[4], ps2[4];
    if ((t & 63) == 0) { ps[t >> 6] = s; ps2[t >> 6] = s2; }
    __syncthreads();
    float S = ps[0] + ps[1] + ps[2] + ps[3];
    float S2 = ps2[0] + ps2[1] + ps2[2] + ps2[3];
    float mu = S / 256.f, var = S2 / 256.f - mu * mu;
    y[(size_t)n * 256 + t] = f2b((v - mu) * rsqrtf(var + 1e-5f) * w[t]);
}

// ---------------- post-LN + selu (fp32 out) ---------------------------------
__global__ void __launch_bounds__(256)
postln_selu(const float* __restrict__ x, const float* __restrict__ w, float* __restrict__ y) {
    int n = blockIdx.x, t = threadIdx.x;
    float v = x[(size_t)n * 256 + t];
    float s = v, s2 = v * v;
    #pragma unroll
    for (int off = 32; off; off >>= 1) { s += __shfl_xor(s, off); s2 += __shfl_xor(s2, off); }
    __shared__ float ps[4], ps2[4];
    if ((t & 63) == 0) { ps[t >> 6] = s; ps2[t >> 6] = s2; }
    __syncthreads();
    float S = ps[0] + ps[1] + ps[2] + ps[3];
    float S2 = ps2[0] + ps2[1] + ps2[2] + ps2[3];
    float mu = S / 256.f, var = S2 / 256.f - mu * mu;
    float yn = (v - mu) * rsqrtf(var + 1e-5f) * w[t];
    y[(size_t)n * 256 + t] = 1.0507009873554805f * (yn > 0.f ? yn : 1.6732632423543772f * (expf(yn) - 1.f));
}

// ---------------- mLSTM: fused conv+silu+headwise qkv (bf16 out) -------------
__global__ void __launch_bounds__(256)
fused_qkv(const float* __restrict__ xi, const float* __restrict__ cw,
          const float* __restrict__ cb,
          const float* __restrict__ qw, const float* __restrict__ kw,
          const float* __restrict__ vw,
          float* __restrict__ xca,
          ushort_t* __restrict__ q16, ushort_t* __restrict__ k16, ushort_t* __restrict__ v16) {
    int idx = blockIdx.x * 256 + threadIdx.x;
    if (idx >= NTOK * 128) return;
    int n = idx >> 7, hh = idx & 127;
    int b = n / S_, s = n - b * S_;
    int c0 = hh * 4;
    float4 hist[4];
    #pragma unroll
    for (int i = 0; i < 4; i++) {
        int sp = s - 3 + i;
        if (sp >= 0) hist[i] = *(const float4*)(xi + (size_t)(b * S_ + sp) * 1024 + c0);
        else hist[i] = (float4){0.f, 0.f, 0.f, 0.f};
    }
    float xm[4] = {hist[3].x, hist[3].y, hist[3].z, hist[3].w};
    float xc4[4];
    #pragma unroll
    for (int d = 0; d < 4; d++) {
        float y = cb[c0 + d];
        const float* cwp = cw + (c0 + d) * 4;
        float hv[4] = { d==0?hist[0].x:(d==1?hist[0].y:(d==2?hist[0].z:hist[0].w)),
                        d==0?hist[1].x:(d==1?hist[1].y:(d==2?hist[1].z:hist[1].w)),
                        d==0?hist[2].x:(d==1?hist[2].y:(d==2?hist[2].z:hist[2].w)),
                        xm[d] };
        #pragma unroll
        for (int i = 0; i < 4; i++) y += hv[i] * cwp[i];
        xc4[d] = siluf_(y);
    }
    *(float4*)(xca + (size_t)n * 512 + c0) = (float4){xc4[0], xc4[1], xc4[2], xc4[3]};
    union { ushort_t us[4]; uint2 u; } qo, ko, vo;
    #pragma unroll
    for (int o = 0; o < 4; o++) {
        const float* qp = qw + (c0 + o) * 4;
        const float* kp = kw + (c0 + o) * 4;
        const float* vp = vw + (c0 + o) * 4;
        float aq = 0.f, ak = 0.f, av = 0.f;
        #pragma unroll
        for (int d = 0; d < 4; d++) {
            aq += xc4[d] * qp[d];
            ak += xc4[d] * kp[d];
            av += xm[d] * vp[d];
        }
        qo.us[o] = f2b(aq); ko.us[o] = f2b(ak); vo.us[o] = f2b(av);
    }
    *(uint2*)(q16 + (size_t)n * 512 + c0) = qo.u;
    *(uint2*)(k16 + (size_t)n * 512 + c0) = ko.u;
    *(uint2*)(v16 + (size_t)n * 512 + c0) = vo.u;
}

// ---------------- mLSTM: ig/fg gates, one wave per token ---------------------
__global__ void __launch_bounds__(256)
gates2(const ushort_t* __restrict__ qb, const ushort_t* __restrict__ kb, const ushort_t* __restrict__ vb,
       const float* __restrict__ igw, const float* __restrict__ igbias,
       const float* __restrict__ fgw, const float* __restrict__ fgbias,
       float* __restrict__ igo, float* __restrict__ fgo) {
    int n = blockIdx.x * 4 + (threadIdx.x >> 6);
    int lane = threadIdx.x & 63;
    uint4 q4 = *(const uint4*)(qb + (size_t)n * 512 + lane * 8);
    uint4 k4 = *(const uint4*)(kb + (size_t)n * 512 + lane * 8);
    uint4 v4 = *(const uint4*)(vb + (size_t)n * 512 + lane * 8);
    float q[8], k[8], v[8];
    unp2(q4.x, q[0], q[1]); unp2(q4.y, q[2], q[3]); unp2(q4.z, q[4], q[5]); unp2(q4.w, q[6], q[7]);
    unp2(k4.x, k[0], k[1]); unp2(k4.y, k[2], k[3]); unp2(k4.z, k[4], k[5]); unp2(k4.w, k[6], k[7]);
    unp2(v4.x, v[0], v[1]); unp2(v4.y, v[2], v[3]); unp2(v4.z, v[4], v[5]); unp2(v4.w, v[6], v[7]);
    float acc[8];
    #pragma unroll
    for (int hd = 0; hd < 4; hd++)
        #pragma unroll
        for (int wh = 0; wh < 2; wh++) {
            const float* w = (wh ? fgw : igw) + hd * 1536 + lane * 8;
            float a = 0.f;
            #pragma unroll
            for (int i = 0; i < 8; i++) a += q[i] * w[i];
            #pragma unroll
            for (int i = 0; i < 8; i++) a += k[i] * w[512 + i];
            #pragma unroll
            for (int i = 0; i < 8; i++) a += v[i] * w[1024 + i];
            acc[hd * 2 + wh] = a;
        }
    #pragma unroll
    for (int t = 0; t < 8; t++) {
        float a = acc[t];
        #pragma unroll
        for (int off = 32; off; off >>= 1) a += __shfl_xor(a, off);
        if (lane == 0) {
            int hd = t >> 1, wh = t & 1;
            a += (wh ? fgbias : igbias)[hd];
            (wh ? fgo : igo)[(size_t)n * 4 + hd] = a;
        }
    }
}

// ---------------- mLSTM: cumsum + prefix-max, wave-parallel shfl scan --------
__global__ void __launch_bounds__(256)
mlstm_cumsum(const float* __restrict__ fgo, const float* __restrict__ igo,
             float* __restrict__ lfc, float* __restrict__ Mx) {
    int bh = blockIdx.x * 4 + (threadIdx.x >> 6);
    int lane = threadIdx.x & 63;
    int b = bh >> 2, h = bh & 3;
    float v[4]; float lsum = 0.f;
    #pragma unroll
    for (int i = 0; i < 4; i++) {
        int s = lane * 4 + i;
        float f = (s < S_) ? fgo[(size_t)(b * S_ + s) * 4 + h] : 0.f;
        lsum += logsigf_(f);
        v[i] = lsum;
    }
    float x = lsum;
    #pragma unroll
    for (int off = 1; off < 64; off <<= 1) {
        float y = __shfl_up(x, off);
        if (lane >= off) x += y;
    }
    float excl = x - lsum;
    float lf1[4];
    #pragma unroll
    for (int i = 0; i < 4; i++) lf1[i] = excl + v[i];
    if (lane == 0) lfc[bh * (S_ + 1)] = 0.f;
    #pragma unroll
    for (int i = 0; i < 4; i++) {
        int s = lane * 4 + i;
        if (s < S_) lfc[bh * (S_ + 1) + s + 1] = lf1[i];
    }
    float gm[4]; float lmax = -1e30f;
    #pragma unroll
    for (int i = 0; i < 4; i++) {
        int s = lane * 4 + i;
        float ig_ = (s < S_) ? igo[(size_t)(b * S_ + s) * 4 + h] : -1e30f;
        float gg = ig_ - lf1[i];
        lmax = fmaxf(lmax, gg);
        gm[i] = lmax;
    }
    float xm = lmax;
    #pragma unroll
    for (int off = 1; off < 64; off <<= 1) {
        float y = __shfl_up(xm, off);
        if (lane >= off) xm = fmaxf(xm, y);
    }
    float exclm = __shfl_up(xm, 1);
    if (lane == 0) exclm = -1e30f;
    #pragma unroll
    for (int i = 0; i < 4; i++) {
        int s = lane * 4 + i;
        if (s < S_) Mx[bh * S_ + s] = fmaxf(exclm, gm[i]);
    }
}

// ---------------- mLSTM attention: MFMA flash-style, bf16 inputs -------------
__global__ void __launch_bounds__(256, 1)
mlstm_attn_mfma(const ushort_t* __restrict__ qb, const ushort_t* __restrict__ kb, const ushort_t* __restrict__ vb,
                const float* __restrict__ igb, const float* __restrict__ lfc, const float* __restrict__ Mx,
                float* __restrict__ outb) {
    __shared__ __align__(16) ushort_t Kb[64 * 136];
    __shared__ __align__(16) ushort_t Vt[128 * 72];
    __shared__ __align__(16) ushort_t Pw[4][16 * 72];
    __shared__ float gv[208], lfv[208], mxv[208];
    int bh = blockIdx.x; int b = bh >> 2, h = bh & 3;
    int tid = threadIdx.x, wave = tid >> 6, lane = tid & 63;
    int quad = lane >> 4, l16 = lane & 15;
    if (tid < 208) {
        if (tid < S_) {
            float lf1 = lfc[bh * (S_ + 1) + tid + 1];
            gv[tid] = igb[(size_t)(b * S_ + tid) * 4 + h] - lf1;
            lfv[tid] = lf1;
            mxv[tid] = Mx[bh * S_ + tid];
        } else { gv[tid] = 0.f; lfv[tid] = 0.f; mxv[tid] = 0.f; }
    }
    floatx4 zero = {0.f, 0.f, 0.f, 0.f};
    float rs[4][4];
    floatx4 accv[4][8];
    #pragma unroll
    for (int qi = 0; qi < 4; qi++) {
        #pragma unroll
        for (int r = 0; r < 4; r++) rs[qi][r] = 0.f;
        #pragma unroll
        for (int dt = 0; dt < 8; dt++) accv[qi][dt] = zero;
    }
    const float scale = 0.08838834764831845f;
    int trow = tid >> 4, d0 = (tid & 15) * 8;
    for (int c = 0; c < 4; c++) {
        __syncthreads();
        #pragma unroll
        for (int i = 0; i < 4; i++) {
            int tl = trow + 16 * i;
            int t = c * 64 + tl;
            union { ushort_t us[8]; uint4 v; } kk, vv;
            if (t < S_) {
                kk.v = *(const uint4*)(kb + (size_t)(b * S_ + t) * 512 + h * 128 + d0);
                vv.v = *(const uint4*)(vb + (size_t)(b * S_ + t) * 512 + h * 128 + d0);
            } else {
                kk.v = (uint4){0, 0, 0, 0};
                vv.v = (uint4){0, 0, 0, 0};
            }
            *(uint4*)&Kb[tl * 136 + d0] = kk.v;
            #pragma unroll
            for (int ii = 0; ii < 8; ii++) Vt[(d0 + ii) * 72 + tl] = vv.us[ii];
        }
        __syncthreads();
        for (int qi = 0; qi < 4; qi++) {
            int qt = wave + 4 * qi;
            if (qt >= NQT || qt < 4 * c) continue;
            uint4 z4 = {0, 0, 0, 0};
            for (int z = lane; z < 144; z += 64) ((uint4*)Pw[wave])[z] = z4;
            int srow = qt * 16 + l16;
            const ushort_t* qp = qb + (size_t)(b * S_ + min(srow, S_ - 1)) * 512 + h * 128 + quad * 8;
            short8 af[4];
            #pragma unroll
            for (int ks = 0; ks < 4; ks++) af[ks] = *(const short8*)(qp + 32 * ks);
            int ktmax_l = min(qt, 4 * c + 3) - 4 * c;
            for (int ktl = 0; ktl <= ktmax_l; ktl++) {
                floatx4 acc = zero;
                #pragma unroll
                for (int ks = 0; ks < 4; ks++) {
                    short8 bf = *(const short8*)&Kb[(ktl * 16 + l16) * 136 + quad * 8 + 32 * ks];
                    acc = __builtin_amdgcn_mfma_f32_16x16x32_bf16(af[ks], bf, acc, 0, 0, 0);
                }
                int tcol = c * 64 + ktl * 16 + l16;
                float gt = gv[tcol];
                #pragma unroll
                for (int r = 0; r < 4; r++) {
                    int s = qt * 16 + quad * 4 + r;
                    bool valid = (tcol <= s) && (tcol < S_);
                    float w = valid ? expf(gt - mxv[s]) : 0.f;
                    float p = acc[r] * scale * w;
                    rs[qi][r] += p;
                    Pw[wave][(quad * 4 + r) * 72 + ktl * 16 + l16] = f2b(p);
                }
            }
            #pragma unroll
            for (int dt = 0; dt < 8; dt++) {
                floatx4 a = accv[qi][dt];
                #pragma unroll
                for (int ks = 0; ks < 2; ks++) {
                    short8 ap = *(const short8*)&Pw[wave][l16 * 72 + quad * 8 + 32 * ks];
                    short8 bp = *(const short8*)&Vt[(dt * 16 + l16) * 72 + quad * 8 + 32 * ks];
                    a = __builtin_amdgcn_mfma_f32_16x16x32_bf16(ap, bp, a, 0, 0, 0);
                }
                accv[qi][dt] = a;
            }
        }
    }
    for (int qi = 0; qi < 4; qi++) {
        int qt = wave + 4 * qi;
        if (qt >= NQT) continue;
        float nrm[4];
        #pragma unroll
        for (int r = 0; r < 4; r++) {
            float v = rs[qi][r];
            v += __shfl_xor(v, 1); v += __shfl_xor(v, 2);
            v += __shfl_xor(v, 4); v += __shfl_xor(v, 8);
            int s = qt * 16 + quad * 4 + r;
            nrm[r] = fmaxf(fabsf(v), expf(-(lfv[s] + mxv[s]))) + 1e-6f;
        }
        #pragma unroll
        for (int dt = 0; dt < 8; dt++)
            #pragma unroll
            for (int r = 0; r < 4; r++) {
                int s = qt * 16 + quad * 4 + r;
                if (s < S_)
                    outb[(size_t)(b * S_ + s) * 512 + h * 128 + dt * 16 + l16] = accv[qi][dt][r] / nrm[r];
            }
    }
}

// ---------------- mLSTM: fused per-head LN + h_state -> bf16 -----------------
__global__ void __launch_bounds__(512)
mhln_hstate(const float* __restrict__ hatt, const float* __restrict__ w,
            const float* __restrict__ xca, const float* __restrict__ xi,
            const float* __restrict__ skip, ushort_t* __restrict__ out16) {
    int n = blockIdx.x, t = threadIdx.x;
    float v = hatt[(size_t)n * 512 + t];
    float s = v, s2 = v * v;
    #pragma unroll
    for (int off = 32; off; off >>= 1) { s += __shfl_xor(s, off); s2 += __shfl_xor(s2, off); }
    __shared__ float ps[8], ps2[8];
    if ((t & 63) == 0) { ps[t >> 6] = s; ps2[t >> 6] = s2; }
    __syncthreads();
    int hd = t >> 7;
    float S = ps[hd * 2] + ps[hd * 2 + 1], S2 = ps2[hd * 2] + ps2[hd * 2 + 1];
    float mu = S / 128.f, var = S2 / 128.f - mu * mu;
    float hn = (v - mu) * rsqrtf(var + 1e-5f) * w[t];
    float z = xi[(size_t)n * 1024 + 512 + t];
    out16[(size_t)n * 512 + t] = f2b((hn + skip[t] * xca[(size_t)n * 512 + t]) * siluf_(z));
}

// ---------------- sLSTM: causal conv (256 ch) + silu, bf16 in/out ------------
__global__ void conv_silu_s(const ushort_t* __restrict__ xln, const float* __restrict__ cw,
                            const float* __restrict__ cb, ushort_t* __restrict__ xc) {
    int idx = blockIdx.x * blockDim.x + threadIdx.x;
    if (idx >= NTOK * 256) return;
    int n = idx >> 8, c = idx & 255;
    int b = n / S_, s = n - b * S_;
    float y = cb[c];
    #pragma unroll
    for (int i = 0; i < 4; i++) {
        int sp = s - 3 + i;
        if (sp >= 0) y += bf2f(xln[(size_t)(b * S_ + sp) * 256 + c]) * cw[c * 4 + i];
    }
    xc[idx] = f2b(siluf_(y));
}

// ---------------- sLSTM: recurrence, weights PINNED in VGPRs -----------------
// 512 thr split-K: g=tid>>7, o=(tid>>1)&63, kh=tid&1, w[32]/thread. The empty
// asm makes the loaded weights opaque: compiler cannot rematerialize the
// global loads inside the loop (it did so at VGPR_Count 56/36/52 in R5-R7,
// streaming 64KB/step). Budget: 512thr -> 2 waves/SIMD -> 256 VGPR. 
__global__ void __launch_bounds__(512)
slstm_rec(const float* __restrict__ Wx, const float* __restrict__ rw,
          const float* __restrict__ bias, float* __restrict__ ys) {
    __shared__ __align__(16) float hs[64];
    __shared__ float raws[4][64];
    int b = blockIdx.x >> 2, h = blockIdx.x & 3;
    int tid = threadIdx.x;
    int g = tid >> 7, o = (tid >> 1) & 63, kh = tid & 1;
    float w[32];
    const float* wp = rw + (size_t)(((g * 4 + h) * 64 + o)) * 64 + kh * 32;
    #pragma unroll
    for (int d = 0; d < 32; d++) w[d] = wp[d];
    #pragma unroll
    for (int d = 0; d < 32; d++) asm volatile("" : "+v"(w[d]));   // pin in VGPRs
    float bi = bias[(g * 4 + h) * 64 + o];
    if (tid < 64) hs[tid] = 0.f;
    float c_ = 0.f, n_ = 0.f, m_ = 0.f;
    size_t wxbase = (size_t)(b * S_) * 1024 + g * 256 + h * 64 + o;
    float wx_cur = Wx[wxbase];
    __syncthreads();
    for (int s = 0; s < S_; s++) {
        float wx_next = (s + 1 < S_) ? Wx[wxbase + (size_t)(s + 1) * 1024] : 0.f;
        float a0 = 0.f, a1 = 0.f, a2 = 0.f, a3 = 0.f;
        #pragma unroll
        for (int d4 = 0; d4 < 8; d4++) {
            float4 hv = *(const float4*)&hs[kh * 32 + d4 * 4];
            a0 += hv.x * w[4 * d4 + 0];
            a1 += hv.y * w[4 * d4 + 1];
            a2 += hv.z * w[4 * d4 + 2];
            a3 += hv.w * w[4 * d4 + 3];
        }
        float a = (a0 + a1) + (a2 + a3);
        a += __shfl_xor(a, 1);
        if (kh == 0) raws[g][o] = a + wx_cur + bi;
        __syncthreads();
        float ir = raws[0][o], fr = raws[1][o], zr = raws[2][o], orr = raws[3][o];
        float lfpm = m_ + logsigf_(fr);
        float mn = fmaxf(ir, lfpm);
        float ig = expf(ir - mn), fg = expf(lfpm - mn);
        c_ = fg * c_ + ig * tanhf(zr);
        n_ = fg * n_ + ig;
        m_ = mn;
        float hn = sigmoidf_(orr) * (c_ / n_);
        if (g == 0 && kh == 0) {
            hs[o] = hn;
            ys[(size_t)(b * S_ + s) * 256 + h * 64 + o] = hn;
        }
        __syncthreads();
        wx_cur = wx_next;
    }
}

// ---------------- sLSTM: fused groupnorm+residual + LN2 -> bf16 --------------
__global__ void __launch_bounds__(256)
slstm_post(const float* __restrict__ ys, const float* __restrict__ gn_w,
           float* __restrict__ h, const float* __restrict__ ln2_w,
           ushort_t* __restrict__ ln16) {
    int n = blockIdx.x, t = threadIdx.x;
    float v = ys[(size_t)n * 256 + t];
    float s = v, s2 = v * v;
    #pragma unroll
    for (int off = 32; off; off >>= 1) { s += __shfl_xor(s, off); s2 += __shfl_xor(s2, off); }
    float mu = s / 64.f, var = s2 / 64.f - mu * mu;
    float hv = h[(size_t)n * 256 + t] + (v - mu) * rsqrtf(var + 1e-5f) * gn_w[t];
    h[(size_t)n * 256 + t] = hv;
    // LN over the full 256 row
    float S = hv, S2 = hv * hv;
    #pragma unroll
    for (int off = 32; off; off >>= 1) { S += __shfl_xor(S, off); S2 += __shfl_xor(S2, off); }
    __shared__ float ps[4], ps2[4];
    if ((t & 63) == 0) { ps[t >> 6] = S; ps2[t >> 6] = S2; }
    __syncthreads();
    float St = ps[0] + ps[1] + ps[2] + ps[3];
    float S2t = ps2[0] + ps2[1] + ps2[2] + ps2[3];
    float mu2 = St / 256.f, var2 = S2t / 256.f - mu2 * mu2;
    ln16[(size_t)n * 256 + t] = f2b((hv - mu2) * rsqrtf(var2 + 1e-5f) * ln2_w[t]);
}

// ---------------- FFN: gelu(gate)*up -> bf16 ---------------------------------
__global__ void ffn_act(const float* __restrict__ up, ushort_t* __restrict__ act) {
    int idx = blockIdx.x * blockDim.x + threadIdx.x;
    if (idx >= NTOK * 384) return;
    int n = idx / 384, j = idx - n * 384;
    float g = up[(size_t)n * 768 + j], u = up[(size_t)n * 768 + 384 + j];
    float t = tanhf(0.7978845608028654f * (g + 0.044715f * g * g * g));
    act[idx] = f2b(0.5f * g * (1.f + t) * u);
}

// ---------------- pooling + heads --------------------------------------------
__global__ void pool_k(const float* __restrict__ a, float* __restrict__ pooled) {
    int b = blockIdx.x, e = threadIdx.x;
    float s = 0.f;
    for (int t = 0; t < S_; t++) s += a[(size_t)(b * S_ + t) * 256 + e];
    pooled[b * 256 + e] = s / (float)S_;
}

__global__ void heads_k(const float* __restrict__ pooled,
                        const float* __restrict__ we, const float* __restrict__ be,
                        const float* __restrict__ ws, const float* __restrict__ bs,
                        float* __restrict__ out) {
    int i = blockIdx.x * blockDim.x + threadIdx.x;
    if (i < B_ * 7) {
        int b = i / 7, o = i - b * 7;
        float a = be[o];
        for (int e = 0; e < 256; e++) a += pooled[b * 256 + e] * we[e * 7 + o];
        out[b * 7 + o] = a;
    } else if (i < B_ * 7 + B_ * 3) {
        int j = i - B_ * 7;
        int b = j / 3, o = j - b * 3;
        float a = bs[o];
        for (int e = 0; e < 256; e++) a += pooled[b * 256 + e] * ws[e * 3 + o];
        out[B_ * 7 + b * 3 + o] = a;
    }
}

// =============================================================================
extern "C" void kernel_launch(void* const* d_in, const int* in_sizes, int n_in,
                              void* d_out, int out_size, void* d_ws, size_t ws_size,
                              hipStream_t stream) {
    (void)in_sizes; (void)n_in; (void)out_size; (void)ws_size;
    const float* x          = (const float*)d_in[0];
    const float* w_down     = (const float*)d_in[1];
    const float* b_down     = (const float*)d_in[2];
    const float* m_ln_w     = (const float*)d_in[3];
    const float* m_proj_up  = (const float*)d_in[4];
    const float* m_conv_w   = (const float*)d_in[5];
    const float* m_conv_b   = (const float*)d_in[6];
    const float* m_q_w      = (const float*)d_in[7];
    const float* m_k_w      = (const float*)d_in[8];
    const float* m_v_w      = (const float*)d_in[9];
    const float* m_ig_w     = (const float*)d_in[10];
    const float* m_ig_b     = (const float*)d_in[11];
    const float* m_fg_w     = (const float*)d_in[12];
    const float* m_fg_b     = (const float*)d_in[13];
    const float* m_skip     = (const float*)d_in[14];
    const float* m_outnorm  = (const float*)d_in[15];
    const float* m_proj_dn  = (const float*)d_in[16];
    const float* s_ln_w     = (const float*)d_in[17];
    const float* s_conv_w   = (const float*)d_in[18];
    const float* s_conv_b   = (const float*)d_in[19];
    const float* s_gate_w   = (const float*)d_in[20];
    const float* s_rec_w    = (const float*)d_in[21];
    const float* s_bias     = (const float*)d_in[22];
    const float* s_gn_w     = (const float*)d_in[23];
    const float* s_ln2_w    = (const float*)d_in[24];
    const float* s_ffn_up   = (const float*)d_in[25];
    const float* s_ffn_dn   = (const float*)d_in[26];
    const float* post_ln_w  = (const float*)d_in[27];
    const float* w_emo      = (const float*)d_in[28];
    const float* b_emo      = (const float*)d_in[29];
    const float* w_sen      = (const float*)d_in[30];
    const float* b_sen      = (const float*)d_in[31];

    float* W    = (float*)d_ws;
    float* h    = W;
    float* lnb  = h    + (size_t)NTOK * 256;
    float* big0 = lnb  + (size_t)NTOK * 256;
    float* xca  = big0 + (size_t)NTOK * 1024;
    float* qb   = xca  + (size_t)NTOK * 512;
    float* kb   = qb   + (size_t)NTOK * 512;
    float* vb   = kb   + (size_t)NTOK * 512;
    float* hatt = vb   + (size_t)NTOK * 512;
    float* igo  = hatt + (size_t)NTOK * 512;
    float* fgo  = igo  + (size_t)NTOK * 4;
    float* lfcb = fgo  + (size_t)NTOK * 4;
    float* Mxb  = lfcb + (size_t)256 * (S_ + 1);
    float* pooled = Mxb + (size_t)256 * S_;
    // bf16 overlays
    ushort_t* lnb16 = (ushort_t*)lnb;
    ushort_t* qb16  = (ushort_t*)qb;
    ushort_t* kb16  = (ushort_t*)kb;
    ushort_t* vb16  = (ushort_t*)vb;
    ushort_t* hat16 = qb16 + (size_t)NTOK * 512;
    ushort_t* xc16  = (ushort_t*)(vb16 + (size_t)NTOK * 512);
    ushort_t* wpk   = (ushort_t*)(pooled + 64 * 256);
    ushort_t* wp_pu = wpk;                             // 5*256*1024
    ushort_t* wp_pd = wp_pu + 5 * 262144;              // 5*512*256
    ushort_t* wp_fu = wp_pd + 5 * 131072;              // 2*256*768
    ushort_t* wp_fd = wp_fu + 2 * 196608;              // 2*384*256

    cvt_all<<<(638976 + 255) / 256, 256, 0, stream>>>(m_proj_up, m_proj_dn, s_ffn_up, s_ffn_dn, wpk, 638976);

    gemm_mfma<<<dim3(256 / 64, NTOK / 64), 256, 0, stream>>>(x, w_down, b_down, h, NTOK, 1024, 256, 0);

    int mi = 0, si = 0;
    for (int blk = 0; blk < 7; blk++) {
        if (blk == 1 || blk == 4) {
            layernorm256<<<NTOK, 256, 0, stream>>>(h, s_ln_w + si * 256, lnb16);
            conv_silu_s<<<(NTOK * 256 + 255) / 256, 256, 0, stream>>>(lnb16, s_conv_w + si * 1024, s_conv_b + si * 256, xc16);
            slstm_wx_mfma<<<dim3(NTOK / 64, 16), 256, 0, stream>>>(xc16, lnb16, s_gate_w + (size_t)si * 65536, big0);
            slstm_rec<<<256, 512, 0, stream>>>(big0, s_rec_w + (size_t)si * 65536, s_bias + si * 1024, hatt);
            slstm_post<<<NTOK, 256, 0, stream>>>(hatt, s_gn_w + si * 256, h, s_ln2_w + si * 256, lnb16);
            gemm_bf<<<dim3(768 / 128, NTOK / 64), 256, 0, stream>>>(lnb16, wp_fu + (size_t)si * 196608, nullptr, big0, NTOK, 256, 768, 0);
            ffn_act<<<(NTOK * 384 + 255) / 256, 256, 0, stream>>>(big0, hat16);
            gemm_bf<<<dim3(256 / 128, NTOK / 64), 256, 0, stream>>>(hat16, wp_fd + (size_t)si * 98304, nullptr, h, NTOK, 384, 256, 1);
            si++;
        } else {
            layernorm256<<<NTOK, 256, 0, stream>>>(h, m_ln_w + mi * 256, lnb16);
            gemm_bf<<<dim3(1024 / 128, NTOK / 64), 256, 0, stream>>>(lnb16, wp_pu + (size_t)mi * 262144, nullptr, big0, NTOK, 256, 1024, 0);
            fused_qkv<<<(NTOK * 128 + 255) / 256, 256, 0, stream>>>(big0, m_conv_w + mi * 2048, m_conv_b + mi * 512,
                                                                    m_q_w + mi * 2048, m_k_w + mi * 2048, m_v_w + mi * 2048,
                                                                    xca, qb16, kb16, vb16);
            gates2<<<NTOK / 4, 256, 0, stream>>>(qb16, kb16, vb16, m_ig_w + mi * 6144, m_ig_b + mi * 4,
                                                 m_fg_w + mi * 6144, m_fg_b + mi * 4, igo, fgo);
            mlstm_cumsum<<<64, 256, 0, stream>>>(fgo, igo, lfcb, Mxb);
            mlstm_attn_mfma<<<256, 256, 0, stream>>>(qb16, kb16, vb16, igo, lfcb, Mxb, hatt);
            mhln_hstate<<<NTOK, 512, 0, stream>>>(hatt, m_outnorm + mi * 512, xca, big0, m_skip + mi * 512, hat16);
            gemm_bf<<<dim3(256 / 128, NTOK / 64), 256, 0, stream>>>(hat16, wp_pd + (size_t)mi * 131072, nullptr, h, NTOK, 512, 256, 1);
            mi++;
        }
    }

    postln_selu<<<NTOK, 256, 0, stream>>>(h, post_ln_w, xca);
    pool_k<<<B_, 256, 0, stream>>>(xca, pooled);
    heads_k<<<3, 256, 0, stream>>>(pooled, w_emo, b_emo, w_sen, b_sen, (float*)d_out);
}

// Round 9
// 1903.543 us; speedup vs baseline: 3.3073x; 1.0081x over previous
//
#include <hip/hip_runtime.h>
#include <hip/hip_bf16.h>
#include <math.h>

// AudioModelV3: 7-block xLSTM (blocks 1,4 = sLSTM+FFN; others mLSTM).
// R9: (1) slstm_rec attempt #4: 32 NAMED scalar weights (no array) + asm pin
// + explicit __launch_bounds__(512,2) (budget 256 VGPR). R8's array+pin
// still spilled (VGPR_Count 36). (2) gates fused into fused_qkv (fp32 dots,
// one launch less); cumsum fused into attention prologue (wave-0 scan).

#define B_    64
#define S_    199
#define E_    256
#define NTOK  (B_*S_)          // 12736
#define NQT   13               // ceil(199/16)

typedef __attribute__((ext_vector_type(8))) short short8;
typedef __attribute__((ext_vector_type(4))) float floatx4;
typedef unsigned short ushort_t;

__device__ __forceinline__ float sigmoidf_(float x) { return 1.f / (1.f + expf(-x)); }
__device__ __forceinline__ float siluf_(float x) { return x / (1.f + expf(-x)); }
__device__ __forceinline__ float logsigf_(float x) { return fminf(x, 0.f) - log1pf(expf(-fabsf(x))); }

__device__ __forceinline__ ushort_t f2b(float f) {   // fp32 -> bf16 (RNE)
    union { float f; unsigned u; } v; v.f = f;
    unsigned r = (v.u + 0x7fffu + ((v.u >> 16) & 1u)) >> 16;
    return (ushort_t)r;
}
__device__ __forceinline__ float bf2f(ushort_t u) {
    union { unsigned u; float f; } v; v.u = ((unsigned)u) << 16;
    return v.f;
}

// ---------------- fp32 -> bf16 pack of all GEMM weights (one launch) ---------
__global__ void cvt_all(const float* __restrict__ pu, const float* __restrict__ pd,
                        const float* __restrict__ fu, const float* __restrict__ fd,
                        ushort_t* __restrict__ out, int n4) {
    int i = blockIdx.x * 256 + threadIdx.x;
    if (i >= n4) return;
    int e = i * 4;
    const float* src;
    if (e < 1310720)      src = pu + e;
    else if (e < 1966080) src = pd + (e - 1310720);
    else if (e < 2359296) src = fu + (e - 1966080);
    else                  src = fd + (e - 2359296);
    float4 v = *(const float4*)src;
    union { ushort_t us[4]; uint2 u; } t;
    t.us[0] = f2b(v.x); t.us[1] = f2b(v.y); t.us[2] = f2b(v.z); t.us[3] = f2b(v.w);
    *(uint2*)&out[e] = t.u;
}

// ---------------- bf16 MFMA GEMM: C[M,N] = A[M,K] @ B[K,N] (+bias)(+=C) ------
__global__ void __launch_bounds__(256)
gemm_bf(const ushort_t* __restrict__ A, const ushort_t* __restrict__ Bw,
        const float* __restrict__ bias, float* __restrict__ C,
        int M, int K, int N, int accum) {
    __shared__ __align__(16) ushort_t As[64][40];
    __shared__ __align__(16) ushort_t Bs[128][40];
    int tid = threadIdx.x;
    int wave = tid >> 6, lane = tid & 63;
    int wm = wave >> 1, wn = wave & 1;
    int quad = lane >> 4, l16 = lane & 15;
    int m0 = blockIdx.y * 64, n0 = blockIdx.x * 128;
    floatx4 zero = {0.f, 0.f, 0.f, 0.f};
    floatx4 acc[2][4];
    #pragma unroll
    for (int i = 0; i < 2; i++)
        #pragma unroll
        for (int j = 0; j < 4; j++) acc[i][j] = zero;
    int ar = tid >> 2, ac = (tid & 3) * 8;
    int bn = tid & 127, bkg = (tid >> 7) * 16;
    for (int k0 = 0; k0 < K; k0 += 32) {
        *(uint4*)&As[ar][ac] = *(const uint4*)(A + (size_t)(m0 + ar) * K + k0 + ac);
        {
            const ushort_t* bp = Bw + (size_t)(k0 + bkg) * N + n0 + bn;
            union { ushort_t us[16]; uint4 v[2]; } t;
            #pragma unroll
            for (int i = 0; i < 16; i++) t.us[i] = bp[(size_t)i * N];
            *(uint4*)&Bs[bn][bkg] = t.v[0];
            *(uint4*)&Bs[bn][bkg + 8] = t.v[1];
        }
        __syncthreads();
        short8 af[2], bf[4];
        #pragma unroll
        for (int i = 0; i < 2; i++) af[i] = *(const short8*)&As[wm * 32 + i * 16 + l16][quad * 8];
        #pragma unroll
        for (int j = 0; j < 4; j++) bf[j] = *(const short8*)&Bs[wn * 64 + j * 16 + l16][quad * 8];
        #pragma unroll
        for (int i = 0; i < 2; i++)
            #pragma unroll
            for (int j = 0; j < 4; j++)
                acc[i][j] = __builtin_amdgcn_mfma_f32_16x16x32_bf16(af[i], bf[j], acc[i][j], 0, 0, 0);
        __syncthreads();
    }
    #pragma unroll
    for (int i = 0; i < 2; i++)
        #pragma unroll
        for (int j = 0; j < 4; j++)
            #pragma unroll
            for (int r = 0; r < 4; r++) {
                int row = m0 + wm * 32 + i * 16 + quad * 4 + r;
                int col = n0 + wn * 64 + j * 16 + l16;
                float o = acc[i][j][r];
                if (bias) o += bias[col];
                float* cp = &C[(size_t)row * N + col];
                if (accum) o += *cp;
                *cp = o;
            }
}

// ---------------- fp32-A MFMA GEMM (embed only) ------------------------------
__global__ void __launch_bounds__(256)
gemm_mfma(const float* __restrict__ A, const float* __restrict__ Bw,
          const float* __restrict__ bias, float* __restrict__ C,
          int M, int K, int N, int accum) {
    __shared__ __align__(16) ushort_t As[64][40];
    __shared__ __align__(16) ushort_t Bs[64][40];
    int tid = threadIdx.x;
    int wave = tid >> 6, lane = tid & 63;
    int wm = wave >> 1, wn = wave & 1;
    int quad = lane >> 4, l16 = lane & 15;
    int m0 = blockIdx.y * 64, n0 = blockIdx.x * 64;
    floatx4 zero = {0.f, 0.f, 0.f, 0.f};
    floatx4 acc[2][2];
    acc[0][0] = zero; acc[0][1] = zero; acc[1][0] = zero; acc[1][1] = zero;
    int ar = tid >> 2, ac = (tid & 3) * 8;
    int bn = tid & 63, bk = (tid >> 6) * 8;
    for (int k0 = 0; k0 < K; k0 += 32) {
        {
            const float* ap = A + (size_t)(m0 + ar) * K + k0 + ac;
            union { ushort_t us[8]; uint4 v; } t;
            #pragma unroll
            for (int i = 0; i < 8; i++) t.us[i] = f2b(ap[i]);
            *(uint4*)&As[ar][ac] = t.v;
        }
        {
            const float* bp = Bw + (size_t)(k0 + bk) * N + n0 + bn;
            union { ushort_t us[8]; uint4 v; } t;
            #pragma unroll
            for (int i = 0; i < 8; i++) t.us[i] = f2b(bp[(size_t)i * N]);
            *(uint4*)&Bs[bn][bk] = t.v;
        }
        __syncthreads();
        short8 af[2], bf[2];
        #pragma unroll
        for (int i = 0; i < 2; i++) af[i] = *(const short8*)&As[wm * 32 + i * 16 + l16][quad * 8];
        #pragma unroll
        for (int j = 0; j < 2; j++) bf[j] = *(const short8*)&Bs[wn * 32 + j * 16 + l16][quad * 8];
        #pragma unroll
        for (int i = 0; i < 2; i++)
            #pragma unroll
            for (int j = 0; j < 2; j++)
                acc[i][j] = __builtin_amdgcn_mfma_f32_16x16x32_bf16(af[i], bf[j], acc[i][j], 0, 0, 0);
        __syncthreads();
    }
    #pragma unroll
    for (int i = 0; i < 2; i++)
        #pragma unroll
        for (int j = 0; j < 2; j++)
            #pragma unroll
            for (int r = 0; r < 4; r++) {
                int row = m0 + wm * 32 + i * 16 + quad * 4 + r;
                int col = n0 + wn * 32 + j * 16 + l16;
                float o = acc[i][j][r];
                if (bias) o += bias[col];
                float* cp = &C[(size_t)row * N + col];
                if (accum) o += *cp;
                *cp = o;
            }
}

// ---------------- sLSTM Wx as block-diagonal MFMA GEMM (bf16 A) --------------
__global__ void __launch_bounds__(256)
slstm_wx_mfma(const ushort_t* __restrict__ xc, const ushort_t* __restrict__ xln,
              const float* __restrict__ gw, float* __restrict__ Wx) {
    __shared__ __align__(16) ushort_t As[64][40];
    __shared__ __align__(16) ushort_t Bs[64][40];
    int gh = blockIdx.y; int g = gh >> 2, hh = gh & 3;
    const ushort_t* src = (g < 2) ? xc : xln;
    const float* w = gw + (size_t)gh * 4096;
    int tid = threadIdx.x;
    int wave = tid >> 6, lane = tid & 63;
    int wm = wave >> 1, wn = wave & 1;
    int quad = lane >> 4, l16 = lane & 15;
    int m0 = blockIdx.x * 64;
    floatx4 zero = {0.f, 0.f, 0.f, 0.f};
    floatx4 acc[2][2];
    acc[0][0] = zero; acc[0][1] = zero; acc[1][0] = zero; acc[1][1] = zero;
    int ar = tid >> 2, ac = (tid & 3) * 8;
    int bn = tid & 63, bk = (tid >> 6) * 8;
    #pragma unroll
    for (int kt = 0; kt < 2; kt++) {
        int k0 = kt * 32;
        *(uint4*)&As[ar][ac] = *(const uint4*)(src + (size_t)(m0 + ar) * 256 + hh * 64 + k0 + ac);
        {
            const float* bp = w + (size_t)bn * 64 + k0 + bk;
            union { ushort_t us[8]; uint4 v; } t;
            #pragma unroll
            for (int i = 0; i < 8; i++) t.us[i] = f2b(bp[i]);
            *(uint4*)&Bs[bn][bk] = t.v;
        }
        __syncthreads();
        short8 af[2], bf[2];
        #pragma unroll
        for (int i = 0; i < 2; i++) af[i] = *(const short8*)&As[wm * 32 + i * 16 + l16][quad * 8];
        #pragma unroll
        for (int j = 0; j < 2; j++) bf[j] = *(const short8*)&Bs[wn * 32 + j * 16 + l16][quad * 8];
        #pragma unroll
        for (int i = 0; i < 2; i++)
            #pragma unroll
            for (int j = 0; j < 2; j++)
                acc[i][j] = __builtin_amdgcn_mfma_f32_16x16x32_bf16(af[i], bf[j], acc[i][j], 0, 0, 0);
        __syncthreads();
    }
    #pragma unroll
    for (int i = 0; i < 2; i++)
        #pragma unroll
        for (int j = 0; j < 2; j++)
            #pragma unroll
            for (int r = 0; r < 4; r++) {
                int row = m0 + wm * 32 + i * 16 + quad * 4 + r;
                int col = wn * 32 + j * 16 + l16;
                Wx[(size_t)row * 1024 + g * 256 + hh * 64 + col] = acc[i][j][r];
            }
}

// ---------------- layernorm over 256, bf16 output ----------------------------
__global__ void __launch_bounds__(256)
layernorm256(const float* __restrict__ x, const float* __restrict__ w, ushort_t* __restrict__ y) {
    int n = blockIdx.x, t = threadIdx.x;
    float v = x[(size_t)n * 256 + t];
    float s = v, s2 = v * v;
    #pragma unroll
    for (int off = 32; off; off >>= 1) { s += __shfl_xor(s, off); s2 += __shfl_xor(s2, off); }
    __shared__ float ps[4], ps2[4];
    if ((t & 63) == 0) { ps[t >> 6] = s; ps2[t >> 6] = s2; }
    __syncthreads();
    float S = ps[0] + ps[1] + ps[2] + ps[3];
    float S2 = ps2[0] + ps2[1] + ps2[2] + ps2[3];
    float mu = S / 256.f, var = S2 / 256.f - mu * mu;
    y[(size_t)n * 256 + t] = f2b((v - mu) * rsqrtf(var + 1e-5f) * w[t]);
}

// ---------------- post-LN + selu (fp32 out) ---------------------------------
__global__ void __launch_bounds__(256)
postln_selu(const float* __restrict__ x, const float* __restrict__ w, float* __restrict__ y) {
    int n = blockIdx.x, t = threadIdx.x;
    float v = x[(size_t)n * 256 + t];
    float s = v, s2 = v * v;
    #pragma unroll
    for (int off = 32; off; off >>= 1) { s += __shfl_xor(s, off); s2 += __shfl_xor(s2, off); }
    __shared__ float ps[4], ps2[4];
    if ((t & 63) == 0) { ps[t >> 6] = s; ps2[t >> 6] = s2; }
    __syncthreads();
    float S = ps[0] + ps[1] + ps[2] + ps[3];
    float S2 = ps2[0] + ps2[1] + ps2[2] + ps2[3];
    float mu = S / 256.f, var = S2 / 256.f - mu * mu;
    float yn = (v - mu) * rsqrtf(var + 1e-5f) * w[t];
    y[(size_t)n * 256 + t] = 1.0507009873554805f * (yn > 0.f ? yn : 1.6732632423543772f * (expf(yn) - 1.f));
}

// ---------------- mLSTM: fused conv+silu+qkv+GATES (bf16 q/k/v out) ----------
// Block = 2 tokens x 128 hh-threads. Gate dots use fp32 pre-rounding q/k/v.
__global__ void __launch_bounds__(256)
fused_qkv(const float* __restrict__ xi, const float* __restrict__ cw,
          const float* __restrict__ cb,
          const float* __restrict__ qw, const float* __restrict__ kw,
          const float* __restrict__ vw,
          const float* __restrict__ igw, const float* __restrict__ igbias,
          const float* __restrict__ fgw, const float* __restrict__ fgbias,
          float* __restrict__ xca,
          ushort_t* __restrict__ q16, ushort_t* __restrict__ k16, ushort_t* __restrict__ v16,
          float* __restrict__ igo, float* __restrict__ fgo) {
    __shared__ float gpart[4][8];
    int tid = threadIdx.x;
    int idx = blockIdx.x * 256 + tid;
    int n = idx >> 7, hh = idx & 127;
    int b = n / S_, s = n - b * S_;
    int c0 = hh * 4;
    float4 hist[4];
    #pragma unroll
    for (int i = 0; i < 4; i++) {
        int sp = s - 3 + i;
        if (sp >= 0) hist[i] = *(const float4*)(xi + (size_t)(b * S_ + sp) * 1024 + c0);
        else hist[i] = (float4){0.f, 0.f, 0.f, 0.f};
    }
    float xm[4] = {hist[3].x, hist[3].y, hist[3].z, hist[3].w};
    float xc4[4];
    #pragma unroll
    for (int d = 0; d < 4; d++) {
        float y = cb[c0 + d];
        const float* cwp = cw + (c0 + d) * 4;
        float hv[4] = { d==0?hist[0].x:(d==1?hist[0].y:(d==2?hist[0].z:hist[0].w)),
                        d==0?hist[1].x:(d==1?hist[1].y:(d==2?hist[1].z:hist[1].w)),
                        d==0?hist[2].x:(d==1?hist[2].y:(d==2?hist[2].z:hist[2].w)),
                        xm[d] };
        #pragma unroll
        for (int i = 0; i < 4; i++) y += hv[i] * cwp[i];
        xc4[d] = siluf_(y);
    }
    *(float4*)(xca + (size_t)n * 512 + c0) = (float4){xc4[0], xc4[1], xc4[2], xc4[3]};
    float aq[4], ak[4], av[4];
    union { ushort_t us[4]; uint2 u; } qo, ko, vo;
    #pragma unroll
    for (int o = 0; o < 4; o++) {
        const float* qp = qw + (c0 + o) * 4;
        const float* kp = kw + (c0 + o) * 4;
        const float* vp = vw + (c0 + o) * 4;
        float q = 0.f, k = 0.f, v = 0.f;
        #pragma unroll
        for (int d = 0; d < 4; d++) {
            q += xc4[d] * qp[d];
            k += xc4[d] * kp[d];
            v += xm[d] * vp[d];
        }
        aq[o] = q; ak[o] = k; av[o] = v;
        qo.us[o] = f2b(q); ko.us[o] = f2b(k); vo.us[o] = f2b(v);
    }
    *(uint2*)(q16 + (size_t)n * 512 + c0) = qo.u;
    *(uint2*)(k16 + (size_t)n * 512 + c0) = ko.u;
    *(uint2*)(v16 + (size_t)n * 512 + c0) = vo.u;
    // ---- gate dots: 8 outputs (4 heads x {ig,fg}) over this token's 512 row
    float gacc[8];
    #pragma unroll
    for (int hd = 0; hd < 4; hd++)
        #pragma unroll
        for (int wh = 0; wh < 2; wh++) {
            const float* w = (wh ? fgw : igw) + hd * 1536 + c0;
            float4 wq = *(const float4*)w;
            float4 wk = *(const float4*)(w + 512);
            float4 wv = *(const float4*)(w + 1024);
            float a = aq[0]*wq.x + aq[1]*wq.y + aq[2]*wq.z + aq[3]*wq.w
                    + ak[0]*wk.x + ak[1]*wk.y + ak[2]*wk.z + ak[3]*wk.w
                    + av[0]*wv.x + av[1]*wv.y + av[2]*wv.z + av[3]*wv.w;
            gacc[hd * 2 + wh] = a;
        }
    int lane = tid & 63, wave = tid >> 6;
    #pragma unroll
    for (int j = 0; j < 8; j++) {
        float a = gacc[j];
        #pragma unroll
        for (int off = 32; off; off >>= 1) a += __shfl_xor(a, off);
        if (lane == 0) gpart[wave][j] = a;
    }
    __syncthreads();
    if (tid < 16) {
        int token = tid >> 3, j = tid & 7;
        int hd = j >> 1, wh = j & 1;
        float val = gpart[token * 2][j] + gpart[token * 2 + 1][j]
                  + (wh ? fgbias : igbias)[hd];
        int nn = blockIdx.x * 2 + token;
        (wh ? fgo : igo)[(size_t)nn * 4 + hd] = val;
    }
}

// ---------------- mLSTM attention: MFMA flash + in-block cumsum scan ---------
__global__ void __launch_bounds__(256, 1)
mlstm_attn_mfma(const ushort_t* __restrict__ qb, const ushort_t* __restrict__ kb, const ushort_t* __restrict__ vb,
                const float* __restrict__ igo, const float* __restrict__ fgo,
                float* __restrict__ outb) {
    __shared__ __align__(16) ushort_t Kb[64 * 136];
    __shared__ __align__(16) ushort_t Vt[128 * 72];
    __shared__ __align__(16) ushort_t Pw[4][16 * 72];
    __shared__ float gv[208], lfv[208], mxv[208];
    int bh = blockIdx.x; int b = bh >> 2, h = bh & 3;
    int tid = threadIdx.x, wave = tid >> 6, lane = tid & 63;
    int quad = lane >> 4, l16 = lane & 15;
    // wave-0 prologue: cumsum(logsig(fg)) + prefix-max scan for this (b,h)
    if (tid < 64) {
        float vloc[4], ggl[4], gml[4], lf1[4];
        float lsum = 0.f;
        #pragma unroll
        for (int i = 0; i < 4; i++) {
            int s = tid * 4 + i;
            float f = (s < S_) ? fgo[(size_t)(b * S_ + s) * 4 + h] : 0.f;
            lsum += logsigf_(f);
            vloc[i] = lsum;
        }
        float x = lsum;
        #pragma unroll
        for (int off = 1; off < 64; off <<= 1) {
            float y = __shfl_up(x, off);
            if (tid >= off) x += y;
        }
        float excl = x - lsum;
        #pragma unroll
        for (int i = 0; i < 4; i++) lf1[i] = excl + vloc[i];
        float lmax = -1e30f;
        #pragma unroll
        for (int i = 0; i < 4; i++) {
            int s = tid * 4 + i;
            float ig_ = (s < S_) ? igo[(size_t)(b * S_ + s) * 4 + h] : -1e30f;
            ggl[i] = ig_ - lf1[i];
            lmax = fmaxf(lmax, ggl[i]);
            gml[i] = lmax;
        }
        float xm = lmax;
        #pragma unroll
        for (int off = 1; off < 64; off <<= 1) {
            float y = __shfl_up(xm, off);
            if (tid >= off) xm = fmaxf(xm, y);
        }
        float exclm = __shfl_up(xm, 1);
        if (tid == 0) exclm = -1e30f;
        #pragma unroll
        for (int i = 0; i < 4; i++) {
            int s = tid * 4 + i;
            if (s < 208) {
                if (s < S_) {
                    lfv[s] = lf1[i];
                    gv[s] = ggl[i];
                    mxv[s] = fmaxf(exclm, gml[i]);
                } else { lfv[s] = 0.f; gv[s] = 0.f; mxv[s] = 0.f; }
            }
        }
    }
    floatx4 zero = {0.f, 0.f, 0.f, 0.f};
    float rs[4][4];
    floatx4 accv[4][8];
    #pragma unroll
    for (int qi = 0; qi < 4; qi++) {
        #pragma unroll
        for (int r = 0; r < 4; r++) rs[qi][r] = 0.f;
        #pragma unroll
        for (int dt = 0; dt < 8; dt++) accv[qi][dt] = zero;
    }
    const float scale = 0.08838834764831845f;
    int trow = tid >> 4, d0 = (tid & 15) * 8;
    for (int c = 0; c < 4; c++) {
        __syncthreads();
        #pragma unroll
        for (int i = 0; i < 4; i++) {
            int tl = trow + 16 * i;
            int t = c * 64 + tl;
            union { ushort_t us[8]; uint4 v; } kk, vv;
            if (t < S_) {
                kk.v = *(const uint4*)(kb + (size_t)(b * S_ + t) * 512 + h * 128 + d0);
                vv.v = *(const uint4*)(vb + (size_t)(b * S_ + t) * 512 + h * 128 + d0);
            } else {
                kk.v = (uint4){0, 0, 0, 0};
                vv.v = (uint4){0, 0, 0, 0};
            }
            *(uint4*)&Kb[tl * 136 + d0] = kk.v;
            #pragma unroll
            for (int ii = 0; ii < 8; ii++) Vt[(d0 + ii) * 72 + tl] = vv.us[ii];
        }
        __syncthreads();
        for (int qi = 0; qi < 4; qi++) {
            int qt = wave + 4 * qi;
            if (qt >= NQT || qt < 4 * c) continue;
            uint4 z4 = {0, 0, 0, 0};
            for (int z = lane; z < 144; z += 64) ((uint4*)Pw[wave])[z] = z4;
            int srow = qt * 16 + l16;
            const ushort_t* qp = qb + (size_t)(b * S_ + min(srow, S_ - 1)) * 512 + h * 128 + quad * 8;
            short8 af[4];
            #pragma unroll
            for (int ks = 0; ks < 4; ks++) af[ks] = *(const short8*)(qp + 32 * ks);
            int ktmax_l = min(qt, 4 * c + 3) - 4 * c;
            for (int ktl = 0; ktl <= ktmax_l; ktl++) {
                floatx4 acc = zero;
                #pragma unroll
                for (int ks = 0; ks < 4; ks++) {
                    short8 bf = *(const short8*)&Kb[(ktl * 16 + l16) * 136 + quad * 8 + 32 * ks];
                    acc = __builtin_amdgcn_mfma_f32_16x16x32_bf16(af[ks], bf, acc, 0, 0, 0);
                }
                int tcol = c * 64 + ktl * 16 + l16;
                float gt = gv[tcol];
                #pragma unroll
                for (int r = 0; r < 4; r++) {
                    int s = qt * 16 + quad * 4 + r;
                    bool valid = (tcol <= s) && (tcol < S_);
                    float w = valid ? expf(gt - mxv[s]) : 0.f;
                    float p = acc[r] * scale * w;
                    rs[qi][r] += p;
                    Pw[wave][(quad * 4 + r) * 72 + ktl * 16 + l16] = f2b(p);
                }
            }
            #pragma unroll
            for (int dt = 0; dt < 8; dt++) {
                floatx4 a = accv[qi][dt];
                #pragma unroll
                for (int ks = 0; ks < 2; ks++) {
                    short8 ap = *(const short8*)&Pw[wave][l16 * 72 + quad * 8 + 32 * ks];
                    short8 bp = *(const short8*)&Vt[(dt * 16 + l16) * 72 + quad * 8 + 32 * ks];
                    a = __builtin_amdgcn_mfma_f32_16x16x32_bf16(ap, bp, a, 0, 0, 0);
                }
                accv[qi][dt] = a;
            }
        }
    }
    for (int qi = 0; qi < 4; qi++) {
        int qt = wave + 4 * qi;
        if (qt >= NQT) continue;
        float nrm[4];
        #pragma unroll
        for (int r = 0; r < 4; r++) {
            float v = rs[qi][r];
            v += __shfl_xor(v, 1); v += __shfl_xor(v, 2);
            v += __shfl_xor(v, 4); v += __shfl_xor(v, 8);
            int s = qt * 16 + quad * 4 + r;
            nrm[r] = fmaxf(fabsf(v), expf(-(lfv[s] + mxv[s]))) + 1e-6f;
        }
        #pragma unroll
        for (int dt = 0; dt < 8; dt++)
            #pragma unroll
            for (int r = 0; r < 4; r++) {
                int s = qt * 16 + quad * 4 + r;
                if (s < S_)
                    outb[(size_t)(b * S_ + s) * 512 + h * 128 + dt * 16 + l16] = accv[qi][dt][r] / nrm[r];
            }
    }
}

// ---------------- mLSTM: fused per-head LN + h_state -> bf16 -----------------
__global__ void __launch_bounds__(512)
mhln_hstate(const float* __restrict__ hatt, const float* __restrict__ w,
            const float* __restrict__ xca, const float* __restrict__ xi,
            const float* __restrict__ skip, ushort_t* __restrict__ out16) {
    int n = blockIdx.x, t = threadIdx.x;
    float v = hatt[(size_t)n * 512 + t];
    float s = v, s2 = v * v;
    #pragma unroll
    for (int off = 32; off; off >>= 1) { s += __shfl_xor(s, off); s2 += __shfl_xor(s2, off); }
    __shared__ float ps[8], ps2[8];
    if ((t & 63) == 0) { ps[t >> 6] = s; ps2[t >> 6] = s2; }
    __syncthreads();
    int hd = t >> 7;
    float S = ps[hd * 2] + ps[hd * 2 + 1], S2 = ps2[hd * 2] + ps2[hd * 2 + 1];
    float mu = S / 128.f, var = S2 / 128.f - mu * mu;
    float hn = (v - mu) * rsqrtf(var + 1e-5f) * w[t];
    float z = xi[(size_t)n * 1024 + 512 + t];
    out16[(size_t)n * 512 + t] = f2b((hn + skip[t] * xca[(size_t)n * 512 + t]) * siluf_(z));
}

// ---------------- sLSTM: causal conv (256 ch) + silu, bf16 in/out ------------
__global__ void conv_silu_s(const ushort_t* __restrict__ xln, const float* __restrict__ cw,
                            const float* __restrict__ cb, ushort_t* __restrict__ xc) {
    int idx = blockIdx.x * blockDim.x + threadIdx.x;
    if (idx >= NTOK * 256) return;
    int n = idx >> 8, c = idx & 255;
    int b = n / S_, s = n - b * S_;
    float y = cb[c];
    #pragma unroll
    for (int i = 0; i < 4; i++) {
        int sp = s - 3 + i;
        if (sp >= 0) y += bf2f(xln[(size_t)(b * S_ + sp) * 256 + c]) * cw[c * 4 + i];
    }
    xc[idx] = f2b(siluf_(y));
}

// ---------------- sLSTM: recurrence, 32 NAMED weight scalars + pin -----------
// Attempt #4: no array (SROA-independent), explicit (512,2) => 256 VGPR
// budget, asm pins on named scalars. g=tid>>7, o=(tid>>1)&63, kh=tid&1.
__global__ void __launch_bounds__(512, 2)
slstm_rec(const float* __restrict__ Wx, const float* __restrict__ rw,
          const float* __restrict__ bias, float* __restrict__ ys) {
    __shared__ __align__(16) float hs[64];
    __shared__ float raws[4][64];
    int b = blockIdx.x >> 2, h = blockIdx.x & 3;
    int tid = threadIdx.x;
    int g = tid >> 7, o = (tid >> 1) & 63, kh = tid & 1;
    const float* wp = rw + (size_t)(((g * 4 + h) * 64 + o)) * 64 + kh * 32;
    float w0 = wp[0],  w1 = wp[1],  w2 = wp[2],  w3 = wp[3];
    float w4 = wp[4],  w5 = wp[5],  w6 = wp[6],  w7 = wp[7];
    float w8 = wp[8],  w9 = wp[9],  w10 = wp[10], w11 = wp[11];
    float w12 = wp[12], w13 = wp[13], w14 = wp[14], w15 = wp[15];
    float w16 = wp[16], w17 = wp[17], w18 = wp[18], w19 = wp[19];
    float w20 = wp[20], w21 = wp[21], w22 = wp[22], w23 = wp[23];
    float w24 = wp[24], w25 = wp[25], w26 = wp[26], w27 = wp[27];
    float w28 = wp[28], w29 = wp[29], w30 = wp[30], w31 = wp[31];
    asm volatile("" : "+v"(w0), "+v"(w1), "+v"(w2), "+v"(w3), "+v"(w4), "+v"(w5),
                      "+v"(w6), "+v"(w7), "+v"(w8), "+v"(w9), "+v"(w10), "+v"(w11),
                      "+v"(w12), "+v"(w13), "+v"(w14), "+v"(w15));
    asm volatile("" : "+v"(w16), "+v"(w17), "+v"(w18), "+v"(w19), "+v"(w20), "+v"(w21),
                      "+v"(w22), "+v"(w23), "+v"(w24), "+v"(w25), "+v"(w26), "+v"(w27),
                      "+v"(w28), "+v"(w29), "+v"(w30), "+v"(w31));
    float bi = bias[(g * 4 + h) * 64 + o];
    if (tid < 64) hs[tid] = 0.f;
    float c_ = 0.f, n_ = 0.f, m_ = 0.f;
    size_t wxbase = (size_t)(b * S_) * 1024 + g * 256 + h * 64 + o;
    float wx_cur = Wx[wxbase];
    const float* hsp = hs + kh * 32;
    __syncthreads();
    for (int s = 0; s < S_; s++) {
        float wx_next = (s + 1 < S_) ? Wx[wxbase + (size_t)(s + 1) * 1024] : 0.f;
        float a0 = 0.f, a1 = 0.f, a2 = 0.f, a3 = 0.f;
        {
            float4 hv;
            hv = *(const float4*)&hsp[0];  a0 += hv.x * w0;  a1 += hv.y * w1;  a2 += hv.z * w2;  a3 += hv.w * w3;
            hv = *(const float4*)&hsp[4];  a0 += hv.x * w4;  a1 += hv.y * w5;  a2 += hv.z * w6;  a3 += hv.w * w7;
            hv = *(const float4*)&hsp[8];  a0 += hv.x * w8;  a1 += hv.y * w9;  a2 += hv.z * w10; a3 += hv.w * w11;
            hv = *(const float4*)&hsp[12]; a0 += hv.x * w12; a1 += hv.y * w13; a2 += hv.z * w14; a3 += hv.w * w15;
            hv = *(const float4*)&hsp[16]; a0 += hv.x * w16; a1 += hv.y * w17; a2 += hv.z * w18; a3 += hv.w * w19;
            hv = *(const float4*)&hsp[20]; a0 += hv.x * w20; a1 += hv.y * w21; a2 += hv.z * w22; a3 += hv.w * w23;
            hv = *(const float4*)&hsp[24]; a0 += hv.x * w24; a1 += hv.y * w25; a2 += hv.z * w26; a3 += hv.w * w27;
            hv = *(const float4*)&hsp[28]; a0 += hv.x * w28; a1 += hv.y * w29; a2 += hv.z * w30; a3 += hv.w * w31;
        }
        float a = (a0 + a1) + (a2 + a3);
        a += __shfl_xor(a, 1);
        if (kh == 0) raws[g][o] = a + wx_cur + bi;
        __syncthreads();
        float ir = raws[0][o], fr = raws[1][o], zr = raws[2][o], orr = raws[3][o];
        float lfpm = m_ + logsigf_(fr);
        float mn = fmaxf(ir, lfpm);
        float ig = expf(ir - mn), fg = expf(lfpm - mn);
        c_ = fg * c_ + ig * tanhf(zr);
        n_ = fg * n_ + ig;
        m_ = mn;
        float hn = sigmoidf_(orr) * (c_ / n_);
        if (g == 0 && kh == 0) {
            hs[o] = hn;
            ys[(size_t)(b * S_ + s) * 256 + h * 64 + o] = hn;
        }
        __syncthreads();
        wx_cur = wx_next;
    }
}

// ---------------- sLSTM: fused groupnorm+residual + LN2 -> bf16 --------------
__global__ void __launch_bounds__(256)
slstm_post(const float* __restrict__ ys, const float* __restrict__ gn_w,
           float* __restrict__ h, const float* __restrict__ ln2_w,
           ushort_t* __restrict__ ln16) {
    int n = blockIdx.x, t = threadIdx.x;
    float v = ys[(size_t)n * 256 + t];
    float s = v, s2 = v * v;
    #pragma unroll
    for (int off = 32; off; off >>= 1) { s += __shfl_xor(s, off); s2 += __shfl_xor(s2, off); }
    float mu = s / 64.f, var = s2 / 64.f - mu * mu;
    float hv = h[(size_t)n * 256 + t] + (v - mu) * rsqrtf(var + 1e-5f) * gn_w[t];
    h[(size_t)n * 256 + t] = hv;
    float S = hv, S2 = hv * hv;
    #pragma unroll
    for (int off = 32; off; off >>= 1) { S += __shfl_xor(S, off); S2 += __shfl_xor(S2, off); }
    __shared__ float ps[4], ps2[4];
    if ((t & 63) == 0) { ps[t >> 6] = S; ps2[t >> 6] = S2; }
    __syncthreads();
    float St = ps[0] + ps[1] + ps[2] + ps[3];
    float S2t = ps2[0] + ps2[1] + ps2[2] + ps2[3];
    float mu2 = St / 256.f, var2 = S2t / 256.f - mu2 * mu2;
    ln16[(size_t)n * 256 + t] = f2b((hv - mu2) * rsqrtf(var2 + 1e-5f) * ln2_w[t]);
}

// ---------------- FFN: gelu(gate)*up -> bf16 ---------------------------------
__global__ void ffn_act(const float* __restrict__ up, ushort_t* __restrict__ act) {
    int idx = blockIdx.x * blockDim.x + threadIdx.x;
    if (idx >= NTOK * 384) return;
    int n = idx / 384, j = idx - n * 384;
    float g = up[(size_t)n * 768 + j], u = up[(size_t)n * 768 + 384 + j];
    float t = tanhf(0.7978845608028654f * (g + 0.044715f * g * g * g));
    act[idx] = f2b(0.5f * g * (1.f + t) * u);
}

// ---------------- pooling + heads --------------------------------------------
__global__ void pool_k(const float* __restrict__ a, float* __restrict__ pooled) {
    int b = blockIdx.x, e = threadIdx.x;
    float s = 0.f;
    for (int t = 0; t < S_; t++) s += a[(size_t)(b * S_ + t) * 256 + e];
    pooled[b * 256 + e] = s / (float)S_;
}

__global__ void heads_k(const float* __restrict__ pooled,
                        const float* __restrict__ we, const float* __restrict__ be,
                        const float* __restrict__ ws, const float* __restrict__ bs,
                        float* __restrict__ out) {
    int i = blockIdx.x * blockDim.x + threadIdx.x;
    if (i < B_ * 7) {
        int b = i / 7, o = i - b * 7;
        float a = be[o];
        for (int e = 0; e < 256; e++) a += pooled[b * 256 + e] * we[e * 7 + o];
        out[b * 7 + o] = a;
    } else if (i < B_ * 7 + B_ * 3) {
        int j = i - B_ * 7;
        int b = j / 3, o = j - b * 3;
        float a = bs[o];
        for (int e = 0; e < 256; e++) a += pooled[b * 256 + e] * ws[e * 3 + o];
        out[B_ * 7 + b * 3 + o] = a;
    }
}

// =============================================================================
extern "C" void kernel_launch(void* const* d_in, const int* in_sizes, int n_in,
                              void* d_out, int out_size, void* d_ws, size_t ws_size,
                              hipStream_t stream) {
    (void)in_sizes; (void)n_in; (void)out_size; (void)ws_size;
    const float* x          = (const float*)d_in[0];
    const float* w_down     = (const float*)d_in[1];
    const float* b_down     = (const float*)d_in[2];
    const float* m_ln_w     = (const float*)d_in[3];
    const float* m_proj_up  = (const float*)d_in[4];
    const float* m_conv_w   = (const float*)d_in[5];
    const float* m_conv_b   = (const float*)d_in[6];
    const float* m_q_w      = (const float*)d_in[7];
    const float* m_k_w      = (const float*)d_in[8];
    const float* m_v_w      = (const float*)d_in[9];
    const float* m_ig_w     = (const float*)d_in[10];
    const float* m_ig_b     = (const float*)d_in[11];
    const float* m_fg_w     = (const float*)d_in[12];
    const float* m_fg_b     = (const float*)d_in[13];
    const float* m_skip     = (const float*)d_in[14];
    const float* m_outnorm  = (const float*)d_in[15];
    const float* m_proj_dn  = (const float*)d_in[16];
    const float* s_ln_w     = (const float*)d_in[17];
    const float* s_conv_w   = (const float*)d_in[18];
    const float* s_conv_b   = (const float*)d_in[19];
    const float* s_gate_w   = (const float*)d_in[20];
    const float* s_rec_w    = (const float*)d_in[21];
    const float* s_bias     = (const float*)d_in[22];
    const float* s_gn_w     = (const float*)d_in[23];
    const float* s_ln2_w    = (const float*)d_in[24];
    const float* s_ffn_up   = (const float*)d_in[25];
    const float* s_ffn_dn   = (const float*)d_in[26];
    const float* post_ln_w  = (const float*)d_in[27];
    const float* w_emo      = (const float*)d_in[28];
    const float* b_emo      = (const float*)d_in[29];
    const float* w_sen      = (const float*)d_in[30];
    const float* b_sen      = (const float*)d_in[31];

    float* W    = (float*)d_ws;
    float* h    = W;
    float* lnb  = h    + (size_t)NTOK * 256;
    float* big0 = lnb  + (size_t)NTOK * 256;
    float* xca  = big0 + (size_t)NTOK * 1024;
    float* qb   = xca  + (size_t)NTOK * 512;
    float* kb   = qb   + (size_t)NTOK * 512;
    float* vb   = kb   + (size_t)NTOK * 512;
    float* hatt = vb   + (size_t)NTOK * 512;
    float* igo  = hatt + (size_t)NTOK * 512;
    float* fgo  = igo  + (size_t)NTOK * 4;
    float* lfcb = fgo  + (size_t)NTOK * 4;
    float* Mxb  = lfcb + (size_t)256 * (S_ + 1);
    float* pooled = Mxb + (size_t)256 * S_;
    // bf16 overlays
    ushort_t* lnb16 = (ushort_t*)lnb;
    ushort_t* qb16  = (ushort_t*)qb;
    ushort_t* kb16  = (ushort_t*)kb;
    ushort_t* vb16  = (ushort_t*)vb;
    ushort_t* hat16 = qb16 + (size_t)NTOK * 512;
    ushort_t* xc16  = (ushort_t*)(vb16 + (size_t)NTOK * 512);
    ushort_t* wpk   = (ushort_t*)(pooled + 64 * 256);
    ushort_t* wp_pu = wpk;                             // 5*256*1024
    ushort_t* wp_pd = wp_pu + 5 * 262144;              // 5*512*256
    ushort_t* wp_fu = wp_pd + 5 * 131072;              // 2*256*768
    ushort_t* wp_fd = wp_fu + 2 * 196608;              // 2*384*256

    cvt_all<<<(638976 + 255) / 256, 256, 0, stream>>>(m_proj_up, m_proj_dn, s_ffn_up, s_ffn_dn, wpk, 638976);

    gemm_mfma<<<dim3(256 / 64, NTOK / 64), 256, 0, stream>>>(x, w_down, b_down, h, NTOK, 1024, 256, 0);

    int mi = 0, si = 0;
    for (int blk = 0; blk < 7; blk++) {
        if (blk == 1 || blk == 4) {
            layernorm256<<<NTOK, 256, 0, stream>>>(h, s_ln_w + si * 256, lnb16);
            conv_silu_s<<<(NTOK * 256 + 255) / 256, 256, 0, stream>>>(lnb16, s_conv_w + si * 1024, s_conv_b + si * 256, xc16);
            slstm_wx_mfma<<<dim3(NTOK / 64, 16), 256, 0, stream>>>(xc16, lnb16, s_gate_w + (size_t)si * 65536, big0);
            slstm_rec<<<256, 512, 0, stream>>>(big0, s_rec_w + (size_t)si * 65536, s_bias + si * 1024, hatt);
            slstm_post<<<NTOK, 256, 0, stream>>>(hatt, s_gn_w + si * 256, h, s_ln2_w + si * 256, lnb16);
            gemm_bf<<<dim3(768 / 128, NTOK / 64), 256, 0, stream>>>(lnb16, wp_fu + (size_t)si * 196608, nullptr, big0, NTOK, 256, 768, 0);
            ffn_act<<<(NTOK * 384 + 255) / 256, 256, 0, stream>>>(big0, hat16);
            gemm_bf<<<dim3(256 / 128, NTOK / 64), 256, 0, stream>>>(hat16, wp_fd + (size_t)si * 98304, nullptr, h, NTOK, 384, 256, 1);
            si++;
        } else {
            layernorm256<<<NTOK, 256, 0, stream>>>(h, m_ln_w + mi * 256, lnb16);
            gemm_bf<<<dim3(1024 / 128, NTOK / 64), 256, 0, stream>>>(lnb16, wp_pu + (size_t)mi * 262144, nullptr, big0, NTOK, 256, 1024, 0);
            fused_qkv<<<NTOK / 2, 256, 0, stream>>>(big0, m_conv_w + mi * 2048, m_conv_b + mi * 512,
                                                    m_q_w + mi * 2048, m_k_w + mi * 2048, m_v_w + mi * 2048,
                                                    m_ig_w + mi * 6144, m_ig_b + mi * 4,
                                                    m_fg_w + mi * 6144, m_fg_b + mi * 4,
                                                    xca, qb16, kb16, vb16, igo, fgo);
            mlstm_attn_mfma<<<256, 256, 0, stream>>>(qb16, kb16, vb16, igo, fgo, hatt);
            mhln_hstate<<<NTOK, 512, 0, stream>>>(hatt, m_outnorm + mi * 512, xca, big0, m_skip + mi * 512, hat16);
            gemm_bf<<<dim3(256 / 128, NTOK / 64), 256, 0, stream>>>(hat16, wp_pd + (size_t)mi * 131072, nullptr, h, NTOK, 512, 256, 1);
            mi++;
        }
    }

    postln_selu<<<NTOK, 256, 0, stream>>>(h, post_ln_w, xca);
    pool_k<<<B_, 256, 0, stream>>>(xca, pooled);
    heads_k<<<3, 256, 0, stream>>>(pooled, w_emo, b_emo, w_sen, b_sen, (float*)d_out);
}